// Round 8
// baseline (1904.170 us; speedup 1.0000x reference)
//
#include <hip/hip_runtime.h>
#include <hip/hip_bf16.h>

#define DI __device__ __forceinline__

constexpr int Bc = 2, Cc = 256, Hc = 256, Wc = 256, Nc = Hc * Wc; // N=65536
constexpr float LA_EPS = 1e-6f;

typedef __attribute__((ext_vector_type(8))) short short8;
typedef __attribute__((ext_vector_type(4))) float floatx4;
typedef __attribute__((ext_vector_type(16))) float floatx16;

union Frag { short8 v; uint u[4]; };

DI ushort f2bf(float f) {
    uint u = __float_as_uint(f);
    uint r = (u + 0x7fff + ((u >> 16) & 1)) >> 16;
    return (ushort)r;
}

DI float bf2f(ushort u) { return __uint_as_float((uint)u << 16); }

DI uint pack2(float a, float b) {
    return (uint)f2bf(a) | ((uint)f2bf(b) << 16);
}

DI void gload16(const void* g, void* l) {
    __builtin_amdgcn_global_load_lds(
        (const __attribute__((address_space(1))) void*)g,
        (__attribute__((address_space(3))) void*)l, 16, 0, 0);
}

// ---------------------------------------------------------------------------
// KPREP_X: NCHW f32 -> NHWC bf16 ([b][px][ci])  (linear, used for x)
// ---------------------------------------------------------------------------
__global__ __launch_bounds__(256) void kprep_x(const float* __restrict__ x,
        ushort* __restrict__ xbf)
{
    int blk = blockIdx.x;
    int b = blk >> 13;
    int rest = blk & 8191;
    int ci0 = (rest & 7) * 32;
    int n0 = (rest >> 3) * 64;
    int t = threadIdx.x;
    __shared__ uint u[16][65];
    int px = t & 63, cig = t >> 6;
    const float* yb = x + (((size_t)(b * 256 + ci0 + cig * 8)) << 16) + n0 + px;
    #pragma unroll
    for (int jj = 0; jj < 4; ++jj) {
        float v0 = yb[((size_t)(jj * 2)) << 16];
        float v1 = yb[((size_t)(jj * 2 + 1)) << 16];
        u[cig * 4 + jj][px] = pack2(v0, v1);
    }
    __syncthreads();
    uint* out32 = (uint*)xbf;
    int pr = t & 15, pg = t >> 4;
    #pragma unroll
    for (int g2 = 0; g2 < 4; ++g2) {
        int ppx = g2 * 16 + pg;
        size_t uidx = (((size_t)(b * 65536 + n0 + ppx) * 256 + ci0) >> 1) + pr;
        out32[uidx] = u[pr][ppx];
    }
}

// ---------------------------------------------------------------------------
// KPREP_QK: Wqkb[64][256] = bf16( rows 0-31: wq, rows 32-63: wk )
// ---------------------------------------------------------------------------
__global__ __launch_bounds__(256) void kprep_qk(const float* __restrict__ wq,
        const float* __restrict__ wk, ushort* __restrict__ Wqkb)
{
    int idx = blockIdx.x * 256 + threadIdx.x;   // 16384
    int oc = idx >> 8, ci = idx & 255;
    float v = (oc < 32) ? wq[oc * 256 + ci] : wk[(oc - 32) * 256 + ci];
    Wqkb[idx] = f2bf(v);
}

// ---------------------------------------------------------------------------
// K1 (MFMA): Q,K = 1x1 conv (32 ch each) + per-pixel channel L2-norm.
// ---------------------------------------------------------------------------
__global__ __launch_bounds__(512, 1) void k1_mfma(
        const ushort* __restrict__ xbf, const ushort* __restrict__ Wqkb,
        const float* __restrict__ bq, const float* __restrict__ bk,
        float* __restrict__ Qo, float* __restrict__ Ko)
{
    int blk = blockIdx.x;
    int b = blk >> 9;
    int px0 = (blk & 511) << 7;
    int t = threadIdx.x;
    int lane = t & 63, w = t >> 6;
    int wr = w >> 2;       // 0: q rows, 1: k rows
    int wc = w & 3;        // px quarter (32 px)

    __shared__ ushort sW[64 * 256];    // 32KB [oc][ci] swizzled
    __shared__ ushort sX[128 * 256];   // 64KB [px][ci] swizzled

    #pragma unroll
    for (int p = 0; p < 4; ++p) {
        int m = p * 512 + t;
        int row = m >> 5, ch = m & 31;
        const ushort* g = Wqkb + row * 256 + ((ch ^ (row & 7)) << 3);
        gload16(g, (char*)sW + p * 8192 + w * 1024);
    }
    const ushort* xb = xbf + (size_t)(b * 65536 + px0) * 256;
    #pragma unroll
    for (int p = 0; p < 8; ++p) {
        int m = p * 512 + t;
        int row = m >> 5, ch = m & 31;
        const ushort* g = xb + row * 256 + ((ch ^ (row & 7)) << 3);
        gload16(g, (char*)sX + p * 8192 + w * 1024);
    }
    __syncthreads();

    int l15 = lane & 15, l4 = lane >> 4;
    floatx4 acc[2][2];
    #pragma unroll
    for (int m2 = 0; m2 < 2; ++m2)
        #pragma unroll
        for (int n2 = 0; n2 < 2; ++n2)
            acc[m2][n2] = {0.f, 0.f, 0.f, 0.f};

    #pragma unroll
    for (int ks = 0; ks < 8; ++ks) {
        int cidx = ks * 4 + l4;
        short8 af[2];
        #pragma unroll
        for (int m2 = 0; m2 < 2; ++m2) {
            int row = wr * 32 + m2 * 16 + l15;
            af[m2] = *(const short8*)((const char*)sW + row * 512 + ((cidx ^ (row & 7)) << 4));
        }
        #pragma unroll
        for (int n2 = 0; n2 < 2; ++n2) {
            int row = wc * 32 + n2 * 16 + l15;
            short8 bf_ = *(const short8*)((const char*)sX + row * 512 + ((cidx ^ (row & 7)) << 4));
            #pragma unroll
            for (int m2 = 0; m2 < 2; ++m2)
                acc[m2][n2] = __builtin_amdgcn_mfma_f32_16x16x32_bf16(af[m2], bf_, acc[m2][n2], 0, 0, 0);
        }
    }

    const float* bias = wr ? bk : bq;
    float* outp = wr ? Ko : Qo;
    float bb[2][4];
    #pragma unroll
    for (int m2 = 0; m2 < 2; ++m2)
        #pragma unroll
        for (int r = 0; r < 4; ++r)
            bb[m2][r] = bias[m2 * 16 + l4 * 4 + r];

    #pragma unroll
    for (int n2 = 0; n2 < 2; ++n2) {
        float v[2][4];
        float s = 0.f;
        #pragma unroll
        for (int m2 = 0; m2 < 2; ++m2)
            #pragma unroll
            for (int r = 0; r < 4; ++r) {
                float vv = acc[m2][n2][r] + bb[m2][r];
                v[m2][r] = vv;
                s += vv * vv;
            }
        s += __shfl_xor(s, 16);
        s += __shfl_xor(s, 32);
        float rn = rsqrtf(s);
        int px = px0 + wc * 32 + n2 * 16 + l15;
        #pragma unroll
        for (int m2 = 0; m2 < 2; ++m2)
            #pragma unroll
            for (int r = 0; r < 4; ++r) {
                int oc = m2 * 16 + l4 * 4 + r;
                outp[((size_t)(b * 32 + oc) << 16) + px] = v[m2][r] * rn;
            }
    }
}

// ---------------------------------------------------------------------------
// K2: partial KX/xsum/Ksum per block (atomic-free). 1024 blocks, 128 px each.
// ---------------------------------------------------------------------------
__global__ __launch_bounds__(256) void k2_kx(const float* __restrict__ x,
        const float* __restrict__ Kn, float* __restrict__ KXp,
        float* __restrict__ xsp, float* __restrict__ ksp)
{
    int blk = blockIdx.x;
    int b = blk >> 9;
    int blkl = blk & 511;
    int t = threadIdx.x;
    int pxl = t & 63, g = t >> 6;
    __shared__ float xT[256][65];
    __shared__ float kT[32][64];
    float acc[32];
    #pragma unroll
    for (int m = 0; m < 32; ++m) acc[m] = 0.f;
    float xs = 0.f, ks = 0.f;
    for (int i = 0; i < 2; ++i) {
        int n0 = (blkl * 2 + i) * 64;
        __syncthreads();
        for (int j = 0; j < 64; ++j) {
            int c = j * 4 + g;
            xT[c][pxl] = x[(size_t)(b * 256 + c) * Nc + n0 + pxl];
        }
        #pragma unroll
        for (int j = 0; j < 8; ++j) {
            int m = j * 4 + g;
            kT[m][pxl] = Kn[((size_t)b * 32 + m) * Nc + n0 + pxl];
        }
        __syncthreads();
        for (int p4 = 0; p4 < 16; ++p4) {
            float x0 = xT[t][p4 * 4 + 0];
            float x1 = xT[t][p4 * 4 + 1];
            float x2 = xT[t][p4 * 4 + 2];
            float x3 = xT[t][p4 * 4 + 3];
            xs += x0 + x1 + x2 + x3;
            #pragma unroll
            for (int m = 0; m < 32; ++m) {
                floatx4 kv = *(const floatx4*)&kT[m][p4 * 4];
                acc[m] += kv[0] * x0 + kv[1] * x1 + kv[2] * x2 + kv[3] * x3;
            }
        }
        if (t < 32) {
            for (int p = 0; p < 64; ++p) ks += kT[t][p];
        }
    }
    xsp[blk * 256 + t] = xs;
    if (t < 32) ksp[blk * 32 + t] = ks;
    #pragma unroll
    for (int m = 0; m < 32; ++m) KXp[(size_t)blk * 8192 + m * 256 + t] = acc[m];
}

// ---------------------------------------------------------------------------
// K2R: reduce partials -> KX, xsum, Ksum
// ---------------------------------------------------------------------------
__global__ __launch_bounds__(256) void k2r(const float* __restrict__ KXp,
        const float* __restrict__ xsp, const float* __restrict__ ksp,
        float* __restrict__ KX, float* __restrict__ xsum, float* __restrict__ Ksum)
{
    int blk = blockIdx.x, t = threadIdx.x;
    if (blk < 64) {
        int gidx = blk * 256 + t;
        int b = gidx >> 13, idx = gidx & 8191;
        float s = 0.f;
        for (int ch = 0; ch < 512; ++ch)
            s += KXp[(size_t)((b << 9) + ch) * 8192 + idx];
        KX[gidx] = s;
    } else if (blk < 66) {
        int b = blk - 64;
        float s = 0.f;
        for (int ch = 0; ch < 512; ++ch)
            s += xsp[((b << 9) + ch) * 256 + t];
        xsum[b * 256 + t] = s;
    } else {
        int b = blk - 66;
        if (t < 32) {
            float s = 0.f;
            for (int ch = 0; ch < 512; ++ch)
                s += ksp[((b << 9) + ch) * 32 + t];
            Ksum[b * 32 + t] = s;
        }
    }
}

// ---------------------------------------------------------------------------
// K3: matrix/vsum from KX, xsum, Ksum
// ---------------------------------------------------------------------------
__global__ __launch_bounds__(256) void k3_mat(const float* __restrict__ wv,
        const float* __restrict__ bv, const float* __restrict__ KX,
        const float* __restrict__ xsum, const float* __restrict__ Ksum,
        float* __restrict__ matrix, float* __restrict__ vsum)
{
    int b = blockIdx.x, t = threadIdx.x;
    __shared__ float sx[256];
    __shared__ float sk[32];
    __shared__ float skx[32][256];
    __shared__ float wT[256][65];
    sx[t] = xsum[b * 256 + t];
    if (t < 32) sk[t] = Ksum[b * 32 + t];
    for (int j = 0; j < 32; ++j) skx[j][t] = KX[(b * 32 + j) * 256 + t];
    float vs = bv[t] * (float)Nc;
    float mv[32];
    #pragma unroll
    for (int m = 0; m < 32; ++m) mv[m] = 0.f;
    for (int cc0 = 0; cc0 < 256; cc0 += 64) {
        __syncthreads();
        for (int i = 0; i < 64; ++i) {
            int c = i * 4 + (t >> 6);
            wT[c][t & 63] = wv[(size_t)c * 256 + cc0 + (t & 63)];
        }
        __syncthreads();
        for (int ccl = 0; ccl < 64; ++ccl) {
            float w = wT[t][ccl];
            int cc = cc0 + ccl;
            vs += w * sx[cc];
            #pragma unroll
            for (int m = 0; m < 32; ++m) mv[m] += w * skx[m][cc];
        }
    }
    vsum[b * 256 + t] = vs;
    float bvt = bv[t];
    for (int m = 0; m < 32; ++m) matrix[(b * 32 + m) * 256 + t] = mv[m] + bvt * sk[m];
}

// ---------------------------------------------------------------------------
// K4: z = x + gamma*(vsum + Q^T matrix)*tailor -> DIRECTLY as bf16 NHWC,
// pre-swizzled in memory (chunk ^= px&7) so k6 can stage it linearly.
// ---------------------------------------------------------------------------
__global__ __launch_bounds__(256) void k4_z(const float* __restrict__ x,
        const float* __restrict__ Q, const float* __restrict__ matrix,
        const float* __restrict__ vsum, const float* __restrict__ Ksum,
        const float* __restrict__ gamma_p, ushort* __restrict__ zbf)
{
    int b = blockIdx.x >> 10;
    int n0 = (blockIdx.x & 1023) * 64;
    int t = threadIdx.x;
    int px = t & 63, g = t >> 6;
    __shared__ float qT[32][64];
    __shared__ float mat[32][256];
    __shared__ float vs[256];
    __shared__ float tail[64];
    __shared__ float sk[32];
    __shared__ uint zsh[64 * 128];   // [px][cp] bf16 pairs, swizzled (32KB)
    #pragma unroll
    for (int j = 0; j < 8; ++j) {
        int m = j * 4 + g;
        qT[m][px] = Q[((size_t)b * 32 + m) * Nc + n0 + px];
    }
    for (int j = 0; j < 32; ++j) {
        int idx = j * 256 + t;
        (&mat[0][0])[idx] = matrix[b * 8192 + idx];
    }
    vs[t] = vsum[b * 256 + t];
    if (t < 32) sk[t] = Ksum[b * 32 + t] + LA_EPS;
    __syncthreads();
    if (t < 64) {
        float s = 0.f;
        #pragma unroll
        for (int m = 0; m < 32; ++m) s += qT[m][t] * sk[m];
        tail[t] = 1.0f / ((float)Nc + s);
    }
    __syncthreads();
    float gamma = gamma_p[0];
    float tl = tail[px];
    for (int l = 0; l < 64; l += 2) {
        int c0 = g * 64 + l;
        float s0 = vs[c0], s1 = vs[c0 + 1];
        #pragma unroll
        for (int m = 0; m < 32; ++m) {
            float qv = qT[m][px];
            s0 += qv * mat[m][c0];
            s1 += qv * mat[m][c0 + 1];
        }
        size_t idx0 = (size_t)(b * 256 + c0) * Nc + n0 + px;
        float z0 = x[idx0] + gamma * s0 * tl;
        float z1 = x[idx0 + Nc] + gamma * s1 * tl;
        int cp = c0 >> 1;
        zsh[(px * 512 + (((cp >> 2) ^ (px & 7)) << 4) + (cp & 3) * 4) >> 2] = pack2(z0, z1);
    }
    __syncthreads();
    const uint4* zl = (const uint4*)zsh;
    uint4* gz = (uint4*)(zbf + (((size_t)(b * 65536 + n0)) << 8));
    #pragma unroll
    for (int i2 = 0; i2 < 8; ++i2)
        gz[i2 * 256 + t] = zl[i2 * 256 + t];
}

// ---------------------------------------------------------------------------
// KPREP_Y: y (NCHW f32) -> ybf (padded NHWC bf16, [b][258][258][256], origin +1)
// ---------------------------------------------------------------------------
__global__ __launch_bounds__(256) void kprep_y(const float* __restrict__ y,
        ushort* __restrict__ ybf)
{
    int blk = blockIdx.x;
    int b = blk >> 13;
    int rest = blk & 8191;
    int ci0 = (rest & 7) * 32;
    int n0 = (rest >> 3) * 64;
    int row = n0 >> 8, x = n0 & 255;
    int t = threadIdx.x;
    __shared__ uint u[16][65];
    int px = t & 63, cig = t >> 6;
    const float* yb = y + (((size_t)(b * 256 + ci0 + cig * 8)) << 16) + n0 + px;
    #pragma unroll
    for (int jj = 0; jj < 4; ++jj) {
        float v0 = yb[((size_t)(jj * 2)) << 16];
        float v1 = yb[((size_t)(jj * 2 + 1)) << 16];
        u[cig * 4 + jj][px] = pack2(v0, v1);
    }
    __syncthreads();
    uint* out32 = (uint*)ybf;
    size_t pbase = (size_t)(row + 1) * 258 + (x + 1);
    int pr = t & 15, pg = t >> 4;
    #pragma unroll
    for (int g2 = 0; g2 < 4; ++g2) {
        int ppx = g2 * 16 + pg;
        size_t uidx = (((size_t)b * 258 * 258 * 256 + (pbase + ppx) * 256 + ci0) >> 1) + pr;
        out32[uidx] = u[pr][ppx];
    }
}

// ---------------------------------------------------------------------------
// KPREP_W: Wb[tap][co][ci] = bf16(wl1*s1 + (tap==4)*wl2*s2)
// ---------------------------------------------------------------------------
__global__ __launch_bounds__(256) void kprep_w(const float* __restrict__ wl1,
        const float* __restrict__ s1, const float* __restrict__ wl2,
        const float* __restrict__ s2, ushort* __restrict__ Wb)
{
    int idx = blockIdx.x * 256 + threadIdx.x;
    int tp = idx >> 16;
    int r = idx & 65535;
    int co = r >> 8;
    float v = wl1[(size_t)r * 9 + tp] * s1[co];
    if (tp == 4) v += wl2[r] * s2[co];
    Wb[idx] = f2bf(v);
}

// ---------------------------------------------------------------------------
// KPREP_QW: Wqb = bf16(wqkv), q rows pre-scaled by 0.25
// ---------------------------------------------------------------------------
__global__ __launch_bounds__(256) void kprep_qw(const float* __restrict__ wqkv,
        ushort* __restrict__ Wqb)
{
    int idx = blockIdx.x * 256 + threadIdx.x;
    float v = wqkv[idx];
    if (idx < 65536) v *= 0.25f;
    Wqb[idx] = f2bf(v);
}

// ---------------------------------------------------------------------------
// KPREP_PW / KPREP_REL
// ---------------------------------------------------------------------------
__global__ __launch_bounds__(256) void kprep_pw(const float* __restrict__ wpw,
        ushort* __restrict__ Wpwb)
{
    int idx = blockIdx.x * 256 + threadIdx.x;
    Wpwb[idx] = f2bf(wpw[idx]);
}

__global__ __launch_bounds__(256) void kprep_rel(const float* __restrict__ rel,
        ushort* __restrict__ relbf)
{
    int idx = blockIdx.x * 256 + threadIdx.x;
    if (idx < 3600) relbf[idx] = f2bf(rel[idx]);
}

// ---------------------------------------------------------------------------
// K5 (MFMA): L = conv3x3(ybf, Wc) + bias
// ---------------------------------------------------------------------------
__global__ __launch_bounds__(512, 2) void k5_mfma(
        const ushort* __restrict__ ybf, const ushort* __restrict__ Wb,
        const float* __restrict__ b1, const float* __restrict__ b2,
        float* __restrict__ L)
{
    int blk = blockIdx.x;
    int b = blk >> 9;
    int y0 = (blk >> 1) & 255;
    int x0 = (blk & 1) << 7;
    int t = threadIdx.x;
    int lane = t & 63;
    int w = t >> 6;
    int wr = w >> 1;
    int wc = w & 1;

    __shared__ ushort sW[256 * 64];
    __shared__ ushort sY[128 * 64];

    floatx4 acc[4][4];
    #pragma unroll
    for (int m = 0; m < 4; ++m)
        #pragma unroll
        for (int n = 0; n < 4; ++n)
            acc[m][n] = {0.f, 0.f, 0.f, 0.f};

    const ushort* yb = ybf + (size_t)b * 258 * 258 * 256;
    int ldsWbase = w * 64 * 16;
    int ldsYbase = w * 64 * 16;

    for (int tp = 0; tp < 9; ++tp) {
        int dy = tp / 3 - 1, dx = tp % 3 - 1;
        const ushort* yrow = yb + ((size_t)(y0 + dy + 1) * 258 + (x0 + dx + 1)) * 256;
        const ushort* wtap = Wb + tp * 65536;
        for (int cb = 0; cb < 4; ++cb) {
            int ci0 = cb * 64;
            __syncthreads();
            #pragma unroll
            for (int p = 0; p < 4; ++p) {
                int m = p * 512 + t;
                int row = m >> 3, ch = m & 7;
                const ushort* g = wtap + row * 256 + ci0 + ((ch ^ (row & 7)) << 3);
                gload16(g, (char*)sW + p * 512 * 16 + ldsWbase);
            }
            #pragma unroll
            for (int p = 0; p < 2; ++p) {
                int m = p * 512 + t;
                int pxr = m >> 3, ch = m & 7;
                const ushort* g = yrow + (size_t)pxr * 256 + ci0 + ((ch ^ (pxr & 7)) << 3);
                gload16(g, (char*)sY + p * 512 * 16 + ldsYbase);
            }
            __syncthreads();
            #pragma unroll
            for (int kk = 0; kk < 2; ++kk) {
                int chunkb = kk * 4 + (lane >> 4);
                short8 afr[4];
                #pragma unroll
                for (int m2 = 0; m2 < 4; ++m2) {
                    int row = wr * 64 + m2 * 16 + (lane & 15);
                    int ch = chunkb ^ (row & 7);
                    afr[m2] = *(const short8*)((const char*)sW + row * 128 + ch * 16);
                }
                #pragma unroll
                for (int n2 = 0; n2 < 4; ++n2) {
                    int row = wc * 64 + n2 * 16 + (lane & 15);
                    int ch = chunkb ^ (row & 7);
                    short8 bfr = *(const short8*)((const char*)sY + row * 128 + ch * 16);
                    #pragma unroll
                    for (int m2 = 0; m2 < 4; ++m2)
                        acc[m2][n2] = __builtin_amdgcn_mfma_f32_16x16x32_bf16(
                            afr[m2], bfr, acc[m2][n2], 0, 0, 0);
                }
            }
        }
    }
    int pxb = x0 + wc * 64 + (lane & 15);
    #pragma unroll
    for (int m2 = 0; m2 < 4; ++m2) {
        int cobase = wr * 64 + m2 * 16 + (lane >> 4) * 4;
        #pragma unroll
        for (int r = 0; r < 4; ++r) {
            int co = cobase + r;
            float bias = b1[co] + b2[co];
            float* dst = L + (((size_t)(b * 256 + co)) << 16) + y0 * 256 + pxb;
            #pragma unroll
            for (int n2 = 0; n2 < 4; ++n2)
                dst[n2 * 16] = acc[m2][n2][r] + bias;
        }
    }
}

// ---------------------------------------------------------------------------
// K6 (MFMA, fused): qkv + window attention. TWO adjacent windows per block
// (full 64B A-lines written per block -> no RFO), 8 waves x 2 heads x 2 wins.
// q/k/v fragment transposes in-register (shfl), no per-wave LDS buffers.
// ---------------------------------------------------------------------------
__global__ __launch_bounds__(512, 2) void k6_mfma(const ushort* __restrict__ zbf,
        const ushort* __restrict__ Wqb, const ushort* __restrict__ relbf,
        float* __restrict__ A)
{
    int blk = blockIdx.x;
    int wxp = blk & 15, wy = (blk >> 4) & 31, b = blk >> 9;
    int t = threadIdx.x;
    int lane = t & 63;
    int w = t >> 6;

    __shared__ ushort zT[128 * 256];  // 64KB [row][ci], swizzle baked into memory
    __shared__ ushort srel[3600];     // 7.2KB bf16 rel table

    char* zTc = (char*)zT;
    {
        const ushort* zb = zbf + (((size_t)b) << 16) * 256;
        #pragma unroll
        for (int p = 0; p < 8; ++p) {
            int m = p * 512 + t;
            int row = m >> 5, ch = m & 31;
            int win2 = row >> 6, px = row & 63;
            int gy = wy * 8 + (px >> 3);
            int gx = (wxp * 2 + win2) * 8 + (px & 7);
            const ushort* g = zb + (((size_t)(gy * 256 + gx)) << 8) + ch * 8;
            gload16(g, zTc + p * 8192 + w * 1024);
        }
    }
    for (int i = t; i < 3600; i += 512) srel[i] = relbf[i];
    __syncthreads();

    int l15 = lane & 15, l4 = lane >> 4;
    int l31 = lane & 31, l5 = lane >> 5;
    bool hilane = (l5 != 0);
    bool hi16 = (l31 & 16) != 0;
    int srcA = (l5 << 5) + (l31 & 15);
    int srcB = srcA + 16;

    for (int win = 0; win < 2; ++win) {
        int pxbase = win * 64;

        #pragma unroll
        for (int hrep = 0; hrep < 2; ++hrep) {
            int h = w * 2 + hrep;

            // ---- q-GEMM: D[d][px] = 0.25*Wq_h @ z ----
            floatx4 qacc[4] = {};
            #pragma unroll
            for (int ks = 0; ks < 8; ++ks) {
                short8 aw = *(const short8*)(Wqb + ((h * 16 + l15) << 8) + ks * 32 + (l4 << 3));
                #pragma unroll
                for (int n = 0; n < 4; ++n) {
                    int px = n * 16 + l15;
                    short8 bz = *(const short8*)(zTc + (pxbase + px) * 512 + (((ks * 4 + l4) ^ (px & 7)) << 4));
                    qacc[n] = __builtin_amdgcn_mfma_f32_16x16x32_bf16(aw, bz, qacc[n], 0, 0, 0);
                }
            }
            // reg-transpose -> bq[it]: lane(l31,l5) = q[px=it*32+l31][d=8*l5+e]
            Frag bq[2];
            {
                uint plo[4], phi[4];
                #pragma unroll
                for (int n = 0; n < 4; ++n) {
                    plo[n] = pack2(qacc[n][0], qacc[n][1]);
                    phi[n] = pack2(qacc[n][2], qacc[n][3]);
                }
                #pragma unroll
                for (int it = 0; it < 2; ++it) {
                    uint a0 = (uint)__shfl((int)plo[it * 2], srcA), a1 = (uint)__shfl((int)plo[it * 2 + 1], srcA);
                    uint b0 = (uint)__shfl((int)phi[it * 2], srcA), b1 = (uint)__shfl((int)phi[it * 2 + 1], srcA);
                    uint c0 = (uint)__shfl((int)plo[it * 2], srcB), c1 = (uint)__shfl((int)plo[it * 2 + 1], srcB);
                    uint d0 = (uint)__shfl((int)phi[it * 2], srcB), d1 = (uint)__shfl((int)phi[it * 2 + 1], srcB);
                    bq[it].u[0] = hi16 ? a1 : a0;
                    bq[it].u[1] = hi16 ? b1 : b0;
                    bq[it].u[2] = hi16 ? c1 : c0;
                    bq[it].u[3] = hi16 ? d1 : d0;
                }
            }

            // ---- k-GEMM: D[d][px] = Wk_h @ z ----
            floatx4 kacc[4] = {};
            #pragma unroll
            for (int ks = 0; ks < 8; ++ks) {
                short8 aw = *(const short8*)(Wqb + ((256 + h * 16 + l15) << 8) + ks * 32 + (l4 << 3));
                #pragma unroll
                for (int n = 0; n < 4; ++n) {
                    int px = n * 16 + l15;
                    short8 bz = *(const short8*)(zTc + (pxbase + px) * 512 + (((ks * 4 + l4) ^ (px & 7)) << 4));
                    kacc[n] = __builtin_amdgcn_mfma_f32_16x16x32_bf16(aw, bz, kacc[n], 0, 0, 0);
                }
            }
            Frag ak[2];
            {
                uint plo[4], phi[4];
                #pragma unroll
                for (int n = 0; n < 4; ++n) {
                    plo[n] = pack2(kacc[n][0], kacc[n][1]);
                    phi[n] = pack2(kacc[n][2], kacc[n][3]);
                }
                #pragma unroll
                for (int jt = 0; jt < 2; ++jt) {
                    uint a0 = (uint)__shfl((int)plo[jt * 2], srcA), a1 = (uint)__shfl((int)plo[jt * 2 + 1], srcA);
                    uint b0 = (uint)__shfl((int)phi[jt * 2], srcA), b1 = (uint)__shfl((int)phi[jt * 2 + 1], srcA);
                    uint c0 = (uint)__shfl((int)plo[jt * 2], srcB), c1 = (uint)__shfl((int)plo[jt * 2 + 1], srcB);
                    uint d0 = (uint)__shfl((int)phi[jt * 2], srcB), d1 = (uint)__shfl((int)phi[jt * 2 + 1], srcB);
                    ak[jt].u[0] = hi16 ? a1 : a0;
                    ak[jt].u[1] = hi16 ? b1 : b0;
                    ak[jt].u[2] = hi16 ? c1 : c0;
                    ak[jt].u[3] = hi16 ? d1 : d0;
                }
            }

            // ---- v-GEMM (transposed): D[px][d] = z^T @ Wv_h^T ----
            floatx4 vacc[4] = {};
            #pragma unroll
            for (int ks = 0; ks < 8; ++ks) {
                short8 bw = *(const short8*)(Wqb + ((512 + h * 16 + l15) << 8) + ks * 32 + (l4 << 3));
                #pragma unroll
                for (int m = 0; m < 4; ++m) {
                    int px = m * 16 + l15;
                    short8 az = *(const short8*)(zTc + (pxbase + px) * 512 + (((ks * 4 + l4) ^ (px & 7)) << 4));
                    vacc[m] = __builtin_amdgcn_mfma_f32_16x16x32_bf16(az, bw, vacc[m], 0, 0, 0);
                }
            }
            // reg-transpose -> av[jc]: lane(l31,l5) = V[d=l31&15][j=jc*16+8*l5+e]
            Frag av[4];
            {
                uint v01[4], v23[4];
                #pragma unroll
                for (int m = 0; m < 4; ++m) {
                    v01[m] = pack2(vacc[m][0], vacc[m][1]);
                    v23[m] = pack2(vacc[m][2], vacc[m][3]);
                }
                #pragma unroll
                for (int jc = 0; jc < 4; ++jc) {
                    av[jc].u[0] = (uint)__shfl((int)v01[jc], srcA);
                    av[jc].u[1] = (uint)__shfl((int)v23[jc], srcA);
                    av[jc].u[2] = (uint)__shfl((int)v01[jc], srcB);
                    av[jc].u[3] = (uint)__shfl((int)v23[jc], srcB);
                }
            }

            // ---- per-it: S^T, softmax, PV ----
            #pragma unroll
            for (int it = 0; it < 2; ++it) {
                floatx16 st[2];
                #pragma unroll
                for (int jt = 0; jt < 2; ++jt) {
                    floatx16 zc = {};
                    st[jt] = __builtin_amdgcn_mfma_f32_32x32x16_bf16(ak[jt].v, bq[it].v, zc, 0, 0, 0);
                }
                int i = it * 32 + l31;
                int Ai = (i >> 3) * 15 + (i & 7) + 112;
                float mx = -1e30f;
                #pragma unroll
                for (int jt = 0; jt < 2; ++jt)
                    #pragma unroll
                    for (int r = 0; r < 16; ++r) {
                        int j = jt * 32 + (r & 3) + 8 * (r >> 2) + 4 * l5;
                        int Bjr = (j >> 3) * 15 + (j & 7);
                        float s = st[jt][r] + bf2f(srel[(Ai - Bjr) * 16 + h]);
                        st[jt][r] = s;
                        mx = fmaxf(mx, s);
                    }
                mx = fmaxf(mx, __shfl_xor(mx, 32));
                float sum = 0.f;
                #pragma unroll
                for (int jt = 0; jt < 2; ++jt)
                    #pragma unroll
                    for (int r = 0; r < 16; ++r) {
                        float e = __expf(st[jt][r] - mx);
                        st[jt][r] = e;
                        sum += e;
                    }
                sum += __shfl_xor(sum, 32);
                float rinv = 1.0f / sum;

                floatx16 ot = {};
                #pragma unroll
                for (int jc = 0; jc < 4; ++jc) {
                    int jt = jc >> 1, rb = (jc & 1) * 8;
                    uint u0 = pack2(st[jt][rb + 0], st[jt][rb + 1]);
                    uint u1 = pack2(st[jt][rb + 2], st[jt][rb + 3]);
                    uint u2 = pack2(st[jt][rb + 4], st[jt][rb + 5]);
                    uint u3 = pack2(st[jt][rb + 6], st[jt][rb + 7]);
                    uint s0 = (uint)__shfl_xor((int)u0, 32);
                    uint s1 = (uint)__shfl_xor((int)u1, 32);
                    uint s2 = (uint)__shfl_xor((int)u2, 32);
                    uint s3 = (uint)__shfl_xor((int)u3, 32);
                    Frag bf;
                    bf.u[0] = hilane ? s2 : u0;
                    bf.u[1] = hilane ? s3 : u1;
                    bf.u[2] = hilane ? u2 : s0;
                    bf.u[3] = hilane ? u3 : s1;
                    ot = __builtin_amdgcn_mfma_f32_32x32x16_bf16(av[jc].v, bf.v, ot, 0, 0, 0);
                }
                int gy = wy * 8 + (i >> 3);
                int gx = (wxp * 2 + win) * 8 + (i & 7);
                float* Ab = A + (((size_t)(b * 256 + h * 16)) << 16) + gy * 256 + gx;
                #pragma unroll
                for (int r = 0; r < 8; ++r) {
                    int d = (r & 3) + 8 * (r >> 2) + 4 * l5;
                    Ab[(size_t)d << 16] = ot[r] * rinv;
                }
            }
        }
    }
}

// ---------------------------------------------------------------------------
// K7 (tiled): L += avgpoolV(A) + avgpoolH(A). 64x64 tile + 7-halo in LDS.
// ---------------------------------------------------------------------------
__global__ __launch_bounds__(256) void k7_pool(const float* __restrict__ A,
        float* __restrict__ L)
{
    int blk = blockIdx.x;
    int tile = blk & 15;
    int c = (blk >> 4) & 255;
    int b = blk >> 12;
    int ty = (tile >> 2) * 64, tx = (tile & 3) * 64;
    int t = threadIdx.x;
    __shared__ float aT[71][73];
    const float* Ac = A + ((size_t)(b * 256 + c) << 16);
    for (int i = t; i < 71 * 71; i += 256) {
        int rr = i / 71, cc = i - rr * 71;
        int gy = ty + rr - 3, gx = tx + cc - 3;
        float v = 0.f;
        if (gy >= 0 && gy <= 256 && gx >= 0 && gx <= 256) {
            int ry = (gy == 256) ? 254 : gy;
            int rx = (gx == 256) ? 254 : gx;
            v = Ac[ry * 256 + rx];
        }
        aT[rr][cc] = v;
    }
    __syncthreads();
    int jj = t & 63;
    int oy0 = (t >> 6) * 16;
    float* Lc = L + ((size_t)(b * 256 + c) << 16);
    #pragma unroll 4
    for (int dy = 0; dy < 16; ++dy) {
        int oi = oy0 + dy;
        float sv = 0.f, sh = 0.f;
        #pragma unroll
        for (int u = 0; u < 8; ++u) {
            sv += aT[oi + u][jj + 3];
            sh += aT[oi + 3][jj + u];
        }
        int idx = (ty + oi) * 256 + tx + jj;
        Lc[idx] += 0.125f * (sv + sh);
    }
}

// ---------------------------------------------------------------------------
// K8 (tiled): D(bf16) = sp * dwconv8x8(pad_out(L), wdw, pad=3) + bp
// ---------------------------------------------------------------------------
__global__ __launch_bounds__(256) void k8_dw(const float* __restrict__ P,
        const float* __restrict__ wdw, const float* __restrict__ sp,
        const float* __restrict__ bp, ushort* __restrict__ D)
{
    int blk = blockIdx.x;
    int tile = blk & 63;
    int c = (blk >> 6) & 255;
    int b = blk >> 14;
    int ty = (tile >> 3) * 32, tx = (tile & 7) * 32;
    int t = threadIdx.x;
    __shared__ float pT[39][40];
    __shared__ float wT[64];
    const float* Pc = P + ((size_t)(b * 256 + c) << 16);
    for (int i = t; i < 39 * 40; i += 256) {
        int rr = i / 40, cc = i - rr * 40;
        int gy = ty + rr - 3, gx = tx + cc - 3;
        float v = 0.f;
        if (gy >= 0 && gy <= 256 && gx >= 0 && gx <= 256) {
            int ry = (gy == 256) ? 254 : gy;
            int rx = (gx == 256) ? 254 : gx;
            v = Pc[ry * 256 + rx];
        }
        pT[rr][cc] = v;
    }
    if (t < 64) wT[t] = wdw[c * 64 + t];
    __syncthreads();
    int jj = t & 31;
    int oy0 = (t >> 5) * 4;
    float spc = sp[c], bpc = bp[c];
    ushort* Dc = D + ((size_t)(b * 256 + c) << 16);
    #pragma unroll
    for (int dy = 0; dy < 4; ++dy) {
        int oi = oy0 + dy;
        float acc = 0.f;
        #pragma unroll
        for (int u = 0; u < 8; ++u)
            #pragma unroll
            for (int v = 0; v < 8; ++v)
                acc += wT[u * 8 + v] * pT[oi + u][jj + v];
        Dc[(ty + oi) * 256 + tx + jj] = f2bf(spc * acc + bpc);
    }
}

// ---------------------------------------------------------------------------
// K9 (MFMA): out[co][px] = sum_ci Wpw[co][ci] * D[ci][px]
// ---------------------------------------------------------------------------
__global__ __launch_bounds__(512, 2) void k9_mfma(
        const ushort* __restrict__ D, const ushort* __restrict__ Wpwb,
        float* __restrict__ out)
{
    int blk = blockIdx.x;
    int b = blk >> 9;
    int px0 = (blk & 511) << 7;
    int t = threadIdx.x;
    int lane = t & 63;
    int w = t >> 6;
    int wr = w >> 1, wc = w & 1;

    __shared__ ushort sW[256 * 64];
    __shared__ ushort sD[128 * 64];

    floatx4 acc[4][4];
    #pragma unroll
    for (int m = 0; m < 4; ++m)
        #pragma unroll
        for (int n = 0; n < 4; ++n)
            acc[m][n] = {0.f, 0.f, 0.f, 0.f};

    int ldsWbase = w * 64 * 16;

    for (int cb = 0; cb < 4; ++cb) {
        int ci0 = cb * 64;
        __syncthreads();
        #pragma unroll
        for (int p = 0; p < 4; ++p) {
            int m = p * 512 + t;
            int row = m >> 3, ch = m & 7;
            const ushort* g = Wpwb + row * 256 + ci0 + ((ch ^ (row & 7)) << 3);
            gload16(g, (char*)sW + p * 512 * 16 + ldsWbase);
        }
        #pragma unroll
        for (int p = 0; p < 2; ++p) {
            int m = p * 512 + t;
            int ci = m & 63, pxb = (m >> 6) * 8;
            short8 v = *(const short8*)(D + ((size_t)(b * 256 + ci0 + ci) << 16) + px0 + pxb);
            #pragma unroll
            for (int k2 = 0; k2 < 8; ++k2) {
                int px = pxb + k2;
                *(ushort*)((char*)sD + px * 128 + (((ci >> 3) ^ (px & 7)) << 4) + (ci & 7) * 2) =
                    (ushort)v[k2];
            }
        }
        __syncthreads();
        #pragma unroll
        for (int kk = 0; kk < 2; ++kk) {
            int chunkb = kk * 4 + (lane >> 4);
            short8 afr[4];
            #pragma unroll
            for (int m2 = 0; m2 < 4; ++m2) {
                int row = wr * 64 + m2 * 16 + (lane & 15);
                int ch = chunkb ^ (row & 7);
                afr[m2] = *(const short8*)((const char*)sW + row * 128 + ch * 16);
            }
            #pragma unroll
            for (int n2 = 0; n2 < 4; ++n2) {
                int row = wc * 64 + n2 * 16 + (lane & 15);
                int ch = chunkb ^ (row & 7);
                short8 bfr = *(const short8*)((const char*)sD + row * 128 + ch * 16);
                #pragma unroll
                for (int m2 = 0; m2 < 4; ++m2)
                    acc[m2][n2] = __builtin_amdgcn_mfma_f32_16x16x32_bf16(
                        afr[m2], bfr, acc[m2][n2], 0, 0, 0);
            }
        }
    }
    int pxb = px0 + wc * 64 + (lane & 15);
    #pragma unroll
    for (int m2 = 0; m2 < 4; ++m2) {
        int cobase = wr * 64 + m2 * 16 + (lane >> 4) * 4;
        #pragma unroll
        for (int r = 0; r < 4; ++r) {
            int co = cobase + r;
            float* dst = out + (((size_t)(b * 256 + co)) << 16) + pxb;
            #pragma unroll
            for (int n2 = 0; n2 < 4; ++n2)
                dst[n2 * 16] = acc[m2][n2][r];
        }
    }
}

// ---------------------------------------------------------------------------
extern "C" void kernel_launch(void* const* d_in, const int* in_sizes, int n_in,
                              void* d_out, int out_size, void* d_ws, size_t ws_size,
                              hipStream_t stream)
{
    (void)in_sizes; (void)n_in; (void)out_size; (void)ws_size;
    const float* x     = (const float*)d_in[0];
    const float* y     = (const float*)d_in[1];
    const float* gamma = (const float*)d_in[2];
    const float* la_wq = (const float*)d_in[3];
    const float* la_bq = (const float*)d_in[4];
    const float* la_wk = (const float*)d_in[5];
    const float* la_bk = (const float*)d_in[6];
    const float* la_wv = (const float*)d_in[7];
    const float* la_bv = (const float*)d_in[8];
    const float* wqkv  = (const float*)d_in[9];
    const float* wl1   = (const float*)d_in[10];
    const float* s1    = (const float*)d_in[11];
    const float* b1    = (const float*)d_in[12];
    const float* wl2   = (const float*)d_in[13];
    const float* s2    = (const float*)d_in[14];
    const float* b2    = (const float*)d_in[15];
    const float* rel   = (const float*)d_in[16];
    const float* wdw   = (const float*)d_in[17];
    const float* sp    = (const float*)d_in[18];
    const float* bp    = (const float*)d_in[19];
    const float* wpw   = (const float*)d_in[20];
    float* out = (float*)d_out;

    float* ws = (float*)d_ws;
    float* Q      = ws;                      // 4,194,304 floats (Qo)
    float* Kn     = ws + 4194304;            // 4,194,304 (W-preps alias after k2)
    float* stats  = ws + 8388608;            // 40,960 floats
    float* Ksum   = stats;
    float* xsum   = stats + 64;
    float* KX     = stats + 576;
    float* matrix = stats + 16960;
    float* vsum   = stats + 33344;
    float* A      = ws + 8429568;            // 33,554,432 (ybf alias; attn out; Dbf)
    float* L      = A + 33554432;            // 33,554,432 (phase1 aliases; Lconv)

    // L-region phase-1 aliases (all dead before k5 writes L):
    float* KXp   = L;                        // 1024 x 8192
    float* xsp   = L + 8388608;
    float* ksp   = L + 8650752;
    ushort* xbf  = (ushort*)(L + 8683520);   // x NHWC bf16
    ushort* Wqkb = (ushort*)(L + 25460736);  // 16,384 ushorts

    ushort* Wb    = (ushort*)Kn;             // conv weights, 589,824 bf16
    ushort* Wqb   = (ushort*)Kn + 600064;    // qkv weights, 196,608 bf16
    ushort* Wpwb  = (ushort*)Kn + 798720;    // pw weights, 65,536 bf16
    ushort* relbf = (ushort*)Kn + 864256;    // rel table, 3,600 bf16
    ushort* ybf   = (ushort*)A;              // padded NHWC y — until k6
    ushort* Dbf   = (ushort*)A;              // bf16 dwconv out — after k8
    ushort* zbf   = (ushort*)d_out;          // z bf16 NHWC (pre-swizzled) — k4..k6

    hipMemsetAsync(ybf, 0, (size_t)2 * 258 * 258 * 256 * sizeof(ushort), stream);

    kprep_y  <<<16384, 256, 0, stream>>>(y, ybf);
    kprep_x  <<<16384, 256, 0, stream>>>(x, xbf);
    kprep_qk <<<64,    256, 0, stream>>>(la_wq, la_wk, Wqkb);
    k1_mfma  <<<1024,  512, 0, stream>>>(xbf, Wqkb, la_bq, la_bk, Q, Kn);
    k2_kx    <<<1024,  256, 0, stream>>>(x, Kn, KXp, xsp, ksp);
    kprep_w  <<<2304,  256, 0, stream>>>(wl1, s1, wl2, s2, Wb);  // Kn dead after k2
    kprep_qw <<<768,   256, 0, stream>>>(wqkv, Wqb);
    kprep_pw <<<256,   256, 0, stream>>>(wpw, Wpwb);
    kprep_rel<<<15,    256, 0, stream>>>(rel, relbf);
    k2r      <<<68,    256, 0, stream>>>(KXp, xsp, ksp, KX, xsum, Ksum);
    k3_mat   <<<2,     256, 0, stream>>>(la_wv, la_bv, KX, xsum, Ksum, matrix, vsum);
    k4_z     <<<2048,  256, 0, stream>>>(x, Q, matrix, vsum, Ksum, gamma, zbf);
    k5_mfma  <<<1024,  512, 0, stream>>>(ybf, Wb, b1, b2, L);    // overwrites xbf etc
    k6_mfma  <<<1024,  512, 0, stream>>>(zbf, Wqb, relbf, A);    // overwrites ybf
    k7_pool  <<<8192,  256, 0, stream>>>(A, L);
    k8_dw    <<<32768, 256, 0, stream>>>(L, wdw, sp, bp, Dbf);
    k9_mfma  <<<1024,  512, 0, stream>>>(Dbf, Wpwb, out);
}

// Round 9
// 1482.660 us; speedup vs baseline: 1.2843x; 1.2843x over previous
//
#include <hip/hip_runtime.h>
#include <hip/hip_bf16.h>

#define DI __device__ __forceinline__

constexpr int Bc = 2, Cc = 256, Hc = 256, Wc = 256, Nc = Hc * Wc; // N=65536
constexpr float LA_EPS = 1e-6f;

typedef __attribute__((ext_vector_type(8))) short short8;
typedef __attribute__((ext_vector_type(4))) float floatx4;
typedef __attribute__((ext_vector_type(16))) float floatx16;

union Frag { short8 v; uint u[4]; };

DI ushort f2bf(float f) {
    uint u = __float_as_uint(f);
    uint r = (u + 0x7fff + ((u >> 16) & 1)) >> 16;
    return (ushort)r;
}

DI uint pack2(float a, float b) {
    return (uint)f2bf(a) | ((uint)f2bf(b) << 16);
}

DI void gload16(const void* g, void* l) {
    __builtin_amdgcn_global_load_lds(
        (const __attribute__((address_space(1))) void*)g,
        (__attribute__((address_space(3))) void*)l, 16, 0, 0);
}

// ---------------------------------------------------------------------------
// KPREP_X: NCHW f32 -> NHWC bf16 ([b][px][ci])  (linear, used for x)
// ---------------------------------------------------------------------------
__global__ __launch_bounds__(256) void kprep_x(const float* __restrict__ x,
        ushort* __restrict__ xbf)
{
    int blk = blockIdx.x;
    int b = blk >> 13;
    int rest = blk & 8191;
    int ci0 = (rest & 7) * 32;
    int n0 = (rest >> 3) * 64;
    int t = threadIdx.x;
    __shared__ uint u[16][65];
    int px = t & 63, cig = t >> 6;
    const float* yb = x + (((size_t)(b * 256 + ci0 + cig * 8)) << 16) + n0 + px;
    #pragma unroll
    for (int jj = 0; jj < 4; ++jj) {
        float v0 = yb[((size_t)(jj * 2)) << 16];
        float v1 = yb[((size_t)(jj * 2 + 1)) << 16];
        u[cig * 4 + jj][px] = pack2(v0, v1);
    }
    __syncthreads();
    uint* out32 = (uint*)xbf;
    int pr = t & 15, pg = t >> 4;
    #pragma unroll
    for (int g2 = 0; g2 < 4; ++g2) {
        int ppx = g2 * 16 + pg;
        size_t uidx = (((size_t)(b * 65536 + n0 + ppx) * 256 + ci0) >> 1) + pr;
        out32[uidx] = u[pr][ppx];
    }
}

// ---------------------------------------------------------------------------
// KPREP_QK: Wqkb[64][256] = bf16( rows 0-31: wq, rows 32-63: wk )
// ---------------------------------------------------------------------------
__global__ __launch_bounds__(256) void kprep_qk(const float* __restrict__ wq,
        const float* __restrict__ wk, ushort* __restrict__ Wqkb)
{
    int idx = blockIdx.x * 256 + threadIdx.x;   // 16384
    int oc = idx >> 8, ci = idx & 255;
    float v = (oc < 32) ? wq[oc * 256 + ci] : wk[(oc - 32) * 256 + ci];
    Wqkb[idx] = f2bf(v);
}

// ---------------------------------------------------------------------------
// K1 (MFMA): Q,K = 1x1 conv (32 ch each) + per-pixel channel L2-norm.
// ---------------------------------------------------------------------------
__global__ __launch_bounds__(512, 1) void k1_mfma(
        const ushort* __restrict__ xbf, const ushort* __restrict__ Wqkb,
        const float* __restrict__ bq, const float* __restrict__ bk,
        float* __restrict__ Qo, float* __restrict__ Ko)
{
    int blk = blockIdx.x;
    int b = blk >> 9;
    int px0 = (blk & 511) << 7;
    int t = threadIdx.x;
    int lane = t & 63, w = t >> 6;
    int wr = w >> 2;       // 0: q rows, 1: k rows
    int wc = w & 3;        // px quarter (32 px)

    __shared__ ushort sW[64 * 256];    // 32KB [oc][ci] swizzled
    __shared__ ushort sX[128 * 256];   // 64KB [px][ci] swizzled

    #pragma unroll
    for (int p = 0; p < 4; ++p) {
        int m = p * 512 + t;
        int row = m >> 5, ch = m & 31;
        const ushort* g = Wqkb + row * 256 + ((ch ^ (row & 7)) << 3);
        gload16(g, (char*)sW + p * 8192 + w * 1024);
    }
    const ushort* xb = xbf + (size_t)(b * 65536 + px0) * 256;
    #pragma unroll
    for (int p = 0; p < 8; ++p) {
        int m = p * 512 + t;
        int row = m >> 5, ch = m & 31;
        const ushort* g = xb + row * 256 + ((ch ^ (row & 7)) << 3);
        gload16(g, (char*)sX + p * 8192 + w * 1024);
    }
    __syncthreads();

    int l15 = lane & 15, l4 = lane >> 4;
    floatx4 acc[2][2];
    #pragma unroll
    for (int m2 = 0; m2 < 2; ++m2)
        #pragma unroll
        for (int n2 = 0; n2 < 2; ++n2)
            acc[m2][n2] = {0.f, 0.f, 0.f, 0.f};

    #pragma unroll
    for (int ks = 0; ks < 8; ++ks) {
        int cidx = ks * 4 + l4;
        short8 af[2];
        #pragma unroll
        for (int m2 = 0; m2 < 2; ++m2) {
            int row = wr * 32 + m2 * 16 + l15;
            af[m2] = *(const short8*)((const char*)sW + row * 512 + ((cidx ^ (row & 7)) << 4));
        }
        #pragma unroll
        for (int n2 = 0; n2 < 2; ++n2) {
            int row = wc * 32 + n2 * 16 + l15;
            short8 bf_ = *(const short8*)((const char*)sX + row * 512 + ((cidx ^ (row & 7)) << 4));
            #pragma unroll
            for (int m2 = 0; m2 < 2; ++m2)
                acc[m2][n2] = __builtin_amdgcn_mfma_f32_16x16x32_bf16(af[m2], bf_, acc[m2][n2], 0, 0, 0);
        }
    }

    const float* bias = wr ? bk : bq;
    float* outp = wr ? Ko : Qo;
    float bb[2][4];
    #pragma unroll
    for (int m2 = 0; m2 < 2; ++m2)
        #pragma unroll
        for (int r = 0; r < 4; ++r)
            bb[m2][r] = bias[m2 * 16 + l4 * 4 + r];

    #pragma unroll
    for (int n2 = 0; n2 < 2; ++n2) {
        float v[2][4];
        float s = 0.f;
        #pragma unroll
        for (int m2 = 0; m2 < 2; ++m2)
            #pragma unroll
            for (int r = 0; r < 4; ++r) {
                float vv = acc[m2][n2][r] + bb[m2][r];
                v[m2][r] = vv;
                s += vv * vv;
            }
        s += __shfl_xor(s, 16);
        s += __shfl_xor(s, 32);
        float rn = rsqrtf(s);
        int px = px0 + wc * 32 + n2 * 16 + l15;
        #pragma unroll
        for (int m2 = 0; m2 < 2; ++m2)
            #pragma unroll
            for (int r = 0; r < 4; ++r) {
                int oc = m2 * 16 + l4 * 4 + r;
                outp[((size_t)(b * 32 + oc) << 16) + px] = v[m2][r] * rn;
            }
    }
}

// ---------------------------------------------------------------------------
// K2: partial KX/xsum/Ksum per block (atomic-free). 1024 blocks, 128 px each.
// ---------------------------------------------------------------------------
__global__ __launch_bounds__(256) void k2_kx(const float* __restrict__ x,
        const float* __restrict__ Kn, float* __restrict__ KXp,
        float* __restrict__ xsp, float* __restrict__ ksp)
{
    int blk = blockIdx.x;
    int b = blk >> 9;
    int blkl = blk & 511;
    int t = threadIdx.x;
    int pxl = t & 63, g = t >> 6;
    __shared__ float xT[256][65];
    __shared__ float kT[32][64];
    float acc[32];
    #pragma unroll
    for (int m = 0; m < 32; ++m) acc[m] = 0.f;
    float xs = 0.f, ks = 0.f;
    for (int i = 0; i < 2; ++i) {
        int n0 = (blkl * 2 + i) * 64;
        __syncthreads();
        for (int j = 0; j < 64; ++j) {
            int c = j * 4 + g;
            xT[c][pxl] = x[(size_t)(b * 256 + c) * Nc + n0 + pxl];
        }
        #pragma unroll
        for (int j = 0; j < 8; ++j) {
            int m = j * 4 + g;
            kT[m][pxl] = Kn[((size_t)b * 32 + m) * Nc + n0 + pxl];
        }
        __syncthreads();
        for (int p4 = 0; p4 < 16; ++p4) {
            float x0 = xT[t][p4 * 4 + 0];
            float x1 = xT[t][p4 * 4 + 1];
            float x2 = xT[t][p4 * 4 + 2];
            float x3 = xT[t][p4 * 4 + 3];
            xs += x0 + x1 + x2 + x3;
            #pragma unroll
            for (int m = 0; m < 32; ++m) {
                floatx4 kv = *(const floatx4*)&kT[m][p4 * 4];
                acc[m] += kv[0] * x0 + kv[1] * x1 + kv[2] * x2 + kv[3] * x3;
            }
        }
        if (t < 32) {
            for (int p = 0; p < 64; ++p) ks += kT[t][p];
        }
    }
    xsp[blk * 256 + t] = xs;
    if (t < 32) ksp[blk * 32 + t] = ks;
    #pragma unroll
    for (int m = 0; m < 32; ++m) KXp[(size_t)blk * 8192 + m * 256 + t] = acc[m];
}

// ---------------------------------------------------------------------------
// K2R: reduce partials -> KX, xsum, Ksum
// ---------------------------------------------------------------------------
__global__ __launch_bounds__(256) void k2r(const float* __restrict__ KXp,
        const float* __restrict__ xsp, const float* __restrict__ ksp,
        float* __restrict__ KX, float* __restrict__ xsum, float* __restrict__ Ksum)
{
    int blk = blockIdx.x, t = threadIdx.x;
    if (blk < 64) {
        int gidx = blk * 256 + t;
        int b = gidx >> 13, idx = gidx & 8191;
        float s = 0.f;
        for (int ch = 0; ch < 512; ++ch)
            s += KXp[(size_t)((b << 9) + ch) * 8192 + idx];
        KX[gidx] = s;
    } else if (blk < 66) {
        int b = blk - 64;
        float s = 0.f;
        for (int ch = 0; ch < 512; ++ch)
            s += xsp[((b << 9) + ch) * 256 + t];
        xsum[b * 256 + t] = s;
    } else {
        int b = blk - 66;
        if (t < 32) {
            float s = 0.f;
            for (int ch = 0; ch < 512; ++ch)
                s += ksp[((b << 9) + ch) * 32 + t];
            Ksum[b * 32 + t] = s;
        }
    }
}

// ---------------------------------------------------------------------------
// K3: matrix/vsum from KX, xsum, Ksum
// ---------------------------------------------------------------------------
__global__ __launch_bounds__(256) void k3_mat(const float* __restrict__ wv,
        const float* __restrict__ bv, const float* __restrict__ KX,
        const float* __restrict__ xsum, const float* __restrict__ Ksum,
        float* __restrict__ matrix, float* __restrict__ vsum)
{
    int b = blockIdx.x, t = threadIdx.x;
    __shared__ float sx[256];
    __shared__ float sk[32];
    __shared__ float skx[32][256];
    __shared__ float wT[256][65];
    sx[t] = xsum[b * 256 + t];
    if (t < 32) sk[t] = Ksum[b * 32 + t];
    for (int j = 0; j < 32; ++j) skx[j][t] = KX[(b * 32 + j) * 256 + t];
    float vs = bv[t] * (float)Nc;
    float mv[32];
    #pragma unroll
    for (int m = 0; m < 32; ++m) mv[m] = 0.f;
    for (int cc0 = 0; cc0 < 256; cc0 += 64) {
        __syncthreads();
        for (int i = 0; i < 64; ++i) {
            int c = i * 4 + (t >> 6);
            wT[c][t & 63] = wv[(size_t)c * 256 + cc0 + (t & 63)];
        }
        __syncthreads();
        for (int ccl = 0; ccl < 64; ++ccl) {
            float w = wT[t][ccl];
            int cc = cc0 + ccl;
            vs += w * sx[cc];
            #pragma unroll
            for (int m = 0; m < 32; ++m) mv[m] += w * skx[m][cc];
        }
    }
    vsum[b * 256 + t] = vs;
    float bvt = bv[t];
    for (int m = 0; m < 32; ++m) matrix[(b * 32 + m) * 256 + t] = mv[m] + bvt * sk[m];
}

// ---------------------------------------------------------------------------
// K4: z = x + gamma*(vsum + Q^T matrix)*tailor -> DIRECTLY as bf16 NHWC,
// pre-swizzled in memory (chunk ^= px&7) so k6 can stage it linearly.
// ---------------------------------------------------------------------------
__global__ __launch_bounds__(256) void k4_z(const float* __restrict__ x,
        const float* __restrict__ Q, const float* __restrict__ matrix,
        const float* __restrict__ vsum, const float* __restrict__ Ksum,
        const float* __restrict__ gamma_p, ushort* __restrict__ zbf)
{
    int b = blockIdx.x >> 10;
    int n0 = (blockIdx.x & 1023) * 64;
    int t = threadIdx.x;
    int px = t & 63, g = t >> 6;
    __shared__ float qT[32][64];
    __shared__ float mat[32][256];
    __shared__ float vs[256];
    __shared__ float tail[64];
    __shared__ float sk[32];
    __shared__ uint zsh[64 * 128];   // [px][cp] bf16 pairs, swizzled (32KB)
    #pragma unroll
    for (int j = 0; j < 8; ++j) {
        int m = j * 4 + g;
        qT[m][px] = Q[((size_t)b * 32 + m) * Nc + n0 + px];
    }
    for (int j = 0; j < 32; ++j) {
        int idx = j * 256 + t;
        (&mat[0][0])[idx] = matrix[b * 8192 + idx];
    }
    vs[t] = vsum[b * 256 + t];
    if (t < 32) sk[t] = Ksum[b * 32 + t] + LA_EPS;
    __syncthreads();
    if (t < 64) {
        float s = 0.f;
        #pragma unroll
        for (int m = 0; m < 32; ++m) s += qT[m][t] * sk[m];
        tail[t] = 1.0f / ((float)Nc + s);
    }
    __syncthreads();
    float gamma = gamma_p[0];
    float tl = tail[px];
    for (int l = 0; l < 64; l += 2) {
        int c0 = g * 64 + l;
        float s0 = vs[c0], s1 = vs[c0 + 1];
        #pragma unroll
        for (int m = 0; m < 32; ++m) {
            float qv = qT[m][px];
            s0 += qv * mat[m][c0];
            s1 += qv * mat[m][c0 + 1];
        }
        size_t idx0 = (size_t)(b * 256 + c0) * Nc + n0 + px;
        float z0 = x[idx0] + gamma * s0 * tl;
        float z1 = x[idx0 + Nc] + gamma * s1 * tl;
        int cp = c0 >> 1;
        zsh[(px * 512 + (((cp >> 2) ^ (px & 7)) << 4) + (cp & 3) * 4) >> 2] = pack2(z0, z1);
    }
    __syncthreads();
    const uint4* zl = (const uint4*)zsh;
    uint4* gz = (uint4*)(zbf + (((size_t)(b * 65536 + n0)) << 8));
    #pragma unroll
    for (int i2 = 0; i2 < 8; ++i2)
        gz[i2 * 256 + t] = zl[i2 * 256 + t];
}

// ---------------------------------------------------------------------------
// KPREP_Y: y (NCHW f32) -> ybf (padded NHWC bf16, [b][258][258][256], origin +1)
// ---------------------------------------------------------------------------
__global__ __launch_bounds__(256) void kprep_y(const float* __restrict__ y,
        ushort* __restrict__ ybf)
{
    int blk = blockIdx.x;
    int b = blk >> 13;
    int rest = blk & 8191;
    int ci0 = (rest & 7) * 32;
    int n0 = (rest >> 3) * 64;
    int row = n0 >> 8, x = n0 & 255;
    int t = threadIdx.x;
    __shared__ uint u[16][65];
    int px = t & 63, cig = t >> 6;
    const float* yb = y + (((size_t)(b * 256 + ci0 + cig * 8)) << 16) + n0 + px;
    #pragma unroll
    for (int jj = 0; jj < 4; ++jj) {
        float v0 = yb[((size_t)(jj * 2)) << 16];
        float v1 = yb[((size_t)(jj * 2 + 1)) << 16];
        u[cig * 4 + jj][px] = pack2(v0, v1);
    }
    __syncthreads();
    uint* out32 = (uint*)ybf;
    size_t pbase = (size_t)(row + 1) * 258 + (x + 1);
    int pr = t & 15, pg = t >> 4;
    #pragma unroll
    for (int g2 = 0; g2 < 4; ++g2) {
        int ppx = g2 * 16 + pg;
        size_t uidx = (((size_t)b * 258 * 258 * 256 + (pbase + ppx) * 256 + ci0) >> 1) + pr;
        out32[uidx] = u[pr][ppx];
    }
}

// ---------------------------------------------------------------------------
// KPREP_W: Wb[tap][co][ci] = bf16(wl1*s1 + (tap==4)*wl2*s2)
// ---------------------------------------------------------------------------
__global__ __launch_bounds__(256) void kprep_w(const float* __restrict__ wl1,
        const float* __restrict__ s1, const float* __restrict__ wl2,
        const float* __restrict__ s2, ushort* __restrict__ Wb)
{
    int idx = blockIdx.x * 256 + threadIdx.x;
    int tp = idx >> 16;
    int r = idx & 65535;
    int co = r >> 8;
    float v = wl1[(size_t)r * 9 + tp] * s1[co];
    if (tp == 4) v += wl2[r] * s2[co];
    Wb[idx] = f2bf(v);
}

// ---------------------------------------------------------------------------
// KPREP_QW: Wqb = bf16(wqkv), q rows pre-scaled by 0.25
// ---------------------------------------------------------------------------
__global__ __launch_bounds__(256) void kprep_qw(const float* __restrict__ wqkv,
        ushort* __restrict__ Wqb)
{
    int idx = blockIdx.x * 256 + threadIdx.x;
    float v = wqkv[idx];
    if (idx < 65536) v *= 0.25f;
    Wqb[idx] = f2bf(v);
}

// ---------------------------------------------------------------------------
// KPREP_PW
// ---------------------------------------------------------------------------
__global__ __launch_bounds__(256) void kprep_pw(const float* __restrict__ wpw,
        ushort* __restrict__ Wpwb)
{
    int idx = blockIdx.x * 256 + threadIdx.x;
    Wpwb[idx] = f2bf(wpw[idx]);
}

// ---------------------------------------------------------------------------
// K5 (MFMA): L = conv3x3(ybf, Wc) + bias
// ---------------------------------------------------------------------------
__global__ __launch_bounds__(512, 2) void k5_mfma(
        const ushort* __restrict__ ybf, const ushort* __restrict__ Wb,
        const float* __restrict__ b1, const float* __restrict__ b2,
        float* __restrict__ L)
{
    int blk = blockIdx.x;
    int b = blk >> 9;
    int y0 = (blk >> 1) & 255;
    int x0 = (blk & 1) << 7;
    int t = threadIdx.x;
    int lane = t & 63;
    int w = t >> 6;
    int wr = w >> 1;
    int wc = w & 1;

    __shared__ ushort sW[256 * 64];
    __shared__ ushort sY[128 * 64];

    floatx4 acc[4][4];
    #pragma unroll
    for (int m = 0; m < 4; ++m)
        #pragma unroll
        for (int n = 0; n < 4; ++n)
            acc[m][n] = {0.f, 0.f, 0.f, 0.f};

    const ushort* yb = ybf + (size_t)b * 258 * 258 * 256;
    int ldsWbase = w * 64 * 16;
    int ldsYbase = w * 64 * 16;

    for (int tp = 0; tp < 9; ++tp) {
        int dy = tp / 3 - 1, dx = tp % 3 - 1;
        const ushort* yrow = yb + ((size_t)(y0 + dy + 1) * 258 + (x0 + dx + 1)) * 256;
        const ushort* wtap = Wb + tp * 65536;
        for (int cb = 0; cb < 4; ++cb) {
            int ci0 = cb * 64;
            __syncthreads();
            #pragma unroll
            for (int p = 0; p < 4; ++p) {
                int m = p * 512 + t;
                int row = m >> 3, ch = m & 7;
                const ushort* g = wtap + row * 256 + ci0 + ((ch ^ (row & 7)) << 3);
                gload16(g, (char*)sW + p * 512 * 16 + ldsWbase);
            }
            #pragma unroll
            for (int p = 0; p < 2; ++p) {
                int m = p * 512 + t;
                int pxr = m >> 3, ch = m & 7;
                const ushort* g = yrow + (size_t)pxr * 256 + ci0 + ((ch ^ (pxr & 7)) << 3);
                gload16(g, (char*)sY + p * 512 * 16 + ldsYbase);
            }
            __syncthreads();
            #pragma unroll
            for (int kk = 0; kk < 2; ++kk) {
                int chunkb = kk * 4 + (lane >> 4);
                short8 afr[4];
                #pragma unroll
                for (int m2 = 0; m2 < 4; ++m2) {
                    int row = wr * 64 + m2 * 16 + (lane & 15);
                    int ch = chunkb ^ (row & 7);
                    afr[m2] = *(const short8*)((const char*)sW + row * 128 + ch * 16);
                }
                #pragma unroll
                for (int n2 = 0; n2 < 4; ++n2) {
                    int row = wc * 64 + n2 * 16 + (lane & 15);
                    int ch = chunkb ^ (row & 7);
                    short8 bfr = *(const short8*)((const char*)sY + row * 128 + ch * 16);
                    #pragma unroll
                    for (int m2 = 0; m2 < 4; ++m2)
                        acc[m2][n2] = __builtin_amdgcn_mfma_f32_16x16x32_bf16(
                            afr[m2], bfr, acc[m2][n2], 0, 0, 0);
                }
            }
        }
    }
    int pxb = x0 + wc * 64 + (lane & 15);
    #pragma unroll
    for (int m2 = 0; m2 < 4; ++m2) {
        int cobase = wr * 64 + m2 * 16 + (lane >> 4) * 4;
        #pragma unroll
        for (int r = 0; r < 4; ++r) {
            int co = cobase + r;
            float bias = b1[co] + b2[co];
            float* dst = L + (((size_t)(b * 256 + co)) << 16) + y0 * 256 + pxb;
            #pragma unroll
            for (int n2 = 0; n2 < 4; ++n2)
                dst[n2 * 16] = acc[m2][n2][r] + bias;
        }
    }
}

// ---------------------------------------------------------------------------
// K6 (MFMA, fused): qkv + window attention, TWO adjacent windows per block.
// Waves 0-3 -> win0, waves 4-7 -> win1 (4 heads each): both 32B halves of
// every 64B A-line are written CONCURRENTLY by the same block -> clean
// full-line writebacks (round-6 verified schedule, 287 us / 131 MB write).
// zbf is pre-swizzled by k4 -> linear global_load_lds staging.
// ---------------------------------------------------------------------------
__global__ __launch_bounds__(512, 1) void k6_mfma(const ushort* __restrict__ zbf,
        const ushort* __restrict__ Wqb, const float* __restrict__ rel,
        float* __restrict__ A)
{
    int blk = blockIdx.x;
    int wxp = blk & 15, wy = (blk >> 4) & 31, b = blk >> 9;
    int t = threadIdx.x;
    int lane = t & 63;
    int w = t >> 6;
    int win = w >> 2;
    int wq4 = w & 3;

    __shared__ ushort zT[128 * 256];     // [pxg][ci] bf16, swizzle baked in mem (64 KB)
    __shared__ float srel[3600];         // rel bias table (14.4 KB)
    __shared__ ushort wbuf[8][4096];     // per-wave: qT / kT / vD

    char* zTc = (char*)zT;

    // ---- stage both z windows via linear global_load_lds (zbf pre-swizzled) ----
    {
        const ushort* zb = zbf + (((size_t)b) << 16) * 256;
        #pragma unroll
        for (int p = 0; p < 8; ++p) {
            int m = p * 512 + t;
            int row = m >> 5, ch = m & 31;
            int win2 = row >> 6, px = row & 63;
            int gy = wy * 8 + (px >> 3);
            int gx = (wxp * 2 + win2) * 8 + (px & 7);
            const ushort* g = zb + (((size_t)(gy * 256 + gx)) << 8) + ch * 8;
            gload16(g, zTc + p * 8192 + w * 1024);
        }
    }
    for (int i = t; i < 3600; i += 512) srel[i] = rel[i];
    __syncthreads();

    char* qTb = (char*)&wbuf[w][0];
    char* kTb = (char*)&wbuf[w][1024];
    char* vDb = (char*)&wbuf[w][2048];

    int l15 = lane & 15, l4 = lane >> 4;
    int l31 = lane & 31, l5 = lane >> 5;
    bool hilane = (l5 != 0);
    int pxbase = win * 64;

    for (int hrep = 0; hrep < 4; ++hrep) {
        int h = wq4 * 4 + hrep;

        // ---- q-GEMM: D[d][px] = 0.25*Wq_h @ z ----
        floatx4 qacc[4] = {};
        #pragma unroll
        for (int ks = 0; ks < 8; ++ks) {
            short8 aw = *(const short8*)(Wqb + ((h * 16 + l15) << 8) + ks * 32 + (l4 << 3));
            #pragma unroll
            for (int n = 0; n < 4; ++n) {
                int px = n * 16 + l15;
                short8 bz = *(const short8*)(zTc + (pxbase + px) * 512 + (((ks * 4 + l4) ^ (px & 7)) << 4));
                qacc[n] = __builtin_amdgcn_mfma_f32_16x16x32_bf16(aw, bz, qacc[n], 0, 0, 0);
            }
        }
        #pragma unroll
        for (int n = 0; n < 4; ++n) {
            int px = n * 16 + l15;
            uint2 wv = { pack2(qacc[n][0], qacc[n][1]), pack2(qacc[n][2], qacc[n][3]) };
            *(uint2*)(qTb + px * 32 + (l4 << 3)) = wv;
        }

        // ---- kT-GEMM ----
        floatx4 kacc[4] = {};
        #pragma unroll
        for (int ks = 0; ks < 8; ++ks) {
            short8 bw = *(const short8*)(Wqb + ((256 + h * 16 + l15) << 8) + ks * 32 + (l4 << 3));
            #pragma unroll
            for (int m = 0; m < 4; ++m) {
                int px = m * 16 + l15;
                short8 az = *(const short8*)(zTc + (pxbase + px) * 512 + (((ks * 4 + l4) ^ (px & 7)) << 4));
                kacc[m] = __builtin_amdgcn_mfma_f32_16x16x32_bf16(az, bw, kacc[m], 0, 0, 0);
            }
        }
        #pragma unroll
        for (int m = 0; m < 4; ++m) {
            #pragma unroll
            for (int r = 0; r < 4; ++r) {
                int px = m * 16 + l4 * 4 + r;
                *(ushort*)(kTb + px * 32 + l15 * 2) = f2bf(kacc[m][r]);
            }
        }

        // ---- v-GEMM ----
        floatx4 vacc[4] = {};
        #pragma unroll
        for (int ks = 0; ks < 8; ++ks) {
            short8 aw = *(const short8*)(Wqb + ((512 + h * 16 + l15) << 8) + ks * 32 + (l4 << 3));
            #pragma unroll
            for (int n = 0; n < 4; ++n) {
                int px = n * 16 + l15;
                short8 bz = *(const short8*)(zTc + (pxbase + px) * 512 + (((ks * 4 + l4) ^ (px & 7)) << 4));
                vacc[n] = __builtin_amdgcn_mfma_f32_16x16x32_bf16(aw, bz, vacc[n], 0, 0, 0);
            }
        }
        #pragma unroll
        for (int n = 0; n < 4; ++n) {
            int px = n * 16 + l15;
            #pragma unroll
            for (int r = 0; r < 4; ++r) {
                int d = l4 * 4 + r;
                *(ushort*)(vDb + d * 128 + ((((px >> 3) ^ (d & 7)) << 4) + (px & 7) * 2)) = f2bf(vacc[n][r]);
            }
        }

        // ---- per-it: S^T, softmax, PV ----
        #pragma unroll
        for (int it = 0; it < 2; ++it) {
            short8 bq_ = *(const short8*)(qTb + (it * 32 + l31) * 32 + (l5 << 4));
            floatx16 st[2];
            #pragma unroll
            for (int jt = 0; jt < 2; ++jt) {
                short8 ak = *(const short8*)(kTb + (jt * 32 + l31) * 32 + (l5 << 4));
                floatx16 zc = {};
                st[jt] = __builtin_amdgcn_mfma_f32_32x32x16_bf16(ak, bq_, zc, 0, 0, 0);
            }
            int i = it * 32 + l31;
            int Ai = (i >> 3) * 15 + (i & 7) + 112;
            float mx = -1e30f;
            #pragma unroll
            for (int jt = 0; jt < 2; ++jt)
                #pragma unroll
                for (int r = 0; r < 16; ++r) {
                    int j = jt * 32 + (r & 3) + 8 * (r >> 2) + 4 * l5;
                    int Bjr = (j >> 3) * 15 + (j & 7);
                    float s = st[jt][r] + srel[(Ai - Bjr) * 16 + h];
                    st[jt][r] = s;
                    mx = fmaxf(mx, s);
                }
            mx = fmaxf(mx, __shfl_xor(mx, 32));
            float sum = 0.f;
            #pragma unroll
            for (int jt = 0; jt < 2; ++jt)
                #pragma unroll
                for (int r = 0; r < 16; ++r) {
                    float e = __expf(st[jt][r] - mx);
                    st[jt][r] = e;
                    sum += e;
                }
            sum += __shfl_xor(sum, 32);
            float rinv = 1.0f / sum;

            floatx16 ot = {};
            #pragma unroll
            for (int jc = 0; jc < 4; ++jc) {
                int jt = jc >> 1, rb = (jc & 1) * 8;
                uint u0 = pack2(st[jt][rb + 0], st[jt][rb + 1]);
                uint u1 = pack2(st[jt][rb + 2], st[jt][rb + 3]);
                uint u2 = pack2(st[jt][rb + 4], st[jt][rb + 5]);
                uint u3 = pack2(st[jt][rb + 6], st[jt][rb + 7]);
                uint s0 = (uint)__shfl_xor((int)u0, 32);
                uint s1 = (uint)__shfl_xor((int)u1, 32);
                uint s2 = (uint)__shfl_xor((int)u2, 32);
                uint s3 = (uint)__shfl_xor((int)u3, 32);
                Frag bf;
                bf.u[0] = hilane ? s2 : u0;
                bf.u[1] = hilane ? s3 : u1;
                bf.u[2] = hilane ? u2 : s0;
                bf.u[3] = hilane ? u3 : s1;
                short8 av = *(const short8*)(vDb + l31 * 128 + (((jc * 2 + l5) ^ (l31 & 7)) << 4));
                ot = __builtin_amdgcn_mfma_f32_32x32x16_bf16(av, bf.v, ot, 0, 0, 0);
            }
            int gy = wy * 8 + (i >> 3);
            int gx = (wxp * 2 + win) * 8 + (i & 7);
            float* Ab = A + (((size_t)(b * 256 + h * 16)) << 16) + gy * 256 + gx;
            #pragma unroll
            for (int r = 0; r < 8; ++r) {
                int d = (r & 3) + 8 * (r >> 2) + 4 * l5;
                Ab[(size_t)d << 16] = ot[r] * rinv;
            }
        }
    }
}

// ---------------------------------------------------------------------------
// K7 (tiled): L += avgpoolV(A) + avgpoolH(A). 64x64 tile + 7-halo in LDS.
// ---------------------------------------------------------------------------
__global__ __launch_bounds__(256) void k7_pool(const float* __restrict__ A,
        float* __restrict__ L)
{
    int blk = blockIdx.x;
    int tile = blk & 15;
    int c = (blk >> 4) & 255;
    int b = blk >> 12;
    int ty = (tile >> 2) * 64, tx = (tile & 3) * 64;
    int t = threadIdx.x;
    __shared__ float aT[71][73];
    const float* Ac = A + ((size_t)(b * 256 + c) << 16);
    for (int i = t; i < 71 * 71; i += 256) {
        int rr = i / 71, cc = i - rr * 71;
        int gy = ty + rr - 3, gx = tx + cc - 3;
        float v = 0.f;
        if (gy >= 0 && gy <= 256 && gx >= 0 && gx <= 256) {
            int ry = (gy == 256) ? 254 : gy;
            int rx = (gx == 256) ? 254 : gx;
            v = Ac[ry * 256 + rx];
        }
        aT[rr][cc] = v;
    }
    __syncthreads();
    int jj = t & 63;
    int oy0 = (t >> 6) * 16;
    float* Lc = L + ((size_t)(b * 256 + c) << 16);
    #pragma unroll 4
    for (int dy = 0; dy < 16; ++dy) {
        int oi = oy0 + dy;
        float sv = 0.f, sh = 0.f;
        #pragma unroll
        for (int u = 0; u < 8; ++u) {
            sv += aT[oi + u][jj + 3];
            sh += aT[oi + 3][jj + u];
        }
        int idx = (ty + oi) * 256 + tx + jj;
        Lc[idx] += 0.125f * (sv + sh);
    }
}

// ---------------------------------------------------------------------------
// K8 (tiled): D(bf16) = sp * dwconv8x8(pad_out(L), wdw, pad=3) + bp
// ---------------------------------------------------------------------------
__global__ __launch_bounds__(256) void k8_dw(const float* __restrict__ P,
        const float* __restrict__ wdw, const float* __restrict__ sp,
        const float* __restrict__ bp, ushort* __restrict__ D)
{
    int blk = blockIdx.x;
    int tile = blk & 63;
    int c = (blk >> 6) & 255;
    int b = blk >> 14;
    int ty = (tile >> 3) * 32, tx = (tile & 7) * 32;
    int t = threadIdx.x;
    __shared__ float pT[39][40];
    __shared__ float wT[64];
    const float* Pc = P + ((size_t)(b * 256 + c) << 16);
    for (int i = t; i < 39 * 40; i += 256) {
        int rr = i / 40, cc = i - rr * 40;
        int gy = ty + rr - 3, gx = tx + cc - 3;
        float v = 0.f;
        if (gy >= 0 && gy <= 256 && gx >= 0 && gx <= 256) {
            int ry = (gy == 256) ? 254 : gy;
            int rx = (gx == 256) ? 254 : gx;
            v = Pc[ry * 256 + rx];
        }
        pT[rr][cc] = v;
    }
    if (t < 64) wT[t] = wdw[c * 64 + t];
    __syncthreads();
    int jj = t & 31;
    int oy0 = (t >> 5) * 4;
    float spc = sp[c], bpc = bp[c];
    ushort* Dc = D + ((size_t)(b * 256 + c) << 16);
    #pragma unroll
    for (int dy = 0; dy < 4; ++dy) {
        int oi = oy0 + dy;
        float acc = 0.f;
        #pragma unroll
        for (int u = 0; u < 8; ++u)
            #pragma unroll
            for (int v = 0; v < 8; ++v)
                acc += wT[u * 8 + v] * pT[oi + u][jj + v];
        Dc[(ty + oi) * 256 + tx + jj] = f2bf(spc * acc + bpc);
    }
}

// ---------------------------------------------------------------------------
// K9 (MFMA): out[co][px] = sum_ci Wpw[co][ci] * D[ci][px]
// ---------------------------------------------------------------------------
__global__ __launch_bounds__(512, 2) void k9_mfma(
        const ushort* __restrict__ D, const ushort* __restrict__ Wpwb,
        float* __restrict__ out)
{
    int blk = blockIdx.x;
    int b = blk >> 9;
    int px0 = (blk & 511) << 7;
    int t = threadIdx.x;
    int lane = t & 63;
    int w = t >> 6;
    int wr = w >> 1, wc = w & 1;

    __shared__ ushort sW[256 * 64];
    __shared__ ushort sD[128 * 64];

    floatx4 acc[4][4];
    #pragma unroll
    for (int m = 0; m < 4; ++m)
        #pragma unroll
        for (int n = 0; n < 4; ++n)
            acc[m][n] = {0.f, 0.f, 0.f, 0.f};

    int ldsWbase = w * 64 * 16;

    for (int cb = 0; cb < 4; ++cb) {
        int ci0 = cb * 64;
        __syncthreads();
        #pragma unroll
        for (int p = 0; p < 4; ++p) {
            int m = p * 512 + t;
            int row = m >> 3, ch = m & 7;
            const ushort* g = Wpwb + row * 256 + ci0 + ((ch ^ (row & 7)) << 3);
            gload16(g, (char*)sW + p * 512 * 16 + ldsWbase);
        }
        #pragma unroll
        for (int p = 0; p < 2; ++p) {
            int m = p * 512 + t;
            int ci = m & 63, pxb = (m >> 6) * 8;
            short8 v = *(const short8*)(D + ((size_t)(b * 256 + ci0 + ci) << 16) + px0 + pxb);
            #pragma unroll
            for (int k2 = 0; k2 < 8; ++k2) {
                int px = pxb + k2;
                *(ushort*)((char*)sD + px * 128 + (((ci >> 3) ^ (px & 7)) << 4) + (ci & 7) * 2) =
                    (ushort)v[k2];
            }
        }
        __syncthreads();
        #pragma unroll
        for (int kk = 0; kk < 2; ++kk) {
            int chunkb = kk * 4 + (lane >> 4);
            short8 afr[4];
            #pragma unroll
            for (int m2 = 0; m2 < 4; ++m2) {
                int row = wr * 64 + m2 * 16 + (lane & 15);
                int ch = chunkb ^ (row & 7);
                afr[m2] = *(const short8*)((const char*)sW + row * 128 + ch * 16);
            }
            #pragma unroll
            for (int n2 = 0; n2 < 4; ++n2) {
                int row = wc * 64 + n2 * 16 + (lane & 15);
                int ch = chunkb ^ (row & 7);
                short8 bfr = *(const short8*)((const char*)sD + row * 128 + ch * 16);
                #pragma unroll
                for (int m2 = 0; m2 < 4; ++m2)
                    acc[m2][n2] = __builtin_amdgcn_mfma_f32_16x16x32_bf16(
                        afr[m2], bfr, acc[m2][n2], 0, 0, 0);
            }
        }
    }
    int pxb = px0 + wc * 64 + (lane & 15);
    #pragma unroll
    for (int m2 = 0; m2 < 4; ++m2) {
        int cobase = wr * 64 + m2 * 16 + (lane >> 4) * 4;
        #pragma unroll
        for (int r = 0; r < 4; ++r) {
            int co = cobase + r;
            float* dst = out + (((size_t)(b * 256 + co)) << 16) + pxb;
            #pragma unroll
            for (int n2 = 0; n2 < 4; ++n2)
                dst[n2 * 16] = acc[m2][n2][r];
        }
    }
}

// ---------------------------------------------------------------------------
extern "C" void kernel_launch(void* const* d_in, const int* in_sizes, int n_in,
                              void* d_out, int out_size, void* d_ws, size_t ws_size,
                              hipStream_t stream)
{
    (void)in_sizes; (void)n_in; (void)out_size; (void)ws_size;
    const float* x     = (const float*)d_in[0];
    const float* y     = (const float*)d_in[1];
    const float* gamma = (const float*)d_in[2];
    const float* la_wq = (const float*)d_in[3];
    const float* la_bq = (const float*)d_in[4];
    const float* la_wk = (const float*)d_in[5];
    const float* la_bk = (const float*)d_in[6];
    const float* la_wv = (const float*)d_in[7];
    const float* la_bv = (const float*)d_in[8];
    const float* wqkv  = (const float*)d_in[9];
    const float* wl1   = (const float*)d_in[10];
    const float* s1    = (const float*)d_in[11];
    const float* b1    = (const float*)d_in[12];
    const float* wl2   = (const float*)d_in[13];
    const float* s2    = (const float*)d_in[14];
    const float* b2    = (const float*)d_in[15];
    const float* rel   = (const float*)d_in[16];
    const float* wdw   = (const float*)d_in[17];
    const float* sp    = (const float*)d_in[18];
    const float* bp    = (const float*)d_in[19];
    const float* wpw   = (const float*)d_in[20];
    float* out = (float*)d_out;

    float* ws = (float*)d_ws;
    float* Q      = ws;                      // 4,194,304 floats (Qo)
    float* Kn     = ws + 4194304;            // 4,194,304 (W-preps alias after k2)
    float* stats  = ws + 8388608;            // 40,960 floats
    float* Ksum   = stats;
    float* xsum   = stats + 64;
    float* KX     = stats + 576;
    float* matrix = stats + 16960;
    float* vsum   = stats + 33344;
    float* A      = ws + 8429568;            // 33,554,432 (ybf alias; attn out; Dbf)
    float* L      = A + 33554432;            // 33,554,432 (phase1 aliases; Lconv)

    // L-region phase-1 aliases (all dead before k5 writes L):
    float* KXp   = L;                        // 1024 x 8192
    float* xsp   = L + 8388608;
    float* ksp   = L + 8650752;
    ushort* xbf  = (ushort*)(L + 8683520);   // x NHWC bf16
    ushort* Wqkb = (ushort*)(L + 25460736);  // 16,384 ushorts

    ushort* Wb    = (ushort*)Kn;             // conv weights, 589,824 bf16
    ushort* Wqb   = (ushort*)Kn + 600064;    // qkv weights, 196,608 bf16
    ushort* Wpwb  = (ushort*)Kn + 798720;    // pw weights, 65,536 bf16
    ushort* ybf   = (ushort*)A;              // padded NHWC y — until k6
    ushort* Dbf   = (ushort*)A;              // bf16 dwconv out — after k8
    ushort* zbf   = (ushort*)d_out;          // z bf16 NHWC (pre-swizzled) — k4..k6

    hipMemsetAsync(ybf, 0, (size_t)2 * 258 * 258 * 256 * sizeof(ushort), stream);

    kprep_y  <<<16384, 256, 0, stream>>>(y, ybf);
    kprep_x  <<<16384, 256, 0, stream>>>(x, xbf);
    kprep_qk <<<64,    256, 0, stream>>>(la_wq, la_wk, Wqkb);
    k1_mfma  <<<1024,  512, 0, stream>>>(xbf, Wqkb, la_bq, la_bk, Q, Kn);
    k2_kx    <<<1024,  256, 0, stream>>>(x, Kn, KXp, xsp, ksp);
    kprep_w  <<<2304,  256, 0, stream>>>(wl1, s1, wl2, s2, Wb);  // Kn dead after k2
    kprep_qw <<<768,   256, 0, stream>>>(wqkv, Wqb);
    kprep_pw <<<256,   256, 0, stream>>>(wpw, Wpwb);
    k2r      <<<68,    256, 0, stream>>>(KXp, xsp, ksp, KX, xsum, Ksum);
    k3_mat   <<<2,     256, 0, stream>>>(la_wv, la_bv, KX, xsum, Ksum, matrix, vsum);
    k4_z     <<<2048,  256, 0, stream>>>(x, Q, matrix, vsum, Ksum, gamma, zbf);
    k5_mfma  <<<1024,  512, 0, stream>>>(ybf, Wb, b1, b2, L);    // overwrites xbf etc
    k6_mfma  <<<1024,  512, 0, stream>>>(zbf, Wqb, rel, A);      // overwrites ybf
    k7_pool  <<<8192,  256, 0, stream>>>(A, L);
    k8_dw    <<<32768, 256, 0, stream>>>(L, wdw, sp, bp, Dbf);
    k9_mfma  <<<1024,  512, 0, stream>>>(Dbf, Wpwb, out);
}

// Round 10
// 1456.254 us; speedup vs baseline: 1.3076x; 1.0181x over previous
//
#include <hip/hip_runtime.h>
#include <hip/hip_bf16.h>

#define DI __device__ __forceinline__

constexpr int Bc = 2, Cc = 256, Hc = 256, Wc = 256, Nc = Hc * Wc; // N=65536
constexpr float LA_EPS = 1e-6f;

typedef __attribute__((ext_vector_type(8))) short short8;
typedef __attribute__((ext_vector_type(4))) float floatx4;
typedef __attribute__((ext_vector_type(16))) float floatx16;

union Frag { short8 v; uint u[4]; };

DI ushort f2bf(float f) {
    uint u = __float_as_uint(f);
    uint r = (u + 0x7fff + ((u >> 16) & 1)) >> 16;
    return (ushort)r;
}

DI uint pack2(float a, float b) {
    return (uint)f2bf(a) | ((uint)f2bf(b) << 16);
}

DI void gload16(const void* g, void* l) {
    __builtin_amdgcn_global_load_lds(
        (const __attribute__((address_space(1))) void*)g,
        (__attribute__((address_space(3))) void*)l, 16, 0, 0);
}

// ---------------------------------------------------------------------------
// KPREP_X: NCHW f32 -> NHWC bf16 ([b][px][ci])  (linear, used for x)
// ---------------------------------------------------------------------------
__global__ __launch_bounds__(256) void kprep_x(const float* __restrict__ x,
        ushort* __restrict__ xbf)
{
    int blk = blockIdx.x;
    int b = blk >> 13;
    int rest = blk & 8191;
    int ci0 = (rest & 7) * 32;
    int n0 = (rest >> 3) * 64;
    int t = threadIdx.x;
    __shared__ uint u[16][65];
    int px = t & 63, cig = t >> 6;
    const float* yb = x + (((size_t)(b * 256 + ci0 + cig * 8)) << 16) + n0 + px;
    #pragma unroll
    for (int jj = 0; jj < 4; ++jj) {
        float v0 = yb[((size_t)(jj * 2)) << 16];
        float v1 = yb[((size_t)(jj * 2 + 1)) << 16];
        u[cig * 4 + jj][px] = pack2(v0, v1);
    }
    __syncthreads();
    uint* out32 = (uint*)xbf;
    int pr = t & 15, pg = t >> 4;
    #pragma unroll
    for (int g2 = 0; g2 < 4; ++g2) {
        int ppx = g2 * 16 + pg;
        size_t uidx = (((size_t)(b * 65536 + n0 + ppx) * 256 + ci0) >> 1) + pr;
        out32[uidx] = u[pr][ppx];
    }
}

// ---------------------------------------------------------------------------
// KPREP_QK: Wqkb[64][256] = bf16( rows 0-31: wq, rows 32-63: wk )
// ---------------------------------------------------------------------------
__global__ __launch_bounds__(256) void kprep_qk(const float* __restrict__ wq,
        const float* __restrict__ wk, ushort* __restrict__ Wqkb)
{
    int idx = blockIdx.x * 256 + threadIdx.x;   // 16384
    int oc = idx >> 8, ci = idx & 255;
    float v = (oc < 32) ? wq[oc * 256 + ci] : wk[(oc - 32) * 256 + ci];
    Wqkb[idx] = f2bf(v);
}

// ---------------------------------------------------------------------------
// K1 (MFMA): Q,K = 1x1 conv (32 ch each) + per-pixel channel L2-norm.
// ---------------------------------------------------------------------------
__global__ __launch_bounds__(512, 1) void k1_mfma(
        const ushort* __restrict__ xbf, const ushort* __restrict__ Wqkb,
        const float* __restrict__ bq, const float* __restrict__ bk,
        float* __restrict__ Qo, float* __restrict__ Ko)
{
    int blk = blockIdx.x;
    int b = blk >> 9;
    int px0 = (blk & 511) << 7;
    int t = threadIdx.x;
    int lane = t & 63, w = t >> 6;
    int wr = w >> 2;       // 0: q rows, 1: k rows
    int wc = w & 3;        // px quarter (32 px)

    __shared__ ushort sW[64 * 256];    // 32KB [oc][ci] swizzled
    __shared__ ushort sX[128 * 256];   // 64KB [px][ci] swizzled

    #pragma unroll
    for (int p = 0; p < 4; ++p) {
        int m = p * 512 + t;
        int row = m >> 5, ch = m & 31;
        const ushort* g = Wqkb + row * 256 + ((ch ^ (row & 7)) << 3);
        gload16(g, (char*)sW + p * 8192 + w * 1024);
    }
    const ushort* xb = xbf + (size_t)(b * 65536 + px0) * 256;
    #pragma unroll
    for (int p = 0; p < 8; ++p) {
        int m = p * 512 + t;
        int row = m >> 5, ch = m & 31;
        const ushort* g = xb + row * 256 + ((ch ^ (row & 7)) << 3);
        gload16(g, (char*)sX + p * 8192 + w * 1024);
    }
    __syncthreads();

    int l15 = lane & 15, l4 = lane >> 4;
    floatx4 acc[2][2];
    #pragma unroll
    for (int m2 = 0; m2 < 2; ++m2)
        #pragma unroll
        for (int n2 = 0; n2 < 2; ++n2)
            acc[m2][n2] = {0.f, 0.f, 0.f, 0.f};

    #pragma unroll
    for (int ks = 0; ks < 8; ++ks) {
        int cidx = ks * 4 + l4;
        short8 af[2];
        #pragma unroll
        for (int m2 = 0; m2 < 2; ++m2) {
            int row = wr * 32 + m2 * 16 + l15;
            af[m2] = *(const short8*)((const char*)sW + row * 512 + ((cidx ^ (row & 7)) << 4));
        }
        #pragma unroll
        for (int n2 = 0; n2 < 2; ++n2) {
            int row = wc * 32 + n2 * 16 + l15;
            short8 bf_ = *(const short8*)((const char*)sX + row * 512 + ((cidx ^ (row & 7)) << 4));
            #pragma unroll
            for (int m2 = 0; m2 < 2; ++m2)
                acc[m2][n2] = __builtin_amdgcn_mfma_f32_16x16x32_bf16(af[m2], bf_, acc[m2][n2], 0, 0, 0);
        }
    }

    const float* bias = wr ? bk : bq;
    float* outp = wr ? Ko : Qo;
    float bb[2][4];
    #pragma unroll
    for (int m2 = 0; m2 < 2; ++m2)
        #pragma unroll
        for (int r = 0; r < 4; ++r)
            bb[m2][r] = bias[m2 * 16 + l4 * 4 + r];

    #pragma unroll
    for (int n2 = 0; n2 < 2; ++n2) {
        float v[2][4];
        float s = 0.f;
        #pragma unroll
        for (int m2 = 0; m2 < 2; ++m2)
            #pragma unroll
            for (int r = 0; r < 4; ++r) {
                float vv = acc[m2][n2][r] + bb[m2][r];
                v[m2][r] = vv;
                s += vv * vv;
            }
        s += __shfl_xor(s, 16);
        s += __shfl_xor(s, 32);
        float rn = rsqrtf(s);
        int px = px0 + wc * 32 + n2 * 16 + l15;
        #pragma unroll
        for (int m2 = 0; m2 < 2; ++m2)
            #pragma unroll
            for (int r = 0; r < 4; ++r) {
                int oc = m2 * 16 + l4 * 4 + r;
                outp[((size_t)(b * 32 + oc) << 16) + px] = v[m2][r] * rn;
            }
    }
}

// ---------------------------------------------------------------------------
// K2: partial KX/xsum/Ksum per block (atomic-free). 1024 blocks, 128 px each.
// ---------------------------------------------------------------------------
__global__ __launch_bounds__(256) void k2_kx(const float* __restrict__ x,
        const float* __restrict__ Kn, float* __restrict__ KXp,
        float* __restrict__ xsp, float* __restrict__ ksp)
{
    int blk = blockIdx.x;
    int b = blk >> 9;
    int blkl = blk & 511;
    int t = threadIdx.x;
    int pxl = t & 63, g = t >> 6;
    __shared__ float xT[256][65];
    __shared__ float kT[32][64];
    float acc[32];
    #pragma unroll
    for (int m = 0; m < 32; ++m) acc[m] = 0.f;
    float xs = 0.f, ks = 0.f;
    for (int i = 0; i < 2; ++i) {
        int n0 = (blkl * 2 + i) * 64;
        __syncthreads();
        for (int j = 0; j < 64; ++j) {
            int c = j * 4 + g;
            xT[c][pxl] = x[(size_t)(b * 256 + c) * Nc + n0 + pxl];
        }
        #pragma unroll
        for (int j = 0; j < 8; ++j) {
            int m = j * 4 + g;
            kT[m][pxl] = Kn[((size_t)b * 32 + m) * Nc + n0 + pxl];
        }
        __syncthreads();
        for (int p4 = 0; p4 < 16; ++p4) {
            float x0 = xT[t][p4 * 4 + 0];
            float x1 = xT[t][p4 * 4 + 1];
            float x2 = xT[t][p4 * 4 + 2];
            float x3 = xT[t][p4 * 4 + 3];
            xs += x0 + x1 + x2 + x3;
            #pragma unroll
            for (int m = 0; m < 32; ++m) {
                floatx4 kv = *(const floatx4*)&kT[m][p4 * 4];
                acc[m] += kv[0] * x0 + kv[1] * x1 + kv[2] * x2 + kv[3] * x3;
            }
        }
        if (t < 32) {
            for (int p = 0; p < 64; ++p) ks += kT[t][p];
        }
    }
    xsp[blk * 256 + t] = xs;
    if (t < 32) ksp[blk * 32 + t] = ks;
    #pragma unroll
    for (int m = 0; m < 32; ++m) KXp[(size_t)blk * 8192 + m * 256 + t] = acc[m];
}

// ---------------------------------------------------------------------------
// K2R: reduce partials -> KX, xsum, Ksum
// ---------------------------------------------------------------------------
__global__ __launch_bounds__(256) void k2r(const float* __restrict__ KXp,
        const float* __restrict__ xsp, const float* __restrict__ ksp,
        float* __restrict__ KX, float* __restrict__ xsum, float* __restrict__ Ksum)
{
    int blk = blockIdx.x, t = threadIdx.x;
    if (blk < 64) {
        int gidx = blk * 256 + t;
        int b = gidx >> 13, idx = gidx & 8191;
        float s = 0.f;
        for (int ch = 0; ch < 512; ++ch)
            s += KXp[(size_t)((b << 9) + ch) * 8192 + idx];
        KX[gidx] = s;
    } else if (blk < 66) {
        int b = blk - 64;
        float s = 0.f;
        for (int ch = 0; ch < 512; ++ch)
            s += xsp[((b << 9) + ch) * 256 + t];
        xsum[b * 256 + t] = s;
    } else {
        int b = blk - 66;
        if (t < 32) {
            float s = 0.f;
            for (int ch = 0; ch < 512; ++ch)
                s += ksp[((b << 9) + ch) * 32 + t];
            Ksum[b * 32 + t] = s;
        }
    }
}

// ---------------------------------------------------------------------------
// K3: matrix/vsum from KX, xsum, Ksum
// ---------------------------------------------------------------------------
__global__ __launch_bounds__(256) void k3_mat(const float* __restrict__ wv,
        const float* __restrict__ bv, const float* __restrict__ KX,
        const float* __restrict__ xsum, const float* __restrict__ Ksum,
        float* __restrict__ matrix, float* __restrict__ vsum)
{
    int b = blockIdx.x, t = threadIdx.x;
    __shared__ float sx[256];
    __shared__ float sk[32];
    __shared__ float skx[32][256];
    __shared__ float wT[256][65];
    sx[t] = xsum[b * 256 + t];
    if (t < 32) sk[t] = Ksum[b * 32 + t];
    for (int j = 0; j < 32; ++j) skx[j][t] = KX[(b * 32 + j) * 256 + t];
    float vs = bv[t] * (float)Nc;
    float mv[32];
    #pragma unroll
    for (int m = 0; m < 32; ++m) mv[m] = 0.f;
    for (int cc0 = 0; cc0 < 256; cc0 += 64) {
        __syncthreads();
        for (int i = 0; i < 64; ++i) {
            int c = i * 4 + (t >> 6);
            wT[c][t & 63] = wv[(size_t)c * 256 + cc0 + (t & 63)];
        }
        __syncthreads();
        for (int ccl = 0; ccl < 64; ++ccl) {
            float w = wT[t][ccl];
            int cc = cc0 + ccl;
            vs += w * sx[cc];
            #pragma unroll
            for (int m = 0; m < 32; ++m) mv[m] += w * skx[m][cc];
        }
    }
    vsum[b * 256 + t] = vs;
    float bvt = bv[t];
    for (int m = 0; m < 32; ++m) matrix[(b * 32 + m) * 256 + t] = mv[m] + bvt * sk[m];
}

// ---------------------------------------------------------------------------
// K4: z = x + gamma*(vsum + Q^T matrix)*tailor -> DIRECTLY as bf16 NHWC,
// pre-swizzled in memory (chunk ^= px&7) so k6 can stage it linearly.
// ---------------------------------------------------------------------------
__global__ __launch_bounds__(256) void k4_z(const float* __restrict__ x,
        const float* __restrict__ Q, const float* __restrict__ matrix,
        const float* __restrict__ vsum, const float* __restrict__ Ksum,
        const float* __restrict__ gamma_p, ushort* __restrict__ zbf)
{
    int b = blockIdx.x >> 10;
    int n0 = (blockIdx.x & 1023) * 64;
    int t = threadIdx.x;
    int px = t & 63, g = t >> 6;
    __shared__ float qT[32][64];
    __shared__ float mat[32][256];
    __shared__ float vs[256];
    __shared__ float tail[64];
    __shared__ float sk[32];
    __shared__ uint zsh[64 * 128];   // [px][cp] bf16 pairs, swizzled (32KB)
    #pragma unroll
    for (int j = 0; j < 8; ++j) {
        int m = j * 4 + g;
        qT[m][px] = Q[((size_t)b * 32 + m) * Nc + n0 + px];
    }
    for (int j = 0; j < 32; ++j) {
        int idx = j * 256 + t;
        (&mat[0][0])[idx] = matrix[b * 8192 + idx];
    }
    vs[t] = vsum[b * 256 + t];
    if (t < 32) sk[t] = Ksum[b * 32 + t] + LA_EPS;
    __syncthreads();
    if (t < 64) {
        float s = 0.f;
        #pragma unroll
        for (int m = 0; m < 32; ++m) s += qT[m][t] * sk[m];
        tail[t] = 1.0f / ((float)Nc + s);
    }
    __syncthreads();
    float gamma = gamma_p[0];
    float tl = tail[px];
    for (int l = 0; l < 64; l += 2) {
        int c0 = g * 64 + l;
        float s0 = vs[c0], s1 = vs[c0 + 1];
        #pragma unroll
        for (int m = 0; m < 32; ++m) {
            float qv = qT[m][px];
            s0 += qv * mat[m][c0];
            s1 += qv * mat[m][c0 + 1];
        }
        size_t idx0 = (size_t)(b * 256 + c0) * Nc + n0 + px;
        float z0 = x[idx0] + gamma * s0 * tl;
        float z1 = x[idx0 + Nc] + gamma * s1 * tl;
        int cp = c0 >> 1;
        zsh[(px * 512 + (((cp >> 2) ^ (px & 7)) << 4) + (cp & 3) * 4) >> 2] = pack2(z0, z1);
    }
    __syncthreads();
    const uint4* zl = (const uint4*)zsh;
    uint4* gz = (uint4*)(zbf + (((size_t)(b * 65536 + n0)) << 8));
    #pragma unroll
    for (int i2 = 0; i2 < 8; ++i2)
        gz[i2 * 256 + t] = zl[i2 * 256 + t];
}

// ---------------------------------------------------------------------------
// KPREP_Y: y (NCHW f32) -> ybf (padded NHWC bf16, [b][258][258][256], origin +1)
// ---------------------------------------------------------------------------
__global__ __launch_bounds__(256) void kprep_y(const float* __restrict__ y,
        ushort* __restrict__ ybf)
{
    int blk = blockIdx.x;
    int b = blk >> 13;
    int rest = blk & 8191;
    int ci0 = (rest & 7) * 32;
    int n0 = (rest >> 3) * 64;
    int row = n0 >> 8, x = n0 & 255;
    int t = threadIdx.x;
    __shared__ uint u[16][65];
    int px = t & 63, cig = t >> 6;
    const float* yb = y + (((size_t)(b * 256 + ci0 + cig * 8)) << 16) + n0 + px;
    #pragma unroll
    for (int jj = 0; jj < 4; ++jj) {
        float v0 = yb[((size_t)(jj * 2)) << 16];
        float v1 = yb[((size_t)(jj * 2 + 1)) << 16];
        u[cig * 4 + jj][px] = pack2(v0, v1);
    }
    __syncthreads();
    uint* out32 = (uint*)ybf;
    size_t pbase = (size_t)(row + 1) * 258 + (x + 1);
    int pr = t & 15, pg = t >> 4;
    #pragma unroll
    for (int g2 = 0; g2 < 4; ++g2) {
        int ppx = g2 * 16 + pg;
        size_t uidx = (((size_t)b * 258 * 258 * 256 + (pbase + ppx) * 256 + ci0) >> 1) + pr;
        out32[uidx] = u[pr][ppx];
    }
}

// ---------------------------------------------------------------------------
// KPREP_W: Wb[tap][co][ci] = bf16(wl1*s1 + (tap==4)*wl2*s2)
// ---------------------------------------------------------------------------
__global__ __launch_bounds__(256) void kprep_w(const float* __restrict__ wl1,
        const float* __restrict__ s1, const float* __restrict__ wl2,
        const float* __restrict__ s2, ushort* __restrict__ Wb)
{
    int idx = blockIdx.x * 256 + threadIdx.x;
    int tp = idx >> 16;
    int r = idx & 65535;
    int co = r >> 8;
    float v = wl1[(size_t)r * 9 + tp] * s1[co];
    if (tp == 4) v += wl2[r] * s2[co];
    Wb[idx] = f2bf(v);
}

// ---------------------------------------------------------------------------
// KPREP_QW: Wqb = bf16(wqkv), q rows pre-scaled by 0.25
// ---------------------------------------------------------------------------
__global__ __launch_bounds__(256) void kprep_qw(const float* __restrict__ wqkv,
        ushort* __restrict__ Wqb)
{
    int idx = blockIdx.x * 256 + threadIdx.x;
    float v = wqkv[idx];
    if (idx < 65536) v *= 0.25f;
    Wqb[idx] = f2bf(v);
}

// ---------------------------------------------------------------------------
// KPREP_PW
// ---------------------------------------------------------------------------
__global__ __launch_bounds__(256) void kprep_pw(const float* __restrict__ wpw,
        ushort* __restrict__ Wpwb)
{
    int idx = blockIdx.x * 256 + threadIdx.x;
    Wpwb[idx] = f2bf(wpw[idx]);
}

// ---------------------------------------------------------------------------
// K5 (MFMA): L = conv3x3(ybf, Wc) + bias
// ---------------------------------------------------------------------------
__global__ __launch_bounds__(512, 2) void k5_mfma(
        const ushort* __restrict__ ybf, const ushort* __restrict__ Wb,
        const float* __restrict__ b1, const float* __restrict__ b2,
        float* __restrict__ L)
{
    int blk = blockIdx.x;
    int b = blk >> 9;
    int y0 = (blk >> 1) & 255;
    int x0 = (blk & 1) << 7;
    int t = threadIdx.x;
    int lane = t & 63;
    int w = t >> 6;
    int wr = w >> 1;
    int wc = w & 1;

    __shared__ ushort sW[256 * 64];
    __shared__ ushort sY[128 * 64];

    floatx4 acc[4][4];
    #pragma unroll
    for (int m = 0; m < 4; ++m)
        #pragma unroll
        for (int n = 0; n < 4; ++n)
            acc[m][n] = {0.f, 0.f, 0.f, 0.f};

    const ushort* yb = ybf + (size_t)b * 258 * 258 * 256;
    int ldsWbase = w * 64 * 16;
    int ldsYbase = w * 64 * 16;

    for (int tp = 0; tp < 9; ++tp) {
        int dy = tp / 3 - 1, dx = tp % 3 - 1;
        const ushort* yrow = yb + ((size_t)(y0 + dy + 1) * 258 + (x0 + dx + 1)) * 256;
        const ushort* wtap = Wb + tp * 65536;
        for (int cb = 0; cb < 4; ++cb) {
            int ci0 = cb * 64;
            __syncthreads();
            #pragma unroll
            for (int p = 0; p < 4; ++p) {
                int m = p * 512 + t;
                int row = m >> 3, ch = m & 7;
                const ushort* g = wtap + row * 256 + ci0 + ((ch ^ (row & 7)) << 3);
                gload16(g, (char*)sW + p * 512 * 16 + ldsWbase);
            }
            #pragma unroll
            for (int p = 0; p < 2; ++p) {
                int m = p * 512 + t;
                int pxr = m >> 3, ch = m & 7;
                const ushort* g = yrow + (size_t)pxr * 256 + ci0 + ((ch ^ (pxr & 7)) << 3);
                gload16(g, (char*)sY + p * 512 * 16 + ldsYbase);
            }
            __syncthreads();
            #pragma unroll
            for (int kk = 0; kk < 2; ++kk) {
                int chunkb = kk * 4 + (lane >> 4);
                short8 afr[4];
                #pragma unroll
                for (int m2 = 0; m2 < 4; ++m2) {
                    int row = wr * 64 + m2 * 16 + (lane & 15);
                    int ch = chunkb ^ (row & 7);
                    afr[m2] = *(const short8*)((const char*)sW + row * 128 + ch * 16);
                }
                #pragma unroll
                for (int n2 = 0; n2 < 4; ++n2) {
                    int row = wc * 64 + n2 * 16 + (lane & 15);
                    int ch = chunkb ^ (row & 7);
                    short8 bfr = *(const short8*)((const char*)sY + row * 128 + ch * 16);
                    #pragma unroll
                    for (int m2 = 0; m2 < 4; ++m2)
                        acc[m2][n2] = __builtin_amdgcn_mfma_f32_16x16x32_bf16(
                            afr[m2], bfr, acc[m2][n2], 0, 0, 0);
                }
            }
        }
    }
    int pxb = x0 + wc * 64 + (lane & 15);
    #pragma unroll
    for (int m2 = 0; m2 < 4; ++m2) {
        int cobase = wr * 64 + m2 * 16 + (lane >> 4) * 4;
        #pragma unroll
        for (int r = 0; r < 4; ++r) {
            int co = cobase + r;
            float bias = b1[co] + b2[co];
            float* dst = L + (((size_t)(b * 256 + co)) << 16) + y0 * 256 + pxb;
            #pragma unroll
            for (int n2 = 0; n2 < 4; ++n2)
                dst[n2 * 16] = acc[m2][n2][r] + bias;
        }
    }
}

// ---------------------------------------------------------------------------
// K6 (MFMA, fused): qkv + window attention, TWO adjacent windows per block.
// Round-9 write schedule (waves 0-3 -> win0, 4-7 -> win1, concurrent halves
// of every 64B A-line) + round-7 in-register shfl transposes (no wbuf).
// LDS 79.9KB -> 2 blocks/CU.
// ---------------------------------------------------------------------------
__global__ __launch_bounds__(512, 2) void k6_mfma(const ushort* __restrict__ zbf,
        const ushort* __restrict__ Wqb, const float* __restrict__ rel,
        float* __restrict__ A)
{
    int blk = blockIdx.x;
    int wxp = blk & 15, wy = (blk >> 4) & 31, b = blk >> 9;
    int t = threadIdx.x;
    int lane = t & 63;
    int w = t >> 6;
    int win = w >> 2;      // waves 0-3: window 0, waves 4-7: window 1
    int wq4 = w & 3;       // 4 heads per wave

    __shared__ ushort zT[128 * 256];     // 64KB, swizzle baked in memory
    __shared__ float srel[3600];         // 14.4KB

    char* zTc = (char*)zT;

    // ---- stage both z windows via linear global_load_lds (zbf pre-swizzled) ----
    {
        const ushort* zb = zbf + (((size_t)b) << 16) * 256;
        #pragma unroll
        for (int p = 0; p < 8; ++p) {
            int m = p * 512 + t;
            int row = m >> 5, ch = m & 31;
            int win2 = row >> 6, px = row & 63;
            int gy = wy * 8 + (px >> 3);
            int gx = (wxp * 2 + win2) * 8 + (px & 7);
            const ushort* g = zb + (((size_t)(gy * 256 + gx)) << 8) + ch * 8;
            gload16(g, zTc + p * 8192 + w * 1024);
        }
    }
    for (int i = t; i < 3600; i += 512) srel[i] = rel[i];
    __syncthreads();

    int l15 = lane & 15, l4 = lane >> 4;
    int l31 = lane & 31, l5 = lane >> 5;
    bool hilane = (l5 != 0);
    bool hi16 = (l31 & 16) != 0;
    int srcA = (l5 << 5) + (l31 & 15);
    int srcB = srcA + 16;
    int pxbase = win * 64;

    for (int hrep = 0; hrep < 4; ++hrep) {
        int h = wq4 * 4 + hrep;

        // ---- q-GEMM: D[d][px] = 0.25*Wq_h @ z ----
        floatx4 qacc[4] = {};
        #pragma unroll
        for (int ks = 0; ks < 8; ++ks) {
            short8 aw = *(const short8*)(Wqb + ((h * 16 + l15) << 8) + ks * 32 + (l4 << 3));
            #pragma unroll
            for (int n = 0; n < 4; ++n) {
                int px = n * 16 + l15;
                short8 bz = *(const short8*)(zTc + (pxbase + px) * 512 + (((ks * 4 + l4) ^ (px & 7)) << 4));
                qacc[n] = __builtin_amdgcn_mfma_f32_16x16x32_bf16(aw, bz, qacc[n], 0, 0, 0);
            }
        }
        // reg-transpose -> bq[it]: lane(l31,l5) = q[px=it*32+l31][d=8*l5+e]
        Frag bq[2];
        {
            uint plo[4], phi[4];
            #pragma unroll
            for (int n = 0; n < 4; ++n) {
                plo[n] = pack2(qacc[n][0], qacc[n][1]);
                phi[n] = pack2(qacc[n][2], qacc[n][3]);
            }
            #pragma unroll
            for (int it = 0; it < 2; ++it) {
                uint a0 = (uint)__shfl((int)plo[it * 2], srcA), a1 = (uint)__shfl((int)plo[it * 2 + 1], srcA);
                uint b0 = (uint)__shfl((int)phi[it * 2], srcA), b1 = (uint)__shfl((int)phi[it * 2 + 1], srcA);
                uint c0 = (uint)__shfl((int)plo[it * 2], srcB), c1 = (uint)__shfl((int)plo[it * 2 + 1], srcB);
                uint d0 = (uint)__shfl((int)phi[it * 2], srcB), d1 = (uint)__shfl((int)phi[it * 2 + 1], srcB);
                bq[it].u[0] = hi16 ? a1 : a0;
                bq[it].u[1] = hi16 ? b1 : b0;
                bq[it].u[2] = hi16 ? c1 : c0;
                bq[it].u[3] = hi16 ? d1 : d0;
            }
        }

        // ---- k-GEMM: D[d][px] = Wk_h @ z ----
        floatx4 kacc[4] = {};
        #pragma unroll
        for (int ks = 0; ks < 8; ++ks) {
            short8 aw = *(const short8*)(Wqb + ((256 + h * 16 + l15) << 8) + ks * 32 + (l4 << 3));
            #pragma unroll
            for (int n = 0; n < 4; ++n) {
                int px = n * 16 + l15;
                short8 bz = *(const short8*)(zTc + (pxbase + px) * 512 + (((ks * 4 + l4) ^ (px & 7)) << 4));
                kacc[n] = __builtin_amdgcn_mfma_f32_16x16x32_bf16(aw, bz, kacc[n], 0, 0, 0);
            }
        }
        Frag ak[2];
        {
            uint plo[4], phi[4];
            #pragma unroll
            for (int n = 0; n < 4; ++n) {
                plo[n] = pack2(kacc[n][0], kacc[n][1]);
                phi[n] = pack2(kacc[n][2], kacc[n][3]);
            }
            #pragma unroll
            for (int jt = 0; jt < 2; ++jt) {
                uint a0 = (uint)__shfl((int)plo[jt * 2], srcA), a1 = (uint)__shfl((int)plo[jt * 2 + 1], srcA);
                uint b0 = (uint)__shfl((int)phi[jt * 2], srcA), b1 = (uint)__shfl((int)phi[jt * 2 + 1], srcA);
                uint c0 = (uint)__shfl((int)plo[jt * 2], srcB), c1 = (uint)__shfl((int)plo[jt * 2 + 1], srcB);
                uint d0 = (uint)__shfl((int)phi[jt * 2], srcB), d1 = (uint)__shfl((int)phi[jt * 2 + 1], srcB);
                ak[jt].u[0] = hi16 ? a1 : a0;
                ak[jt].u[1] = hi16 ? b1 : b0;
                ak[jt].u[2] = hi16 ? c1 : c0;
                ak[jt].u[3] = hi16 ? d1 : d0;
            }
        }

        // ---- v-GEMM (transposed): D[px][d] = z^T @ Wv_h^T ----
        floatx4 vacc[4] = {};
        #pragma unroll
        for (int ks = 0; ks < 8; ++ks) {
            short8 bw = *(const short8*)(Wqb + ((512 + h * 16 + l15) << 8) + ks * 32 + (l4 << 3));
            #pragma unroll
            for (int m = 0; m < 4; ++m) {
                int px = m * 16 + l15;
                short8 az = *(const short8*)(zTc + (pxbase + px) * 512 + (((ks * 4 + l4) ^ (px & 7)) << 4));
                vacc[m] = __builtin_amdgcn_mfma_f32_16x16x32_bf16(az, bw, vacc[m], 0, 0, 0);
            }
        }
        // reg-transpose -> av[jc]: lane(l31,l5) = V[d=l31&15][j=jc*16+8*l5+e]
        Frag av[4];
        {
            uint v01[4], v23[4];
            #pragma unroll
            for (int m = 0; m < 4; ++m) {
                v01[m] = pack2(vacc[m][0], vacc[m][1]);
                v23[m] = pack2(vacc[m][2], vacc[m][3]);
            }
            #pragma unroll
            for (int jc = 0; jc < 4; ++jc) {
                av[jc].u[0] = (uint)__shfl((int)v01[jc], srcA);
                av[jc].u[1] = (uint)__shfl((int)v23[jc], srcA);
                av[jc].u[2] = (uint)__shfl((int)v01[jc], srcB);
                av[jc].u[3] = (uint)__shfl((int)v23[jc], srcB);
            }
        }

        // ---- per-it: S^T, softmax, PV ----
        #pragma unroll
        for (int it = 0; it < 2; ++it) {
            floatx16 st[2];
            #pragma unroll
            for (int jt = 0; jt < 2; ++jt) {
                floatx16 zc = {};
                st[jt] = __builtin_amdgcn_mfma_f32_32x32x16_bf16(ak[jt].v, bq[it].v, zc, 0, 0, 0);
            }
            int i = it * 32 + l31;
            int Ai = (i >> 3) * 15 + (i & 7) + 112;
            float mx = -1e30f;
            #pragma unroll
            for (int jt = 0; jt < 2; ++jt)
                #pragma unroll
                for (int r = 0; r < 16; ++r) {
                    int j = jt * 32 + (r & 3) + 8 * (r >> 2) + 4 * l5;
                    int Bjr = (j >> 3) * 15 + (j & 7);
                    float s = st[jt][r] + srel[(Ai - Bjr) * 16 + h];
                    st[jt][r] = s;
                    mx = fmaxf(mx, s);
                }
            mx = fmaxf(mx, __shfl_xor(mx, 32));
            float sum = 0.f;
            #pragma unroll
            for (int jt = 0; jt < 2; ++jt)
                #pragma unroll
                for (int r = 0; r < 16; ++r) {
                    float e = __expf(st[jt][r] - mx);
                    st[jt][r] = e;
                    sum += e;
                }
            sum += __shfl_xor(sum, 32);
            float rinv = 1.0f / sum;

            floatx16 ot = {};
            #pragma unroll
            for (int jc = 0; jc < 4; ++jc) {
                int jt = jc >> 1, rb = (jc & 1) * 8;
                uint u0 = pack2(st[jt][rb + 0], st[jt][rb + 1]);
                uint u1 = pack2(st[jt][rb + 2], st[jt][rb + 3]);
                uint u2 = pack2(st[jt][rb + 4], st[jt][rb + 5]);
                uint u3 = pack2(st[jt][rb + 6], st[jt][rb + 7]);
                uint s0 = (uint)__shfl_xor((int)u0, 32);
                uint s1 = (uint)__shfl_xor((int)u1, 32);
                uint s2 = (uint)__shfl_xor((int)u2, 32);
                uint s3 = (uint)__shfl_xor((int)u3, 32);
                Frag bf;
                bf.u[0] = hilane ? s2 : u0;
                bf.u[1] = hilane ? s3 : u1;
                bf.u[2] = hilane ? u2 : s0;
                bf.u[3] = hilane ? u3 : s1;
                ot = __builtin_amdgcn_mfma_f32_32x32x16_bf16(av[jc].v, bf.v, ot, 0, 0, 0);
            }
            int gy = wy * 8 + (i >> 3);
            int gx = (wxp * 2 + win) * 8 + (i & 7);
            float* Ab = A + (((size_t)(b * 256 + h * 16)) << 16) + gy * 256 + gx;
            #pragma unroll
            for (int r = 0; r < 8; ++r) {
                int d = (r & 3) + 8 * (r >> 2) + 4 * l5;
                Ab[(size_t)d << 16] = ot[r] * rinv;
            }
        }
    }
}

// ---------------------------------------------------------------------------
// K7 (tiled): L += avgpoolV(A) + avgpoolH(A). 64x64 tile + 7-halo in LDS.
// ---------------------------------------------------------------------------
__global__ __launch_bounds__(256) void k7_pool(const float* __restrict__ A,
        float* __restrict__ L)
{
    int blk = blockIdx.x;
    int tile = blk & 15;
    int c = (blk >> 4) & 255;
    int b = blk >> 12;
    int ty = (tile >> 2) * 64, tx = (tile & 3) * 64;
    int t = threadIdx.x;
    __shared__ float aT[71][73];
    const float* Ac = A + ((size_t)(b * 256 + c) << 16);
    for (int i = t; i < 71 * 71; i += 256) {
        int rr = i / 71, cc = i - rr * 71;
        int gy = ty + rr - 3, gx = tx + cc - 3;
        float v = 0.f;
        if (gy >= 0 && gy <= 256 && gx >= 0 && gx <= 256) {
            int ry = (gy == 256) ? 254 : gy;
            int rx = (gx == 256) ? 254 : gx;
            v = Ac[ry * 256 + rx];
        }
        aT[rr][cc] = v;
    }
    __syncthreads();
    int jj = t & 63;
    int oy0 = (t >> 6) * 16;
    float* Lc = L + ((size_t)(b * 256 + c) << 16);
    #pragma unroll 4
    for (int dy = 0; dy < 16; ++dy) {
        int oi = oy0 + dy;
        float sv = 0.f, sh = 0.f;
        #pragma unroll
        for (int u = 0; u < 8; ++u) {
            sv += aT[oi + u][jj + 3];
            sh += aT[oi + 3][jj + u];
        }
        int idx = (ty + oi) * 256 + tx + jj;
        Lc[idx] += 0.125f * (sv + sh);
    }
}

// ---------------------------------------------------------------------------
// K8 (tiled): D(bf16) = sp * dwconv8x8(pad_out(L), wdw, pad=3) + bp
// ---------------------------------------------------------------------------
__global__ __launch_bounds__(256) void k8_dw(const float* __restrict__ P,
        const float* __restrict__ wdw, const float* __restrict__ sp,
        const float* __restrict__ bp, ushort* __restrict__ D)
{
    int blk = blockIdx.x;
    int tile = blk & 63;
    int c = (blk >> 6) & 255;
    int b = blk >> 14;
    int ty = (tile >> 3) * 32, tx = (tile & 7) * 32;
    int t = threadIdx.x;
    __shared__ float pT[39][40];
    __shared__ float wT[64];
    const float* Pc = P + ((size_t)(b * 256 + c) << 16);
    for (int i = t; i < 39 * 40; i += 256) {
        int rr = i / 40, cc = i - rr * 40;
        int gy = ty + rr - 3, gx = tx + cc - 3;
        float v = 0.f;
        if (gy >= 0 && gy <= 256 && gx >= 0 && gx <= 256) {
            int ry = (gy == 256) ? 254 : gy;
            int rx = (gx == 256) ? 254 : gx;
            v = Pc[ry * 256 + rx];
        }
        pT[rr][cc] = v;
    }
    if (t < 64) wT[t] = wdw[c * 64 + t];
    __syncthreads();
    int jj = t & 31;
    int oy0 = (t >> 5) * 4;
    float spc = sp[c], bpc = bp[c];
    ushort* Dc = D + ((size_t)(b * 256 + c) << 16);
    #pragma unroll
    for (int dy = 0; dy < 4; ++dy) {
        int oi = oy0 + dy;
        float acc = 0.f;
        #pragma unroll
        for (int u = 0; u < 8; ++u)
            #pragma unroll
            for (int v = 0; v < 8; ++v)
                acc += wT[u * 8 + v] * pT[oi + u][jj + v];
        Dc[(ty + oi) * 256 + tx + jj] = f2bf(spc * acc + bpc);
    }
}

// ---------------------------------------------------------------------------
// K9 (MFMA): out[co][px] = sum_ci Wpw[co][ci] * D[ci][px]
// ---------------------------------------------------------------------------
__global__ __launch_bounds__(512, 2) void k9_mfma(
        const ushort* __restrict__ D, const ushort* __restrict__ Wpwb,
        float* __restrict__ out)
{
    int blk = blockIdx.x;
    int b = blk >> 9;
    int px0 = (blk & 511) << 7;
    int t = threadIdx.x;
    int lane = t & 63;
    int w = t >> 6;
    int wr = w >> 1, wc = w & 1;

    __shared__ ushort sW[256 * 64];
    __shared__ ushort sD[128 * 64];

    floatx4 acc[4][4];
    #pragma unroll
    for (int m = 0; m < 4; ++m)
        #pragma unroll
        for (int n = 0; n < 4; ++n)
            acc[m][n] = {0.f, 0.f, 0.f, 0.f};

    int ldsWbase = w * 64 * 16;

    for (int cb = 0; cb < 4; ++cb) {
        int ci0 = cb * 64;
        __syncthreads();
        #pragma unroll
        for (int p = 0; p < 4; ++p) {
            int m = p * 512 + t;
            int row = m >> 3, ch = m & 7;
            const ushort* g = Wpwb + row * 256 + ci0 + ((ch ^ (row & 7)) << 3);
            gload16(g, (char*)sW + p * 512 * 16 + ldsWbase);
        }
        #pragma unroll
        for (int p = 0; p < 2; ++p) {
            int m = p * 512 + t;
            int ci = m & 63, pxb = (m >> 6) * 8;
            short8 v = *(const short8*)(D + ((size_t)(b * 256 + ci0 + ci) << 16) + px0 + pxb);
            #pragma unroll
            for (int k2 = 0; k2 < 8; ++k2) {
                int px = pxb + k2;
                *(ushort*)((char*)sD + px * 128 + (((ci >> 3) ^ (px & 7)) << 4) + (ci & 7) * 2) =
                    (ushort)v[k2];
            }
        }
        __syncthreads();
        #pragma unroll
        for (int kk = 0; kk < 2; ++kk) {
            int chunkb = kk * 4 + (lane >> 4);
            short8 afr[4];
            #pragma unroll
            for (int m2 = 0; m2 < 4; ++m2) {
                int row = wr * 64 + m2 * 16 + (lane & 15);
                int ch = chunkb ^ (row & 7);
                afr[m2] = *(const short8*)((const char*)sW + row * 128 + ch * 16);
            }
            #pragma unroll
            for (int n2 = 0; n2 < 4; ++n2) {
                int row = wc * 64 + n2 * 16 + (lane & 15);
                int ch = chunkb ^ (row & 7);
                short8 bfr = *(const short8*)((const char*)sD + row * 128 + ch * 16);
                #pragma unroll
                for (int m2 = 0; m2 < 4; ++m2)
                    acc[m2][n2] = __builtin_amdgcn_mfma_f32_16x16x32_bf16(
                        afr[m2], bfr, acc[m2][n2], 0, 0, 0);
            }
        }
    }
    int pxb = px0 + wc * 64 + (lane & 15);
    #pragma unroll
    for (int m2 = 0; m2 < 4; ++m2) {
        int cobase = wr * 64 + m2 * 16 + (lane >> 4) * 4;
        #pragma unroll
        for (int r = 0; r < 4; ++r) {
            int co = cobase + r;
            float* dst = out + (((size_t)(b * 256 + co)) << 16) + pxb;
            #pragma unroll
            for (int n2 = 0; n2 < 4; ++n2)
                dst[n2 * 16] = acc[m2][n2][r];
        }
    }
}

// ---------------------------------------------------------------------------
extern "C" void kernel_launch(void* const* d_in, const int* in_sizes, int n_in,
                              void* d_out, int out_size, void* d_ws, size_t ws_size,
                              hipStream_t stream)
{
    (void)in_sizes; (void)n_in; (void)out_size; (void)ws_size;
    const float* x     = (const float*)d_in[0];
    const float* y     = (const float*)d_in[1];
    const float* gamma = (const float*)d_in[2];
    const float* la_wq = (const float*)d_in[3];
    const float* la_bq = (const float*)d_in[4];
    const float* la_wk = (const float*)d_in[5];
    const float* la_bk = (const float*)d_in[6];
    const float* la_wv = (const float*)d_in[7];
    const float* la_bv = (const float*)d_in[8];
    const float* wqkv  = (const float*)d_in[9];
    const float* wl1   = (const float*)d_in[10];
    const float* s1    = (const float*)d_in[11];
    const float* b1    = (const float*)d_in[12];
    const float* wl2   = (const float*)d_in[13];
    const float* s2    = (const float*)d_in[14];
    const float* b2    = (const float*)d_in[15];
    const float* rel   = (const float*)d_in[16];
    const float* wdw   = (const float*)d_in[17];
    const float* sp    = (const float*)d_in[18];
    const float* bp    = (const float*)d_in[19];
    const float* wpw   = (const float*)d_in[20];
    float* out = (float*)d_out;

    float* ws = (float*)d_ws;
    float* Q      = ws;                      // 4,194,304 floats (Qo)
    float* Kn     = ws + 4194304;            // 4,194,304 (W-preps alias after k2)
    float* stats  = ws + 8388608;            // 40,960 floats
    float* Ksum   = stats;
    float* xsum   = stats + 64;
    float* KX     = stats + 576;
    float* matrix = stats + 16960;
    float* vsum   = stats + 33344;
    float* A      = ws + 8429568;            // 33,554,432 (ybf alias; attn out; Dbf)
    float* L      = A + 33554432;            // 33,554,432 (phase1 aliases; Lconv)

    // L-region phase-1 aliases (all dead before k5 writes L):
    float* KXp   = L;                        // 1024 x 8192
    float* xsp   = L + 8388608;
    float* ksp   = L + 8650752;
    ushort* xbf  = (ushort*)(L + 8683520);   // x NHWC bf16
    ushort* Wqkb = (ushort*)(L + 25460736);  // 16,384 ushorts

    ushort* Wb    = (ushort*)Kn;             // conv weights, 589,824 bf16
    ushort* Wqb   = (ushort*)Kn + 600064;    // qkv weights, 196,608 bf16
    ushort* Wpwb  = (ushort*)Kn + 798720;    // pw weights, 65,536 bf16
    ushort* ybf   = (ushort*)A;              // padded NHWC y — until k6
    ushort* Dbf   = (ushort*)A;              // bf16 dwconv out — after k8
    ushort* zbf   = (ushort*)d_out;          // z bf16 NHWC (pre-swizzled) — k4..k6

    hipMemsetAsync(ybf, 0, (size_t)2 * 258 * 258 * 256 * sizeof(ushort), stream);

    kprep_y  <<<16384, 256, 0, stream>>>(y, ybf);
    kprep_x  <<<16384, 256, 0, stream>>>(x, xbf);
    kprep_qk <<<64,    256, 0, stream>>>(la_wq, la_wk, Wqkb);
    k1_mfma  <<<1024,  512, 0, stream>>>(xbf, Wqkb, la_bq, la_bk, Q, Kn);
    k2_kx    <<<1024,  256, 0, stream>>>(x, Kn, KXp, xsp, ksp);
    kprep_w  <<<2304,  256, 0, stream>>>(wl1, s1, wl2, s2, Wb);  // Kn dead after k2
    kprep_qw <<<768,   256, 0, stream>>>(wqkv, Wqb);
    kprep_pw <<<256,   256, 0, stream>>>(wpw, Wpwb);
    k2r      <<<68,    256, 0, stream>>>(KXp, xsp, ksp, KX, xsum, Ksum);
    k3_mat   <<<2,     256, 0, stream>>>(la_wv, la_bv, KX, xsum, Ksum, matrix, vsum);
    k4_z     <<<2048,  256, 0, stream>>>(x, Q, matrix, vsum, Ksum, gamma, zbf);
    k5_mfma  <<<1024,  512, 0, stream>>>(ybf, Wb, b1, b2, L);    // overwrites xbf etc
    k6_mfma  <<<1024,  512, 0, stream>>>(zbf, Wqb, rel, A);      // overwrites ybf
    k7_pool  <<<8192,  256, 0, stream>>>(A, L);
    k8_dw    <<<32768, 256, 0, stream>>>(L, wdw, sp, bp, Dbf);
    k9_mfma  <<<1024,  512, 0, stream>>>(Dbf, Wpwb, out);
}

// Round 11
// 1268.234 us; speedup vs baseline: 1.5014x; 1.1483x over previous
//
#include <hip/hip_runtime.h>
#include <hip/hip_bf16.h>

#define DI __device__ __forceinline__

constexpr int Bc = 2, Cc = 256, Hc = 256, Wc = 256, Nc = Hc * Wc; // N=65536
constexpr float LA_EPS = 1e-6f;

typedef __attribute__((ext_vector_type(8))) short short8;
typedef __attribute__((ext_vector_type(4))) float floatx4;
typedef __attribute__((ext_vector_type(16))) float floatx16;

union Frag { short8 v; uint u[4]; };

DI ushort f2bf(float f) {
    uint u = __float_as_uint(f);
    uint r = (u + 0x7fff + ((u >> 16) & 1)) >> 16;
    return (ushort)r;
}

DI float bf2f(ushort u) { return __uint_as_float((uint)u << 16); }

DI uint pack2(float a, float b) {
    return (uint)f2bf(a) | ((uint)f2bf(b) << 16);
}

DI void gload16(const void* g, void* l) {
    __builtin_amdgcn_global_load_lds(
        (const __attribute__((address_space(1))) void*)g,
        (__attribute__((address_space(3))) void*)l, 16, 0, 0);
}

// ---------------------------------------------------------------------------
// KPREP_X: NCHW f32 -> NHWC bf16 ([b][px][ci])  (linear, used for x)
// ---------------------------------------------------------------------------
__global__ __launch_bounds__(256) void kprep_x(const float* __restrict__ x,
        ushort* __restrict__ xbf)
{
    int blk = blockIdx.x;
    int b = blk >> 13;
    int rest = blk & 8191;
    int ci0 = (rest & 7) * 32;
    int n0 = (rest >> 3) * 64;
    int t = threadIdx.x;
    __shared__ uint u[16][65];
    int px = t & 63, cig = t >> 6;
    const float* yb = x + (((size_t)(b * 256 + ci0 + cig * 8)) << 16) + n0 + px;
    #pragma unroll
    for (int jj = 0; jj < 4; ++jj) {
        float v0 = yb[((size_t)(jj * 2)) << 16];
        float v1 = yb[((size_t)(jj * 2 + 1)) << 16];
        u[cig * 4 + jj][px] = pack2(v0, v1);
    }
    __syncthreads();
    uint* out32 = (uint*)xbf;
    int pr = t & 15, pg = t >> 4;
    #pragma unroll
    for (int g2 = 0; g2 < 4; ++g2) {
        int ppx = g2 * 16 + pg;
        size_t uidx = (((size_t)(b * 65536 + n0 + ppx) * 256 + ci0) >> 1) + pr;
        out32[uidx] = u[pr][ppx];
    }
}

// ---------------------------------------------------------------------------
// KPREP_QK: Wqkb[64][256] = bf16( rows 0-31: wq, rows 32-63: wk )
// ---------------------------------------------------------------------------
__global__ __launch_bounds__(256) void kprep_qk(const float* __restrict__ wq,
        const float* __restrict__ wk, ushort* __restrict__ Wqkb)
{
    int idx = blockIdx.x * 256 + threadIdx.x;   // 16384
    int oc = idx >> 8, ci = idx & 255;
    float v = (oc < 32) ? wq[oc * 256 + ci] : wk[(oc - 32) * 256 + ci];
    Wqkb[idx] = f2bf(v);
}

// ---------------------------------------------------------------------------
// K1 (MFMA): Q,K = 1x1 conv (32 ch each) + per-pixel channel L2-norm.
// 64-px tiles: LDS 64KB -> 2 blocks/CU (16 waves). 8 waves = 2(q/k) x 4(16px).
// ---------------------------------------------------------------------------
__global__ __launch_bounds__(512, 2) void k1_mfma(
        const ushort* __restrict__ xbf, const ushort* __restrict__ Wqkb,
        const float* __restrict__ bq, const float* __restrict__ bk,
        float* __restrict__ Qo, float* __restrict__ Ko)
{
    int blk = blockIdx.x;
    int b = blk >> 10;
    int px0 = (blk & 1023) << 6;
    int t = threadIdx.x;
    int lane = t & 63, w = t >> 6;
    int wr = w >> 2;       // 0: q rows, 1: k rows
    int wc = w & 3;        // px quarter (16 px)

    __shared__ ushort sW[64 * 256];    // 32KB [oc][ci] swizzled
    __shared__ ushort sX[64 * 256];    // 32KB [px][ci] swizzled

    #pragma unroll
    for (int p = 0; p < 4; ++p) {
        int m = p * 512 + t;
        int row = m >> 5, ch = m & 31;
        const ushort* g = Wqkb + row * 256 + ((ch ^ (row & 7)) << 3);
        gload16(g, (char*)sW + p * 8192 + w * 1024);
    }
    const ushort* xb = xbf + (size_t)(b * 65536 + px0) * 256;
    #pragma unroll
    for (int p = 0; p < 4; ++p) {
        int m = p * 512 + t;
        int row = m >> 5, ch = m & 31;
        const ushort* g = xb + row * 256 + ((ch ^ (row & 7)) << 3);
        gload16(g, (char*)sX + p * 8192 + w * 1024);
    }
    __syncthreads();

    int l15 = lane & 15, l4 = lane >> 4;
    floatx4 acc[2];
    acc[0] = {0.f, 0.f, 0.f, 0.f};
    acc[1] = {0.f, 0.f, 0.f, 0.f};

    #pragma unroll
    for (int ks = 0; ks < 8; ++ks) {
        int cidx = ks * 4 + l4;
        short8 af[2];
        #pragma unroll
        for (int m2 = 0; m2 < 2; ++m2) {
            int row = wr * 32 + m2 * 16 + l15;
            af[m2] = *(const short8*)((const char*)sW + row * 512 + ((cidx ^ (row & 7)) << 4));
        }
        int brow = wc * 16 + l15;
        short8 bf_ = *(const short8*)((const char*)sX + brow * 512 + ((cidx ^ (brow & 7)) << 4));
        #pragma unroll
        for (int m2 = 0; m2 < 2; ++m2)
            acc[m2] = __builtin_amdgcn_mfma_f32_16x16x32_bf16(af[m2], bf_, acc[m2], 0, 0, 0);
    }

    const float* bias = wr ? bk : bq;
    float* outp = wr ? Ko : Qo;
    float v[2][4];
    float s = 0.f;
    #pragma unroll
    for (int m2 = 0; m2 < 2; ++m2)
        #pragma unroll
        for (int r = 0; r < 4; ++r) {
            float vv = acc[m2][r] + bias[m2 * 16 + l4 * 4 + r];
            v[m2][r] = vv;
            s += vv * vv;
        }
    s += __shfl_xor(s, 16);
    s += __shfl_xor(s, 32);
    float rn = rsqrtf(s);
    int px = px0 + wc * 16 + l15;
    #pragma unroll
    for (int m2 = 0; m2 < 2; ++m2)
        #pragma unroll
        for (int r = 0; r < 4; ++r) {
            int oc = m2 * 16 + l4 * 4 + r;
            outp[((size_t)(b * 32 + oc) << 16) + px] = v[m2][r] * rn;
        }
}

// ---------------------------------------------------------------------------
// K2: partial KX/xsum/Ksum per block. Reads xbf (NHWC bf16) DIRECTLY —
// lanes = c -> coalesced 128B rows, no x staging. kT broadcast from LDS.
// 1024 blocks, 128 px each. ~48 VGPR, 16KB LDS -> near-full occupancy.
// ---------------------------------------------------------------------------
__global__ __launch_bounds__(256) void k2_kx(const ushort* __restrict__ xbf,
        const float* __restrict__ Kn, float* __restrict__ KXp,
        float* __restrict__ xsp, float* __restrict__ ksp)
{
    int blk = blockIdx.x;
    int b = blk >> 9;
    int blkl = blk & 511;
    int t = threadIdx.x;               // t = c
    int n0 = blkl * 128;
    __shared__ float kT[32][128];      // 16KB
    for (int i = t; i < 4096; i += 256) {
        int m = i >> 7, p = i & 127;
        kT[m][p] = Kn[((size_t)(b * 32 + m) << 16) + n0 + p];
    }
    __syncthreads();
    float acc[32];
    #pragma unroll
    for (int m = 0; m < 32; ++m) acc[m] = 0.f;
    float xs = 0.f;
    const ushort* xb = xbf + (((size_t)(b * 65536 + n0)) << 8) + t;
    for (int p4 = 0; p4 < 32; ++p4) {
        float xv0 = bf2f(xb[(size_t)(p4 * 4 + 0) << 8]);
        float xv1 = bf2f(xb[(size_t)(p4 * 4 + 1) << 8]);
        float xv2 = bf2f(xb[(size_t)(p4 * 4 + 2) << 8]);
        float xv3 = bf2f(xb[(size_t)(p4 * 4 + 3) << 8]);
        xs += xv0 + xv1 + xv2 + xv3;
        #pragma unroll
        for (int m = 0; m < 32; ++m) {
            floatx4 kv = *(const floatx4*)&kT[m][p4 * 4];
            acc[m] += kv[0] * xv0 + kv[1] * xv1 + kv[2] * xv2 + kv[3] * xv3;
        }
    }
    xsp[blk * 256 + t] = xs;
    if (t < 32) {
        float ks = 0.f;
        for (int p = 0; p < 128; ++p) ks += kT[t][p];
        ksp[blk * 32 + t] = ks;
    }
    #pragma unroll
    for (int m = 0; m < 32; ++m) KXp[(size_t)blk * 8192 + m * 256 + t] = acc[m];
}

// ---------------------------------------------------------------------------
// K2R: reduce partials -> KX, xsum, Ksum
// ---------------------------------------------------------------------------
__global__ __launch_bounds__(256) void k2r(const float* __restrict__ KXp,
        const float* __restrict__ xsp, const float* __restrict__ ksp,
        float* __restrict__ KX, float* __restrict__ xsum, float* __restrict__ Ksum)
{
    int blk = blockIdx.x, t = threadIdx.x;
    if (blk < 64) {
        int gidx = blk * 256 + t;
        int b = gidx >> 13, idx = gidx & 8191;
        float s = 0.f;
        for (int ch = 0; ch < 512; ++ch)
            s += KXp[(size_t)((b << 9) + ch) * 8192 + idx];
        KX[gidx] = s;
    } else if (blk < 66) {
        int b = blk - 64;
        float s = 0.f;
        for (int ch = 0; ch < 512; ++ch)
            s += xsp[((b << 9) + ch) * 256 + t];
        xsum[b * 256 + t] = s;
    } else {
        int b = blk - 66;
        if (t < 32) {
            float s = 0.f;
            for (int ch = 0; ch < 512; ++ch)
                s += ksp[((b << 9) + ch) * 32 + t];
            Ksum[b * 32 + t] = s;
        }
    }
}

// ---------------------------------------------------------------------------
// K3: matrix/vsum from KX, xsum, Ksum
// ---------------------------------------------------------------------------
__global__ __launch_bounds__(256) void k3_mat(const float* __restrict__ wv,
        const float* __restrict__ bv, const float* __restrict__ KX,
        const float* __restrict__ xsum, const float* __restrict__ Ksum,
        float* __restrict__ matrix, float* __restrict__ vsum)
{
    int b = blockIdx.x, t = threadIdx.x;
    __shared__ float sx[256];
    __shared__ float sk[32];
    __shared__ float skx[32][256];
    __shared__ float wT[256][65];
    sx[t] = xsum[b * 256 + t];
    if (t < 32) sk[t] = Ksum[b * 32 + t];
    for (int j = 0; j < 32; ++j) skx[j][t] = KX[(b * 32 + j) * 256 + t];
    float vs = bv[t] * (float)Nc;
    float mv[32];
    #pragma unroll
    for (int m = 0; m < 32; ++m) mv[m] = 0.f;
    for (int cc0 = 0; cc0 < 256; cc0 += 64) {
        __syncthreads();
        for (int i = 0; i < 64; ++i) {
            int c = i * 4 + (t >> 6);
            wT[c][t & 63] = wv[(size_t)c * 256 + cc0 + (t & 63)];
        }
        __syncthreads();
        for (int ccl = 0; ccl < 64; ++ccl) {
            float w = wT[t][ccl];
            int cc = cc0 + ccl;
            vs += w * sx[cc];
            #pragma unroll
            for (int m = 0; m < 32; ++m) mv[m] += w * skx[m][cc];
        }
    }
    vsum[b * 256 + t] = vs;
    float bvt = bv[t];
    for (int m = 0; m < 32; ++m) matrix[(b * 32 + m) * 256 + t] = mv[m] + bvt * sk[m];
}

// ---------------------------------------------------------------------------
// K4: z = x + gamma*(vsum + Q^T matrix)*tailor -> DIRECTLY as bf16 NHWC,
// pre-swizzled in memory (chunk ^= px&7) so k6 can stage it linearly.
// ---------------------------------------------------------------------------
__global__ __launch_bounds__(256) void k4_z(const float* __restrict__ x,
        const float* __restrict__ Q, const float* __restrict__ matrix,
        const float* __restrict__ vsum, const float* __restrict__ Ksum,
        const float* __restrict__ gamma_p, ushort* __restrict__ zbf)
{
    int b = blockIdx.x >> 10;
    int n0 = (blockIdx.x & 1023) * 64;
    int t = threadIdx.x;
    int px = t & 63, g = t >> 6;
    __shared__ float qT[32][64];
    __shared__ float mat[32][256];
    __shared__ float vs[256];
    __shared__ float tail[64];
    __shared__ float sk[32];
    __shared__ uint zsh[64 * 128];   // [px][cp] bf16 pairs, swizzled (32KB)
    #pragma unroll
    for (int j = 0; j < 8; ++j) {
        int m = j * 4 + g;
        qT[m][px] = Q[((size_t)b * 32 + m) * Nc + n0 + px];
    }
    for (int j = 0; j < 32; ++j) {
        int idx = j * 256 + t;
        (&mat[0][0])[idx] = matrix[b * 8192 + idx];
    }
    vs[t] = vsum[b * 256 + t];
    if (t < 32) sk[t] = Ksum[b * 32 + t] + LA_EPS;
    __syncthreads();
    if (t < 64) {
        float s = 0.f;
        #pragma unroll
        for (int m = 0; m < 32; ++m) s += qT[m][t] * sk[m];
        tail[t] = 1.0f / ((float)Nc + s);
    }
    __syncthreads();
    float gamma = gamma_p[0];
    float tl = tail[px];
    for (int l = 0; l < 64; l += 2) {
        int c0 = g * 64 + l;
        float s0 = vs[c0], s1 = vs[c0 + 1];
        #pragma unroll
        for (int m = 0; m < 32; ++m) {
            float qv = qT[m][px];
            s0 += qv * mat[m][c0];
            s1 += qv * mat[m][c0 + 1];
        }
        size_t idx0 = (size_t)(b * 256 + c0) * Nc + n0 + px;
        float z0 = x[idx0] + gamma * s0 * tl;
        float z1 = x[idx0 + Nc] + gamma * s1 * tl;
        int cp = c0 >> 1;
        zsh[(px * 512 + (((cp >> 2) ^ (px & 7)) << 4) + (cp & 3) * 4) >> 2] = pack2(z0, z1);
    }
    __syncthreads();
    const uint4* zl = (const uint4*)zsh;
    uint4* gz = (uint4*)(zbf + (((size_t)(b * 65536 + n0)) << 8));
    #pragma unroll
    for (int i2 = 0; i2 < 8; ++i2)
        gz[i2 * 256 + t] = zl[i2 * 256 + t];
}

// ---------------------------------------------------------------------------
// KPREP_Y: y (NCHW f32) -> ybf (padded NHWC bf16, [b][258][258][256], origin +1)
// ---------------------------------------------------------------------------
__global__ __launch_bounds__(256) void kprep_y(const float* __restrict__ y,
        ushort* __restrict__ ybf)
{
    int blk = blockIdx.x;
    int b = blk >> 13;
    int rest = blk & 8191;
    int ci0 = (rest & 7) * 32;
    int n0 = (rest >> 3) * 64;
    int row = n0 >> 8, x = n0 & 255;
    int t = threadIdx.x;
    __shared__ uint u[16][65];
    int px = t & 63, cig = t >> 6;
    const float* yb = y + (((size_t)(b * 256 + ci0 + cig * 8)) << 16) + n0 + px;
    #pragma unroll
    for (int jj = 0; jj < 4; ++jj) {
        float v0 = yb[((size_t)(jj * 2)) << 16];
        float v1 = yb[((size_t)(jj * 2 + 1)) << 16];
        u[cig * 4 + jj][px] = pack2(v0, v1);
    }
    __syncthreads();
    uint* out32 = (uint*)ybf;
    size_t pbase = (size_t)(row + 1) * 258 + (x + 1);
    int pr = t & 15, pg = t >> 4;
    #pragma unroll
    for (int g2 = 0; g2 < 4; ++g2) {
        int ppx = g2 * 16 + pg;
        size_t uidx = (((size_t)b * 258 * 258 * 256 + (pbase + ppx) * 256 + ci0) >> 1) + pr;
        out32[uidx] = u[pr][ppx];
    }
}

// ---------------------------------------------------------------------------
// KPREP_W: Wb[tap][co][ci] = bf16(wl1*s1 + (tap==4)*wl2*s2)
// ---------------------------------------------------------------------------
__global__ __launch_bounds__(256) void kprep_w(const float* __restrict__ wl1,
        const float* __restrict__ s1, const float* __restrict__ wl2,
        const float* __restrict__ s2, ushort* __restrict__ Wb)
{
    int idx = blockIdx.x * 256 + threadIdx.x;
    int tp = idx >> 16;
    int r = idx & 65535;
    int co = r >> 8;
    float v = wl1[(size_t)r * 9 + tp] * s1[co];
    if (tp == 4) v += wl2[r] * s2[co];
    Wb[idx] = f2bf(v);
}

// ---------------------------------------------------------------------------
// KPREP_QW: Wqb = bf16(wqkv), q rows pre-scaled by 0.25
// ---------------------------------------------------------------------------
__global__ __launch_bounds__(256) void kprep_qw(const float* __restrict__ wqkv,
        ushort* __restrict__ Wqb)
{
    int idx = blockIdx.x * 256 + threadIdx.x;
    float v = wqkv[idx];
    if (idx < 65536) v *= 0.25f;
    Wqb[idx] = f2bf(v);
}

// ---------------------------------------------------------------------------
// KPREP_PW
// ---------------------------------------------------------------------------
__global__ __launch_bounds__(256) void kprep_pw(const float* __restrict__ wpw,
        ushort* __restrict__ Wpwb)
{
    int idx = blockIdx.x * 256 + threadIdx.x;
    Wpwb[idx] = f2bf(wpw[idx]);
}

// ---------------------------------------------------------------------------
// K5 (MFMA): L = conv3x3(ybf, Wc) + bias
// ---------------------------------------------------------------------------
__global__ __launch_bounds__(512, 2) void k5_mfma(
        const ushort* __restrict__ ybf, const ushort* __restrict__ Wb,
        const float* __restrict__ b1, const float* __restrict__ b2,
        float* __restrict__ L)
{
    int blk = blockIdx.x;
    int b = blk >> 9;
    int y0 = (blk >> 1) & 255;
    int x0 = (blk & 1) << 7;
    int t = threadIdx.x;
    int lane = t & 63;
    int w = t >> 6;
    int wr = w >> 1;
    int wc = w & 1;

    __shared__ ushort sW[256 * 64];
    __shared__ ushort sY[128 * 64];

    floatx4 acc[4][4];
    #pragma unroll
    for (int m = 0; m < 4; ++m)
        #pragma unroll
        for (int n = 0; n < 4; ++n)
            acc[m][n] = {0.f, 0.f, 0.f, 0.f};

    const ushort* yb = ybf + (size_t)b * 258 * 258 * 256;
    int ldsWbase = w * 64 * 16;
    int ldsYbase = w * 64 * 16;

    for (int tp = 0; tp < 9; ++tp) {
        int dy = tp / 3 - 1, dx = tp % 3 - 1;
        const ushort* yrow = yb + ((size_t)(y0 + dy + 1) * 258 + (x0 + dx + 1)) * 256;
        const ushort* wtap = Wb + tp * 65536;
        for (int cb = 0; cb < 4; ++cb) {
            int ci0 = cb * 64;
            __syncthreads();
            #pragma unroll
            for (int p = 0; p < 4; ++p) {
                int m = p * 512 + t;
                int row = m >> 3, ch = m & 7;
                const ushort* g = wtap + row * 256 + ci0 + ((ch ^ (row & 7)) << 3);
                gload16(g, (char*)sW + p * 512 * 16 + ldsWbase);
            }
            #pragma unroll
            for (int p = 0; p < 2; ++p) {
                int m = p * 512 + t;
                int pxr = m >> 3, ch = m & 7;
                const ushort* g = yrow + (size_t)pxr * 256 + ci0 + ((ch ^ (pxr & 7)) << 3);
                gload16(g, (char*)sY + p * 512 * 16 + ldsYbase);
            }
            __syncthreads();
            #pragma unroll
            for (int kk = 0; kk < 2; ++kk) {
                int chunkb = kk * 4 + (lane >> 4);
                short8 afr[4];
                #pragma unroll
                for (int m2 = 0; m2 < 4; ++m2) {
                    int row = wr * 64 + m2 * 16 + (lane & 15);
                    int ch = chunkb ^ (row & 7);
                    afr[m2] = *(const short8*)((const char*)sW + row * 128 + ch * 16);
                }
                #pragma unroll
                for (int n2 = 0; n2 < 4; ++n2) {
                    int row = wc * 64 + n2 * 16 + (lane & 15);
                    int ch = chunkb ^ (row & 7);
                    short8 bfr = *(const short8*)((const char*)sY + row * 128 + ch * 16);
                    #pragma unroll
                    for (int m2 = 0; m2 < 4; ++m2)
                        acc[m2][n2] = __builtin_amdgcn_mfma_f32_16x16x32_bf16(
                            afr[m2], bfr, acc[m2][n2], 0, 0, 0);
                }
            }
        }
    }
    int pxb = x0 + wc * 64 + (lane & 15);
    #pragma unroll
    for (int m2 = 0; m2 < 4; ++m2) {
        int cobase = wr * 64 + m2 * 16 + (lane >> 4) * 4;
        #pragma unroll
        for (int r = 0; r < 4; ++r) {
            int co = cobase + r;
            float bias = b1[co] + b2[co];
            float* dst = L + (((size_t)(b * 256 + co)) << 16) + y0 * 256 + pxb;
            #pragma unroll
            for (int n2 = 0; n2 < 4; ++n2)
                dst[n2 * 16] = acc[m2][n2][r] + bias;
        }
    }
}

// ---------------------------------------------------------------------------
// K6 (MFMA, fused): qkv + window attention, TWO adjacent windows per block.
// Round-9 write schedule (waves 0-3 -> win0, 4-7 -> win1, concurrent halves
// of every 64B A-line) + in-register shfl transposes (no wbuf).
// ---------------------------------------------------------------------------
__global__ __launch_bounds__(512, 2) void k6_mfma(const ushort* __restrict__ zbf,
        const ushort* __restrict__ Wqb, const float* __restrict__ rel,
        float* __restrict__ A)
{
    int blk = blockIdx.x;
    int wxp = blk & 15, wy = (blk >> 4) & 31, b = blk >> 9;
    int t = threadIdx.x;
    int lane = t & 63;
    int w = t >> 6;
    int win = w >> 2;      // waves 0-3: window 0, waves 4-7: window 1
    int wq4 = w & 3;       // 4 heads per wave

    __shared__ ushort zT[128 * 256];     // 64KB, swizzle baked in memory
    __shared__ float srel[3600];         // 14.4KB

    char* zTc = (char*)zT;

    // ---- stage both z windows via linear global_load_lds (zbf pre-swizzled) ----
    {
        const ushort* zb = zbf + (((size_t)b) << 16) * 256;
        #pragma unroll
        for (int p = 0; p < 8; ++p) {
            int m = p * 512 + t;
            int row = m >> 5, ch = m & 31;
            int win2 = row >> 6, px = row & 63;
            int gy = wy * 8 + (px >> 3);
            int gx = (wxp * 2 + win2) * 8 + (px & 7);
            const ushort* g = zb + (((size_t)(gy * 256 + gx)) << 8) + ch * 8;
            gload16(g, zTc + p * 8192 + w * 1024);
        }
    }
    for (int i = t; i < 3600; i += 512) srel[i] = rel[i];
    __syncthreads();

    int l15 = lane & 15, l4 = lane >> 4;
    int l31 = lane & 31, l5 = lane >> 5;
    bool hilane = (l5 != 0);
    bool hi16 = (l31 & 16) != 0;
    int srcA = (l5 << 5) + (l31 & 15);
    int srcB = srcA + 16;
    int pxbase = win * 64;

    for (int hrep = 0; hrep < 4; ++hrep) {
        int h = wq4 * 4 + hrep;

        // ---- q-GEMM: D[d][px] = 0.25*Wq_h @ z ----
        floatx4 qacc[4] = {};
        #pragma unroll
        for (int ks = 0; ks < 8; ++ks) {
            short8 aw = *(const short8*)(Wqb + ((h * 16 + l15) << 8) + ks * 32 + (l4 << 3));
            #pragma unroll
            for (int n = 0; n < 4; ++n) {
                int px = n * 16 + l15;
                short8 bz = *(const short8*)(zTc + (pxbase + px) * 512 + (((ks * 4 + l4) ^ (px & 7)) << 4));
                qacc[n] = __builtin_amdgcn_mfma_f32_16x16x32_bf16(aw, bz, qacc[n], 0, 0, 0);
            }
        }
        Frag bq[2];
        {
            uint plo[4], phi[4];
            #pragma unroll
            for (int n = 0; n < 4; ++n) {
                plo[n] = pack2(qacc[n][0], qacc[n][1]);
                phi[n] = pack2(qacc[n][2], qacc[n][3]);
            }
            #pragma unroll
            for (int it = 0; it < 2; ++it) {
                uint a0 = (uint)__shfl((int)plo[it * 2], srcA), a1 = (uint)__shfl((int)plo[it * 2 + 1], srcA);
                uint b0 = (uint)__shfl((int)phi[it * 2], srcA), b1 = (uint)__shfl((int)phi[it * 2 + 1], srcA);
                uint c0 = (uint)__shfl((int)plo[it * 2], srcB), c1 = (uint)__shfl((int)plo[it * 2 + 1], srcB);
                uint d0 = (uint)__shfl((int)phi[it * 2], srcB), d1 = (uint)__shfl((int)phi[it * 2 + 1], srcB);
                bq[it].u[0] = hi16 ? a1 : a0;
                bq[it].u[1] = hi16 ? b1 : b0;
                bq[it].u[2] = hi16 ? c1 : c0;
                bq[it].u[3] = hi16 ? d1 : d0;
            }
        }

        // ---- k-GEMM: D[d][px] = Wk_h @ z ----
        floatx4 kacc[4] = {};
        #pragma unroll
        for (int ks = 0; ks < 8; ++ks) {
            short8 aw = *(const short8*)(Wqb + ((256 + h * 16 + l15) << 8) + ks * 32 + (l4 << 3));
            #pragma unroll
            for (int n = 0; n < 4; ++n) {
                int px = n * 16 + l15;
                short8 bz = *(const short8*)(zTc + (pxbase + px) * 512 + (((ks * 4 + l4) ^ (px & 7)) << 4));
                kacc[n] = __builtin_amdgcn_mfma_f32_16x16x32_bf16(aw, bz, kacc[n], 0, 0, 0);
            }
        }
        Frag ak[2];
        {
            uint plo[4], phi[4];
            #pragma unroll
            for (int n = 0; n < 4; ++n) {
                plo[n] = pack2(kacc[n][0], kacc[n][1]);
                phi[n] = pack2(kacc[n][2], kacc[n][3]);
            }
            #pragma unroll
            for (int jt = 0; jt < 2; ++jt) {
                uint a0 = (uint)__shfl((int)plo[jt * 2], srcA), a1 = (uint)__shfl((int)plo[jt * 2 + 1], srcA);
                uint b0 = (uint)__shfl((int)phi[jt * 2], srcA), b1 = (uint)__shfl((int)phi[jt * 2 + 1], srcA);
                uint c0 = (uint)__shfl((int)plo[jt * 2], srcB), c1 = (uint)__shfl((int)plo[jt * 2 + 1], srcB);
                uint d0 = (uint)__shfl((int)phi[jt * 2], srcB), d1 = (uint)__shfl((int)phi[jt * 2 + 1], srcB);
                ak[jt].u[0] = hi16 ? a1 : a0;
                ak[jt].u[1] = hi16 ? b1 : b0;
                ak[jt].u[2] = hi16 ? c1 : c0;
                ak[jt].u[3] = hi16 ? d1 : d0;
            }
        }

        // ---- v-GEMM (transposed): D[px][d] = z^T @ Wv_h^T ----
        floatx4 vacc[4] = {};
        #pragma unroll
        for (int ks = 0; ks < 8; ++ks) {
            short8 bw = *(const short8*)(Wqb + ((512 + h * 16 + l15) << 8) + ks * 32 + (l4 << 3));
            #pragma unroll
            for (int m = 0; m < 4; ++m) {
                int px = m * 16 + l15;
                short8 az = *(const short8*)(zTc + (pxbase + px) * 512 + (((ks * 4 + l4) ^ (px & 7)) << 4));
                vacc[m] = __builtin_amdgcn_mfma_f32_16x16x32_bf16(az, bw, vacc[m], 0, 0, 0);
            }
        }
        Frag av[4];
        {
            uint v01[4], v23[4];
            #pragma unroll
            for (int m = 0; m < 4; ++m) {
                v01[m] = pack2(vacc[m][0], vacc[m][1]);
                v23[m] = pack2(vacc[m][2], vacc[m][3]);
            }
            #pragma unroll
            for (int jc = 0; jc < 4; ++jc) {
                av[jc].u[0] = (uint)__shfl((int)v01[jc], srcA);
                av[jc].u[1] = (uint)__shfl((int)v23[jc], srcA);
                av[jc].u[2] = (uint)__shfl((int)v01[jc], srcB);
                av[jc].u[3] = (uint)__shfl((int)v23[jc], srcB);
            }
        }

        // ---- per-it: S^T, softmax, PV ----
        #pragma unroll
        for (int it = 0; it < 2; ++it) {
            floatx16 st[2];
            #pragma unroll
            for (int jt = 0; jt < 2; ++jt) {
                floatx16 zc = {};
                st[jt] = __builtin_amdgcn_mfma_f32_32x32x16_bf16(ak[jt].v, bq[it].v, zc, 0, 0, 0);
            }
            int i = it * 32 + l31;
            int Ai = (i >> 3) * 15 + (i & 7) + 112;
            float mx = -1e30f;
            #pragma unroll
            for (int jt = 0; jt < 2; ++jt)
                #pragma unroll
                for (int r = 0; r < 16; ++r) {
                    int j = jt * 32 + (r & 3) + 8 * (r >> 2) + 4 * l5;
                    int Bjr = (j >> 3) * 15 + (j & 7);
                    float s = st[jt][r] + srel[(Ai - Bjr) * 16 + h];
                    st[jt][r] = s;
                    mx = fmaxf(mx, s);
                }
            mx = fmaxf(mx, __shfl_xor(mx, 32));
            float sum = 0.f;
            #pragma unroll
            for (int jt = 0; jt < 2; ++jt)
                #pragma unroll
                for (int r = 0; r < 16; ++r) {
                    float e = __expf(st[jt][r] - mx);
                    st[jt][r] = e;
                    sum += e;
                }
            sum += __shfl_xor(sum, 32);
            float rinv = 1.0f / sum;

            floatx16 ot = {};
            #pragma unroll
            for (int jc = 0; jc < 4; ++jc) {
                int jt = jc >> 1, rb = (jc & 1) * 8;
                uint u0 = pack2(st[jt][rb + 0], st[jt][rb + 1]);
                uint u1 = pack2(st[jt][rb + 2], st[jt][rb + 3]);
                uint u2 = pack2(st[jt][rb + 4], st[jt][rb + 5]);
                uint u3 = pack2(st[jt][rb + 6], st[jt][rb + 7]);
                uint s0 = (uint)__shfl_xor((int)u0, 32);
                uint s1 = (uint)__shfl_xor((int)u1, 32);
                uint s2 = (uint)__shfl_xor((int)u2, 32);
                uint s3 = (uint)__shfl_xor((int)u3, 32);
                Frag bf;
                bf.u[0] = hilane ? s2 : u0;
                bf.u[1] = hilane ? s3 : u1;
                bf.u[2] = hilane ? u2 : s0;
                bf.u[3] = hilane ? u3 : s1;
                ot = __builtin_amdgcn_mfma_f32_32x32x16_bf16(av[jc].v, bf.v, ot, 0, 0, 0);
            }
            int gy = wy * 8 + (i >> 3);
            int gx = (wxp * 2 + win) * 8 + (i & 7);
            float* Ab = A + (((size_t)(b * 256 + h * 16)) << 16) + gy * 256 + gx;
            #pragma unroll
            for (int r = 0; r < 8; ++r) {
                int d = (r & 3) + 8 * (r >> 2) + 4 * l5;
                Ab[(size_t)d << 16] = ot[r] * rinv;
            }
        }
    }
}

// ---------------------------------------------------------------------------
// K7 (tiled): L += avgpoolV(A) + avgpoolH(A). 64x64 tile + 7-halo in LDS.
// ---------------------------------------------------------------------------
__global__ __launch_bounds__(256) void k7_pool(const float* __restrict__ A,
        float* __restrict__ L)
{
    int blk = blockIdx.x;
    int tile = blk & 15;
    int c = (blk >> 4) & 255;
    int b = blk >> 12;
    int ty = (tile >> 2) * 64, tx = (tile & 3) * 64;
    int t = threadIdx.x;
    __shared__ float aT[71][73];
    const float* Ac = A + ((size_t)(b * 256 + c) << 16);
    for (int i = t; i < 71 * 71; i += 256) {
        int rr = i / 71, cc = i - rr * 71;
        int gy = ty + rr - 3, gx = tx + cc - 3;
        float v = 0.f;
        if (gy >= 0 && gy <= 256 && gx >= 0 && gx <= 256) {
            int ry = (gy == 256) ? 254 : gy;
            int rx = (gx == 256) ? 254 : gx;
            v = Ac[ry * 256 + rx];
        }
        aT[rr][cc] = v;
    }
    __syncthreads();
    int jj = t & 63;
    int oy0 = (t >> 6) * 16;
    float* Lc = L + ((size_t)(b * 256 + c) << 16);
    #pragma unroll 4
    for (int dy = 0; dy < 16; ++dy) {
        int oi = oy0 + dy;
        float sv = 0.f, sh = 0.f;
        #pragma unroll
        for (int u = 0; u < 8; ++u) {
            sv += aT[oi + u][jj + 3];
            sh += aT[oi + 3][jj + u];
        }
        int idx = (ty + oi) * 256 + tx + jj;
        Lc[idx] += 0.125f * (sv + sh);
    }
}

// ---------------------------------------------------------------------------
// K8 (tiled): D(bf16) = sp * dwconv8x8(pad_out(L), wdw, pad=3) + bp
// ---------------------------------------------------------------------------
__global__ __launch_bounds__(256) void k8_dw(const float* __restrict__ P,
        const float* __restrict__ wdw, const float* __restrict__ sp,
        const float* __restrict__ bp, ushort* __restrict__ D)
{
    int blk = blockIdx.x;
    int tile = blk & 63;
    int c = (blk >> 6) & 255;
    int b = blk >> 14;
    int ty = (tile >> 3) * 32, tx = (tile & 7) * 32;
    int t = threadIdx.x;
    __shared__ float pT[39][40];
    __shared__ float wT[64];
    const float* Pc = P + ((size_t)(b * 256 + c) << 16);
    for (int i = t; i < 39 * 40; i += 256) {
        int rr = i / 40, cc = i - rr * 40;
        int gy = ty + rr - 3, gx = tx + cc - 3;
        float v = 0.f;
        if (gy >= 0 && gy <= 256 && gx >= 0 && gx <= 256) {
            int ry = (gy == 256) ? 254 : gy;
            int rx = (gx == 256) ? 254 : gx;
            v = Pc[ry * 256 + rx];
        }
        pT[rr][cc] = v;
    }
    if (t < 64) wT[t] = wdw[c * 64 + t];
    __syncthreads();
    int jj = t & 31;
    int oy0 = (t >> 5) * 4;
    float spc = sp[c], bpc = bp[c];
    ushort* Dc = D + ((size_t)(b * 256 + c) << 16);
    #pragma unroll
    for (int dy = 0; dy < 4; ++dy) {
        int oi = oy0 + dy;
        float acc = 0.f;
        #pragma unroll
        for (int u = 0; u < 8; ++u)
            #pragma unroll
            for (int v = 0; v < 8; ++v)
                acc += wT[u * 8 + v] * pT[oi + u][jj + v];
        Dc[(ty + oi) * 256 + tx + jj] = f2bf(spc * acc + bpc);
    }
}

// ---------------------------------------------------------------------------
// K9 (MFMA): out[co][px] = sum_ci Wpw[co][ci] * D[ci][px]
// ---------------------------------------------------------------------------
__global__ __launch_bounds__(512, 2) void k9_mfma(
        const ushort* __restrict__ D, const ushort* __restrict__ Wpwb,
        float* __restrict__ out)
{
    int blk = blockIdx.x;
    int b = blk >> 9;
    int px0 = (blk & 511) << 7;
    int t = threadIdx.x;
    int lane = t & 63;
    int w = t >> 6;
    int wr = w >> 1, wc = w & 1;

    __shared__ ushort sW[256 * 64];
    __shared__ ushort sD[128 * 64];

    floatx4 acc[4][4];
    #pragma unroll
    for (int m = 0; m < 4; ++m)
        #pragma unroll
        for (int n = 0; n < 4; ++n)
            acc[m][n] = {0.f, 0.f, 0.f, 0.f};

    int ldsWbase = w * 64 * 16;

    for (int cb = 0; cb < 4; ++cb) {
        int ci0 = cb * 64;
        __syncthreads();
        #pragma unroll
        for (int p = 0; p < 4; ++p) {
            int m = p * 512 + t;
            int row = m >> 3, ch = m & 7;
            const ushort* g = Wpwb + row * 256 + ci0 + ((ch ^ (row & 7)) << 3);
            gload16(g, (char*)sW + p * 512 * 16 + ldsWbase);
        }
        #pragma unroll
        for (int p = 0; p < 2; ++p) {
            int m = p * 512 + t;
            int ci = m & 63, pxb = (m >> 6) * 8;
            short8 v = *(const short8*)(D + ((size_t)(b * 256 + ci0 + ci) << 16) + px0 + pxb);
            #pragma unroll
            for (int k2 = 0; k2 < 8; ++k2) {
                int px = pxb + k2;
                *(ushort*)((char*)sD + px * 128 + (((ci >> 3) ^ (px & 7)) << 4) + (ci & 7) * 2) =
                    (ushort)v[k2];
            }
        }
        __syncthreads();
        #pragma unroll
        for (int kk = 0; kk < 2; ++kk) {
            int chunkb = kk * 4 + (lane >> 4);
            short8 afr[4];
            #pragma unroll
            for (int m2 = 0; m2 < 4; ++m2) {
                int row = wr * 64 + m2 * 16 + (lane & 15);
                int ch = chunkb ^ (row & 7);
                afr[m2] = *(const short8*)((const char*)sW + row * 128 + ch * 16);
            }
            #pragma unroll
            for (int n2 = 0; n2 < 4; ++n2) {
                int row = wc * 64 + n2 * 16 + (lane & 15);
                int ch = chunkb ^ (row & 7);
                short8 bfr = *(const short8*)((const char*)sD + row * 128 + ch * 16);
                #pragma unroll
                for (int m2 = 0; m2 < 4; ++m2)
                    acc[m2][n2] = __builtin_amdgcn_mfma_f32_16x16x32_bf16(
                        afr[m2], bfr, acc[m2][n2], 0, 0, 0);
            }
        }
    }
    int pxb = px0 + wc * 64 + (lane & 15);
    #pragma unroll
    for (int m2 = 0; m2 < 4; ++m2) {
        int cobase = wr * 64 + m2 * 16 + (lane >> 4) * 4;
        #pragma unroll
        for (int r = 0; r < 4; ++r) {
            int co = cobase + r;
            float* dst = out + (((size_t)(b * 256 + co)) << 16) + pxb;
            #pragma unroll
            for (int n2 = 0; n2 < 4; ++n2)
                dst[n2 * 16] = acc[m2][n2][r];
        }
    }
}

// ---------------------------------------------------------------------------
extern "C" void kernel_launch(void* const* d_in, const int* in_sizes, int n_in,
                              void* d_out, int out_size, void* d_ws, size_t ws_size,
                              hipStream_t stream)
{
    (void)in_sizes; (void)n_in; (void)out_size; (void)ws_size;
    const float* x     = (const float*)d_in[0];
    const float* y     = (const float*)d_in[1];
    const float* gamma = (const float*)d_in[2];
    const float* la_wq = (const float*)d_in[3];
    const float* la_bq = (const float*)d_in[4];
    const float* la_wk = (const float*)d_in[5];
    const float* la_bk = (const float*)d_in[6];
    const float* la_wv = (const float*)d_in[7];
    const float* la_bv = (const float*)d_in[8];
    const float* wqkv  = (const float*)d_in[9];
    const float* wl1   = (const float*)d_in[10];
    const float* s1    = (const float*)d_in[11];
    const float* b1    = (const float*)d_in[12];
    const float* wl2   = (const float*)d_in[13];
    const float* s2    = (const float*)d_in[14];
    const float* b2    = (const float*)d_in[15];
    const float* rel   = (const float*)d_in[16];
    const float* wdw   = (const float*)d_in[17];
    const float* sp    = (const float*)d_in[18];
    const float* bp    = (const float*)d_in[19];
    const float* wpw   = (const float*)d_in[20];
    float* out = (float*)d_out;

    float* ws = (float*)d_ws;
    float* Q      = ws;                      // 4,194,304 floats (Qo)
    float* Kn     = ws + 4194304;            // 4,194,304 (W-preps alias after k2)
    float* stats  = ws + 8388608;            // 40,960 floats
    float* Ksum   = stats;
    float* xsum   = stats + 64;
    float* KX     = stats + 576;
    float* matrix = stats + 16960;
    float* vsum   = stats + 33344;
    float* A      = ws + 8429568;            // 33,554,432 (ybf alias; attn out; Dbf)
    float* L      = A + 33554432;            // 33,554,432 (phase1 aliases; Lconv)

    // L-region phase-1 aliases (all dead before k5 writes L):
    float* KXp   = L;                        // 1024 x 8192
    float* xsp   = L + 8388608;
    float* ksp   = L + 8650752;
    ushort* xbf  = (ushort*)(L + 8683520);   // x NHWC bf16
    ushort* Wqkb = (ushort*)(L + 25460736);  // 16,384 ushorts

    ushort* Wb    = (ushort*)Kn;             // conv weights, 589,824 bf16
    ushort* Wqb   = (ushort*)Kn + 600064;    // qkv weights, 196,608 bf16
    ushort* Wpwb  = (ushort*)Kn + 798720;    // pw weights, 65,536 bf16
    ushort* ybf   = (ushort*)A;              // padded NHWC y — until k6
    ushort* Dbf   = (ushort*)A;              // bf16 dwconv out — after k8
    ushort* zbf   = (ushort*)d_out;          // z bf16 NHWC (pre-swizzled) — k4..k6

    hipMemsetAsync(ybf, 0, (size_t)2 * 258 * 258 * 256 * sizeof(ushort), stream);

    kprep_y  <<<16384, 256, 0, stream>>>(y, ybf);
    kprep_x  <<<16384, 256, 0, stream>>>(x, xbf);
    kprep_qk <<<64,    256, 0, stream>>>(la_wq, la_wk, Wqkb);
    k1_mfma  <<<2048,  512, 0, stream>>>(xbf, Wqkb, la_bq, la_bk, Q, Kn);
    k2_kx    <<<1024,  256, 0, stream>>>(xbf, Kn, KXp, xsp, ksp);
    kprep_w  <<<2304,  256, 0, stream>>>(wl1, s1, wl2, s2, Wb);  // Kn dead after k2
    kprep_qw <<<768,   256, 0, stream>>>(wqkv, Wqb);
    kprep_pw <<<256,   256, 0, stream>>>(wpw, Wpwb);
    k2r      <<<68,    256, 0, stream>>>(KXp, xsp, ksp, KX, xsum, Ksum);
    k3_mat   <<<2,     256, 0, stream>>>(la_wv, la_bv, KX, xsum, Ksum, matrix, vsum);
    k4_z     <<<2048,  256, 0, stream>>>(x, Q, matrix, vsum, Ksum, gamma, zbf);
    k5_mfma  <<<1024,  512, 0, stream>>>(ybf, Wb, b1, b2, L);    // overwrites xbf etc
    k6_mfma  <<<1024,  512, 0, stream>>>(zbf, Wqb, rel, A);      // overwrites ybf
    k7_pool  <<<8192,  256, 0, stream>>>(A, L);
    k8_dw    <<<32768, 256, 0, stream>>>(L, wdw, sp, bp, Dbf);
    k9_mfma  <<<1024,  512, 0, stream>>>(Dbf, Wpwb, out);
}

// Round 12
// 1231.073 us; speedup vs baseline: 1.5468x; 1.0302x over previous
//
#include <hip/hip_runtime.h>
#include <hip/hip_bf16.h>

#define DI __device__ __forceinline__

constexpr int Bc = 2, Cc = 256, Hc = 256, Wc = 256, Nc = Hc * Wc; // N=65536
constexpr float LA_EPS = 1e-6f;

typedef __attribute__((ext_vector_type(8))) short short8;
typedef __attribute__((ext_vector_type(4))) float floatx4;
typedef __attribute__((ext_vector_type(16))) float floatx16;

union Frag { short8 v; uint u[4]; };

DI ushort f2bf(float f) {
    uint u = __float_as_uint(f);
    uint r = (u + 0x7fff + ((u >> 16) & 1)) >> 16;
    return (ushort)r;
}

DI float bf2f(ushort u) { return __uint_as_float((uint)u << 16); }

DI uint pack2(float a, float b) {
    return (uint)f2bf(a) | ((uint)f2bf(b) << 16);
}

DI void gload16(const void* g, void* l) {
    __builtin_amdgcn_global_load_lds(
        (const __attribute__((address_space(1))) void*)g,
        (__attribute__((address_space(3))) void*)l, 16, 0, 0);
}

// ---------------------------------------------------------------------------
// KPREP_X: NCHW f32 -> NHWC bf16 ([b][px][ci])  (linear, used for x)
// ---------------------------------------------------------------------------
__global__ __launch_bounds__(256) void kprep_x(const float* __restrict__ x,
        ushort* __restrict__ xbf)
{
    int blk = blockIdx.x;
    int b = blk >> 13;
    int rest = blk & 8191;
    int ci0 = (rest & 7) * 32;
    int n0 = (rest >> 3) * 64;
    int t = threadIdx.x;
    __shared__ uint u[16][65];
    int px = t & 63, cig = t >> 6;
    const float* yb = x + (((size_t)(b * 256 + ci0 + cig * 8)) << 16) + n0 + px;
    #pragma unroll
    for (int jj = 0; jj < 4; ++jj) {
        float v0 = yb[((size_t)(jj * 2)) << 16];
        float v1 = yb[((size_t)(jj * 2 + 1)) << 16];
        u[cig * 4 + jj][px] = pack2(v0, v1);
    }
    __syncthreads();
    uint* out32 = (uint*)xbf;
    int pr = t & 15, pg = t >> 4;
    #pragma unroll
    for (int g2 = 0; g2 < 4; ++g2) {
        int ppx = g2 * 16 + pg;
        size_t uidx = (((size_t)(b * 65536 + n0 + ppx) * 256 + ci0) >> 1) + pr;
        out32[uidx] = u[pr][ppx];
    }
}

// ---------------------------------------------------------------------------
// KPREP_QK: Wqkb[64][256] = bf16( rows 0-31: wq, rows 32-63: wk )
// ---------------------------------------------------------------------------
__global__ __launch_bounds__(256) void kprep_qk(const float* __restrict__ wq,
        const float* __restrict__ wk, ushort* __restrict__ Wqkb)
{
    int idx = blockIdx.x * 256 + threadIdx.x;   // 16384
    int oc = idx >> 8, ci = idx & 255;
    float v = (oc < 32) ? wq[oc * 256 + ci] : wk[(oc - 32) * 256 + ci];
    Wqkb[idx] = f2bf(v);
}

// ---------------------------------------------------------------------------
// K1 (MFMA): Q,K = 1x1 conv (32 ch each) + per-pixel channel L2-norm.
// 64-px tiles: LDS 64KB -> 2 blocks/CU. 8 waves = 2(q/k) x 4(16px).
// ---------------------------------------------------------------------------
__global__ __launch_bounds__(512, 2) void k1_mfma(
        const ushort* __restrict__ xbf, const ushort* __restrict__ Wqkb,
        const float* __restrict__ bq, const float* __restrict__ bk,
        float* __restrict__ Qo, float* __restrict__ Ko)
{
    int blk = blockIdx.x;
    int b = blk >> 10;
    int px0 = (blk & 1023) << 6;
    int t = threadIdx.x;
    int lane = t & 63, w = t >> 6;
    int wr = w >> 2;       // 0: q rows, 1: k rows
    int wc = w & 3;        // px quarter (16 px)

    __shared__ ushort sW[64 * 256];    // 32KB [oc][ci] swizzled
    __shared__ ushort sX[64 * 256];    // 32KB [px][ci] swizzled

    #pragma unroll
    for (int p = 0; p < 4; ++p) {
        int m = p * 512 + t;
        int row = m >> 5, ch = m & 31;
        const ushort* g = Wqkb + row * 256 + ((ch ^ (row & 7)) << 3);
        gload16(g, (char*)sW + p * 8192 + w * 1024);
    }
    const ushort* xb = xbf + (size_t)(b * 65536 + px0) * 256;
    #pragma unroll
    for (int p = 0; p < 4; ++p) {
        int m = p * 512 + t;
        int row = m >> 5, ch = m & 31;
        const ushort* g = xb + row * 256 + ((ch ^ (row & 7)) << 3);
        gload16(g, (char*)sX + p * 8192 + w * 1024);
    }
    __syncthreads();

    int l15 = lane & 15, l4 = lane >> 4;
    floatx4 acc[2];
    acc[0] = {0.f, 0.f, 0.f, 0.f};
    acc[1] = {0.f, 0.f, 0.f, 0.f};

    #pragma unroll
    for (int ks = 0; ks < 8; ++ks) {
        int cidx = ks * 4 + l4;
        short8 af[2];
        #pragma unroll
        for (int m2 = 0; m2 < 2; ++m2) {
            int row = wr * 32 + m2 * 16 + l15;
            af[m2] = *(const short8*)((const char*)sW + row * 512 + ((cidx ^ (row & 7)) << 4));
        }
        int brow = wc * 16 + l15;
        short8 bf_ = *(const short8*)((const char*)sX + brow * 512 + ((cidx ^ (brow & 7)) << 4));
        #pragma unroll
        for (int m2 = 0; m2 < 2; ++m2)
            acc[m2] = __builtin_amdgcn_mfma_f32_16x16x32_bf16(af[m2], bf_, acc[m2], 0, 0, 0);
    }

    const float* bias = wr ? bk : bq;
    float* outp = wr ? Ko : Qo;
    float v[2][4];
    float s = 0.f;
    #pragma unroll
    for (int m2 = 0; m2 < 2; ++m2)
        #pragma unroll
        for (int r = 0; r < 4; ++r) {
            float vv = acc[m2][r] + bias[m2 * 16 + l4 * 4 + r];
            v[m2][r] = vv;
            s += vv * vv;
        }
    s += __shfl_xor(s, 16);
    s += __shfl_xor(s, 32);
    float rn = rsqrtf(s);
    int px = px0 + wc * 16 + l15;
    #pragma unroll
    for (int m2 = 0; m2 < 2; ++m2)
        #pragma unroll
        for (int r = 0; r < 4; ++r) {
            int oc = m2 * 16 + l4 * 4 + r;
            outp[((size_t)(b * 32 + oc) << 16) + px] = v[m2][r] * rn;
        }
}

// ---------------------------------------------------------------------------
// K2: partial KX/xsum/Ksum per block. Reads xbf (NHWC bf16) directly.
// ---------------------------------------------------------------------------
__global__ __launch_bounds__(256) void k2_kx(const ushort* __restrict__ xbf,
        const float* __restrict__ Kn, float* __restrict__ KXp,
        float* __restrict__ xsp, float* __restrict__ ksp)
{
    int blk = blockIdx.x;
    int b = blk >> 9;
    int blkl = blk & 511;
    int t = threadIdx.x;               // t = c
    int n0 = blkl * 128;
    __shared__ float kT[32][128];      // 16KB
    for (int i = t; i < 4096; i += 256) {
        int m = i >> 7, p = i & 127;
        kT[m][p] = Kn[((size_t)(b * 32 + m) << 16) + n0 + p];
    }
    __syncthreads();
    float acc[32];
    #pragma unroll
    for (int m = 0; m < 32; ++m) acc[m] = 0.f;
    float xs = 0.f;
    const ushort* xb = xbf + (((size_t)(b * 65536 + n0)) << 8) + t;
    for (int p4 = 0; p4 < 32; ++p4) {
        float xv0 = bf2f(xb[(size_t)(p4 * 4 + 0) << 8]);
        float xv1 = bf2f(xb[(size_t)(p4 * 4 + 1) << 8]);
        float xv2 = bf2f(xb[(size_t)(p4 * 4 + 2) << 8]);
        float xv3 = bf2f(xb[(size_t)(p4 * 4 + 3) << 8]);
        xs += xv0 + xv1 + xv2 + xv3;
        #pragma unroll
        for (int m = 0; m < 32; ++m) {
            floatx4 kv = *(const floatx4*)&kT[m][p4 * 4];
            acc[m] += kv[0] * xv0 + kv[1] * xv1 + kv[2] * xv2 + kv[3] * xv3;
        }
    }
    xsp[blk * 256 + t] = xs;
    if (t < 32) {
        float ks = 0.f;
        for (int p = 0; p < 128; ++p) ks += kT[t][p];
        ksp[blk * 32 + t] = ks;
    }
    #pragma unroll
    for (int m = 0; m < 32; ++m) KXp[(size_t)blk * 8192 + m * 256 + t] = acc[m];
}

// ---------------------------------------------------------------------------
// K2R: reduce partials -> KX, xsum, Ksum
// ---------------------------------------------------------------------------
__global__ __launch_bounds__(256) void k2r(const float* __restrict__ KXp,
        const float* __restrict__ xsp, const float* __restrict__ ksp,
        float* __restrict__ KX, float* __restrict__ xsum, float* __restrict__ Ksum)
{
    int blk = blockIdx.x, t = threadIdx.x;
    if (blk < 64) {
        int gidx = blk * 256 + t;
        int b = gidx >> 13, idx = gidx & 8191;
        float s = 0.f;
        for (int ch = 0; ch < 512; ++ch)
            s += KXp[(size_t)((b << 9) + ch) * 8192 + idx];
        KX[gidx] = s;
    } else if (blk < 66) {
        int b = blk - 64;
        float s = 0.f;
        for (int ch = 0; ch < 512; ++ch)
            s += xsp[((b << 9) + ch) * 256 + t];
        xsum[b * 256 + t] = s;
    } else {
        int b = blk - 66;
        if (t < 32) {
            float s = 0.f;
            for (int ch = 0; ch < 512; ++ch)
                s += ksp[((b << 9) + ch) * 32 + t];
            Ksum[b * 32 + t] = s;
        }
    }
}

// ---------------------------------------------------------------------------
// K3: matrix/vsum from KX, xsum, Ksum
// ---------------------------------------------------------------------------
__global__ __launch_bounds__(256) void k3_mat(const float* __restrict__ wv,
        const float* __restrict__ bv, const float* __restrict__ KX,
        const float* __restrict__ xsum, const float* __restrict__ Ksum,
        float* __restrict__ matrix, float* __restrict__ vsum)
{
    int b = blockIdx.x, t = threadIdx.x;
    __shared__ float sx[256];
    __shared__ float sk[32];
    __shared__ float skx[32][256];
    __shared__ float wT[256][65];
    sx[t] = xsum[b * 256 + t];
    if (t < 32) sk[t] = Ksum[b * 32 + t];
    for (int j = 0; j < 32; ++j) skx[j][t] = KX[(b * 32 + j) * 256 + t];
    float vs = bv[t] * (float)Nc;
    float mv[32];
    #pragma unroll
    for (int m = 0; m < 32; ++m) mv[m] = 0.f;
    for (int cc0 = 0; cc0 < 256; cc0 += 64) {
        __syncthreads();
        for (int i = 0; i < 64; ++i) {
            int c = i * 4 + (t >> 6);
            wT[c][t & 63] = wv[(size_t)c * 256 + cc0 + (t & 63)];
        }
        __syncthreads();
        for (int ccl = 0; ccl < 64; ++ccl) {
            float w = wT[t][ccl];
            int cc = cc0 + ccl;
            vs += w * sx[cc];
            #pragma unroll
            for (int m = 0; m < 32; ++m) mv[m] += w * skx[m][cc];
        }
    }
    vsum[b * 256 + t] = vs;
    float bvt = bv[t];
    for (int m = 0; m < 32; ++m) matrix[(b * 32 + m) * 256 + t] = mv[m] + bvt * sk[m];
}

// ---------------------------------------------------------------------------
// K4: z = x + gamma*(vsum + Q^T matrix)*tailor -> bf16 NHWC, pre-swizzled
// ---------------------------------------------------------------------------
__global__ __launch_bounds__(256) void k4_z(const float* __restrict__ x,
        const float* __restrict__ Q, const float* __restrict__ matrix,
        const float* __restrict__ vsum, const float* __restrict__ Ksum,
        const float* __restrict__ gamma_p, ushort* __restrict__ zbf)
{
    int b = blockIdx.x >> 10;
    int n0 = (blockIdx.x & 1023) * 64;
    int t = threadIdx.x;
    int px = t & 63, g = t >> 6;
    __shared__ float qT[32][64];
    __shared__ float mat[32][256];
    __shared__ float vs[256];
    __shared__ float tail[64];
    __shared__ float sk[32];
    __shared__ uint zsh[64 * 128];   // [px][cp] bf16 pairs, swizzled (32KB)
    #pragma unroll
    for (int j = 0; j < 8; ++j) {
        int m = j * 4 + g;
        qT[m][px] = Q[((size_t)b * 32 + m) * Nc + n0 + px];
    }
    for (int j = 0; j < 32; ++j) {
        int idx = j * 256 + t;
        (&mat[0][0])[idx] = matrix[b * 8192 + idx];
    }
    vs[t] = vsum[b * 256 + t];
    if (t < 32) sk[t] = Ksum[b * 32 + t] + LA_EPS;
    __syncthreads();
    if (t < 64) {
        float s = 0.f;
        #pragma unroll
        for (int m = 0; m < 32; ++m) s += qT[m][t] * sk[m];
        tail[t] = 1.0f / ((float)Nc + s);
    }
    __syncthreads();
    float gamma = gamma_p[0];
    float tl = tail[px];
    for (int l = 0; l < 64; l += 2) {
        int c0 = g * 64 + l;
        float s0 = vs[c0], s1 = vs[c0 + 1];
        #pragma unroll
        for (int m = 0; m < 32; ++m) {
            float qv = qT[m][px];
            s0 += qv * mat[m][c0];
            s1 += qv * mat[m][c0 + 1];
        }
        size_t idx0 = (size_t)(b * 256 + c0) * Nc + n0 + px;
        float z0 = x[idx0] + gamma * s0 * tl;
        float z1 = x[idx0 + Nc] + gamma * s1 * tl;
        int cp = c0 >> 1;
        zsh[(px * 512 + (((cp >> 2) ^ (px & 7)) << 4) + (cp & 3) * 4) >> 2] = pack2(z0, z1);
    }
    __syncthreads();
    const uint4* zl = (const uint4*)zsh;
    uint4* gz = (uint4*)(zbf + (((size_t)(b * 65536 + n0)) << 8));
    #pragma unroll
    for (int i2 = 0; i2 < 8; ++i2)
        gz[i2 * 256 + t] = zl[i2 * 256 + t];
}

// ---------------------------------------------------------------------------
// KPREP_Y: y (NCHW f32) -> ybf (padded NHWC bf16, [b][258][258][256])
// ---------------------------------------------------------------------------
__global__ __launch_bounds__(256) void kprep_y(const float* __restrict__ y,
        ushort* __restrict__ ybf)
{
    int blk = blockIdx.x;
    int b = blk >> 13;
    int rest = blk & 8191;
    int ci0 = (rest & 7) * 32;
    int n0 = (rest >> 3) * 64;
    int row = n0 >> 8, x = n0 & 255;
    int t = threadIdx.x;
    __shared__ uint u[16][65];
    int px = t & 63, cig = t >> 6;
    const float* yb = y + (((size_t)(b * 256 + ci0 + cig * 8)) << 16) + n0 + px;
    #pragma unroll
    for (int jj = 0; jj < 4; ++jj) {
        float v0 = yb[((size_t)(jj * 2)) << 16];
        float v1 = yb[((size_t)(jj * 2 + 1)) << 16];
        u[cig * 4 + jj][px] = pack2(v0, v1);
    }
    __syncthreads();
    uint* out32 = (uint*)ybf;
    size_t pbase = (size_t)(row + 1) * 258 + (x + 1);
    int pr = t & 15, pg = t >> 4;
    #pragma unroll
    for (int g2 = 0; g2 < 4; ++g2) {
        int ppx = g2 * 16 + pg;
        size_t uidx = (((size_t)b * 258 * 258 * 256 + (pbase + ppx) * 256 + ci0) >> 1) + pr;
        out32[uidx] = u[pr][ppx];
    }
}

// ---------------------------------------------------------------------------
// KPREP_W: Wb[tap][co][ci] = bf16(wl1*s1 + (tap==4)*wl2*s2)
// ---------------------------------------------------------------------------
__global__ __launch_bounds__(256) void kprep_w(const float* __restrict__ wl1,
        const float* __restrict__ s1, const float* __restrict__ wl2,
        const float* __restrict__ s2, ushort* __restrict__ Wb)
{
    int idx = blockIdx.x * 256 + threadIdx.x;
    int tp = idx >> 16;
    int r = idx & 65535;
    int co = r >> 8;
    float v = wl1[(size_t)r * 9 + tp] * s1[co];
    if (tp == 4) v += wl2[r] * s2[co];
    Wb[idx] = f2bf(v);
}

// ---------------------------------------------------------------------------
// KPREP_QW: Wqb = bf16(wqkv), q rows pre-scaled by 0.25
// ---------------------------------------------------------------------------
__global__ __launch_bounds__(256) void kprep_qw(const float* __restrict__ wqkv,
        ushort* __restrict__ Wqb)
{
    int idx = blockIdx.x * 256 + threadIdx.x;
    float v = wqkv[idx];
    if (idx < 65536) v *= 0.25f;
    Wqb[idx] = f2bf(v);
}

// ---------------------------------------------------------------------------
// KPREP_PW / KPREP_REL
// ---------------------------------------------------------------------------
__global__ __launch_bounds__(256) void kprep_pw(const float* __restrict__ wpw,
        ushort* __restrict__ Wpwb)
{
    int idx = blockIdx.x * 256 + threadIdx.x;
    Wpwb[idx] = f2bf(wpw[idx]);
}

__global__ __launch_bounds__(256) void kprep_rel(const float* __restrict__ rel,
        ushort* __restrict__ relbf)
{
    int idx = blockIdx.x * 256 + threadIdx.x;
    if (idx < 3600) relbf[idx] = f2bf(rel[idx]);
}

// ---------------------------------------------------------------------------
// K5 (MFMA): L = conv3x3(ybf, Wc) + bias
// ---------------------------------------------------------------------------
__global__ __launch_bounds__(512, 2) void k5_mfma(
        const ushort* __restrict__ ybf, const ushort* __restrict__ Wb,
        const float* __restrict__ b1, const float* __restrict__ b2,
        float* __restrict__ L)
{
    int blk = blockIdx.x;
    int b = blk >> 9;
    int y0 = (blk >> 1) & 255;
    int x0 = (blk & 1) << 7;
    int t = threadIdx.x;
    int lane = t & 63;
    int w = t >> 6;
    int wr = w >> 1;
    int wc = w & 1;

    __shared__ ushort sW[256 * 64];
    __shared__ ushort sY[128 * 64];

    floatx4 acc[4][4];
    #pragma unroll
    for (int m = 0; m < 4; ++m)
        #pragma unroll
        for (int n = 0; n < 4; ++n)
            acc[m][n] = {0.f, 0.f, 0.f, 0.f};

    const ushort* yb = ybf + (size_t)b * 258 * 258 * 256;
    int ldsWbase = w * 64 * 16;
    int ldsYbase = w * 64 * 16;

    for (int tp = 0; tp < 9; ++tp) {
        int dy = tp / 3 - 1, dx = tp % 3 - 1;
        const ushort* yrow = yb + ((size_t)(y0 + dy + 1) * 258 + (x0 + dx + 1)) * 256;
        const ushort* wtap = Wb + tp * 65536;
        for (int cb = 0; cb < 4; ++cb) {
            int ci0 = cb * 64;
            __syncthreads();
            #pragma unroll
            for (int p = 0; p < 4; ++p) {
                int m = p * 512 + t;
                int row = m >> 3, ch = m & 7;
                const ushort* g = wtap + row * 256 + ci0 + ((ch ^ (row & 7)) << 3);
                gload16(g, (char*)sW + p * 512 * 16 + ldsWbase);
            }
            #pragma unroll
            for (int p = 0; p < 2; ++p) {
                int m = p * 512 + t;
                int pxr = m >> 3, ch = m & 7;
                const ushort* g = yrow + (size_t)pxr * 256 + ci0 + ((ch ^ (pxr & 7)) << 3);
                gload16(g, (char*)sY + p * 512 * 16 + ldsYbase);
            }
            __syncthreads();
            #pragma unroll
            for (int kk = 0; kk < 2; ++kk) {
                int chunkb = kk * 4 + (lane >> 4);
                short8 afr[4];
                #pragma unroll
                for (int m2 = 0; m2 < 4; ++m2) {
                    int row = wr * 64 + m2 * 16 + (lane & 15);
                    int ch = chunkb ^ (row & 7);
                    afr[m2] = *(const short8*)((const char*)sW + row * 128 + ch * 16);
                }
                #pragma unroll
                for (int n2 = 0; n2 < 4; ++n2) {
                    int row = wc * 64 + n2 * 16 + (lane & 15);
                    int ch = chunkb ^ (row & 7);
                    short8 bfr = *(const short8*)((const char*)sY + row * 128 + ch * 16);
                    #pragma unroll
                    for (int m2 = 0; m2 < 4; ++m2)
                        acc[m2][n2] = __builtin_amdgcn_mfma_f32_16x16x32_bf16(
                            afr[m2], bfr, acc[m2][n2], 0, 0, 0);
                }
            }
        }
    }
    int pxb = x0 + wc * 64 + (lane & 15);
    #pragma unroll
    for (int m2 = 0; m2 < 4; ++m2) {
        int cobase = wr * 64 + m2 * 16 + (lane >> 4) * 4;
        #pragma unroll
        for (int r = 0; r < 4; ++r) {
            int co = cobase + r;
            float bias = b1[co] + b2[co];
            float* dst = L + (((size_t)(b * 256 + co)) << 16) + y0 * 256 + pxb;
            #pragma unroll
            for (int n2 = 0; n2 < 4; ++n2)
                dst[n2 * 16] = acc[m2][n2][r] + bias;
        }
    }
}

// ---------------------------------------------------------------------------
// K6 (MFMA, fused): qkv + window attention, TWO adjacent windows per block.
// Round-9 write schedule + in-register shfl transposes + FUSED single-pass
// qkv GEMMs (one bz read feeds q/k as B-operand and v as A-operand) +
// bf16 rel table (conflict fix). LDS ~73KB.
// ---------------------------------------------------------------------------
__global__ __launch_bounds__(512, 2) void k6_mfma(const ushort* __restrict__ zbf,
        const ushort* __restrict__ Wqb, const ushort* __restrict__ relbf,
        float* __restrict__ A)
{
    int blk = blockIdx.x;
    int wxp = blk & 15, wy = (blk >> 4) & 31, b = blk >> 9;
    int t = threadIdx.x;
    int lane = t & 63;
    int w = t >> 6;
    int win = w >> 2;      // waves 0-3: window 0, waves 4-7: window 1
    int wq4 = w & 3;       // 4 heads per wave

    __shared__ ushort zT[128 * 256];     // 64KB, swizzle baked in memory
    __shared__ ushort srel[3600];        // 7.2KB bf16

    char* zTc = (char*)zT;

    // ---- stage both z windows via linear global_load_lds (zbf pre-swizzled) ----
    {
        const ushort* zb = zbf + (((size_t)b) << 16) * 256;
        #pragma unroll
        for (int p = 0; p < 8; ++p) {
            int m = p * 512 + t;
            int row = m >> 5, ch = m & 31;
            int win2 = row >> 6, px = row & 63;
            int gy = wy * 8 + (px >> 3);
            int gx = (wxp * 2 + win2) * 8 + (px & 7);
            const ushort* g = zb + (((size_t)(gy * 256 + gx)) << 8) + ch * 8;
            gload16(g, zTc + p * 8192 + w * 1024);
        }
    }
    for (int i = t; i < 3600; i += 512) srel[i] = relbf[i];
    __syncthreads();

    int l15 = lane & 15, l4 = lane >> 4;
    int l31 = lane & 31, l5 = lane >> 5;
    bool hilane = (l5 != 0);
    bool hi16 = (l31 & 16) != 0;
    int srcA = (l5 << 5) + (l31 & 15);
    int srcB = srcA + 16;
    int pxbase = win * 64;

    for (int hrep = 0; hrep < 4; ++hrep) {
        int h = wq4 * 4 + hrep;

        // ---- FUSED qkv: one bz read per (ks,n) feeds all three GEMMs ----
        floatx4 qacc[4] = {}, kacc[4] = {}, vacc[4] = {};
        #pragma unroll
        for (int ks = 0; ks < 8; ++ks) {
            short8 awq = *(const short8*)(Wqb + ((h * 16 + l15) << 8) + ks * 32 + (l4 << 3));
            short8 awk = *(const short8*)(Wqb + ((256 + h * 16 + l15) << 8) + ks * 32 + (l4 << 3));
            short8 bwv = *(const short8*)(Wqb + ((512 + h * 16 + l15) << 8) + ks * 32 + (l4 << 3));
            #pragma unroll
            for (int n = 0; n < 4; ++n) {
                int px = n * 16 + l15;
                short8 bz = *(const short8*)(zTc + (pxbase + px) * 512 + (((ks * 4 + l4) ^ (px & 7)) << 4));
                qacc[n] = __builtin_amdgcn_mfma_f32_16x16x32_bf16(awq, bz, qacc[n], 0, 0, 0);
                kacc[n] = __builtin_amdgcn_mfma_f32_16x16x32_bf16(awk, bz, kacc[n], 0, 0, 0);
                vacc[n] = __builtin_amdgcn_mfma_f32_16x16x32_bf16(bz, bwv, vacc[n], 0, 0, 0);
            }
        }

        // reg-transpose -> bq[it]: lane(l31,l5) = q[px=it*32+l31][d=8*l5+e]
        Frag bq[2];
        {
            uint plo[4], phi[4];
            #pragma unroll
            for (int n = 0; n < 4; ++n) {
                plo[n] = pack2(qacc[n][0], qacc[n][1]);
                phi[n] = pack2(qacc[n][2], qacc[n][3]);
            }
            #pragma unroll
            for (int it = 0; it < 2; ++it) {
                uint a0 = (uint)__shfl((int)plo[it * 2], srcA), a1 = (uint)__shfl((int)plo[it * 2 + 1], srcA);
                uint b0 = (uint)__shfl((int)phi[it * 2], srcA), b1 = (uint)__shfl((int)phi[it * 2 + 1], srcA);
                uint c0 = (uint)__shfl((int)plo[it * 2], srcB), c1 = (uint)__shfl((int)plo[it * 2 + 1], srcB);
                uint d0 = (uint)__shfl((int)phi[it * 2], srcB), d1 = (uint)__shfl((int)phi[it * 2 + 1], srcB);
                bq[it].u[0] = hi16 ? a1 : a0;
                bq[it].u[1] = hi16 ? b1 : b0;
                bq[it].u[2] = hi16 ? c1 : c0;
                bq[it].u[3] = hi16 ? d1 : d0;
            }
        }
        Frag ak[2];
        {
            uint plo[4], phi[4];
            #pragma unroll
            for (int n = 0; n < 4; ++n) {
                plo[n] = pack2(kacc[n][0], kacc[n][1]);
                phi[n] = pack2(kacc[n][2], kacc[n][3]);
            }
            #pragma unroll
            for (int jt = 0; jt < 2; ++jt) {
                uint a0 = (uint)__shfl((int)plo[jt * 2], srcA), a1 = (uint)__shfl((int)plo[jt * 2 + 1], srcA);
                uint b0 = (uint)__shfl((int)phi[jt * 2], srcA), b1 = (uint)__shfl((int)phi[jt * 2 + 1], srcA);
                uint c0 = (uint)__shfl((int)plo[jt * 2], srcB), c1 = (uint)__shfl((int)plo[jt * 2 + 1], srcB);
                uint d0 = (uint)__shfl((int)phi[jt * 2], srcB), d1 = (uint)__shfl((int)phi[jt * 2 + 1], srcB);
                ak[jt].u[0] = hi16 ? a1 : a0;
                ak[jt].u[1] = hi16 ? b1 : b0;
                ak[jt].u[2] = hi16 ? c1 : c0;
                ak[jt].u[3] = hi16 ? d1 : d0;
            }
        }
        // v was computed TRANSPOSED (z as A-operand): vacc[m] rows are d, cols px
        Frag av[4];
        {
            uint v01[4], v23[4];
            #pragma unroll
            for (int m = 0; m < 4; ++m) {
                v01[m] = pack2(vacc[m][0], vacc[m][1]);
                v23[m] = pack2(vacc[m][2], vacc[m][3]);
            }
            #pragma unroll
            for (int jc = 0; jc < 4; ++jc) {
                av[jc].u[0] = (uint)__shfl((int)v01[jc], srcA);
                av[jc].u[1] = (uint)__shfl((int)v23[jc], srcA);
                av[jc].u[2] = (uint)__shfl((int)v01[jc], srcB);
                av[jc].u[3] = (uint)__shfl((int)v23[jc], srcB);
            }
        }

        // ---- per-it: S^T, softmax, PV ----
        #pragma unroll
        for (int it = 0; it < 2; ++it) {
            floatx16 st[2];
            #pragma unroll
            for (int jt = 0; jt < 2; ++jt) {
                floatx16 zc = {};
                st[jt] = __builtin_amdgcn_mfma_f32_32x32x16_bf16(ak[jt].v, bq[it].v, zc, 0, 0, 0);
            }
            int i = it * 32 + l31;
            int Ai = (i >> 3) * 15 + (i & 7) + 112;
            float mx = -1e30f;
            #pragma unroll
            for (int jt = 0; jt < 2; ++jt)
                #pragma unroll
                for (int r = 0; r < 16; ++r) {
                    int j = jt * 32 + (r & 3) + 8 * (r >> 2) + 4 * l5;
                    int Bjr = (j >> 3) * 15 + (j & 7);
                    float s = st[jt][r] + bf2f(srel[(Ai - Bjr) * 16 + h]);
                    st[jt][r] = s;
                    mx = fmaxf(mx, s);
                }
            mx = fmaxf(mx, __shfl_xor(mx, 32));
            float sum = 0.f;
            #pragma unroll
            for (int jt = 0; jt < 2; ++jt)
                #pragma unroll
                for (int r = 0; r < 16; ++r) {
                    float e = __expf(st[jt][r] - mx);
                    st[jt][r] = e;
                    sum += e;
                }
            sum += __shfl_xor(sum, 32);
            float rinv = 1.0f / sum;

            floatx16 ot = {};
            #pragma unroll
            for (int jc = 0; jc < 4; ++jc) {
                int jt = jc >> 1, rb = (jc & 1) * 8;
                uint u0 = pack2(st[jt][rb + 0], st[jt][rb + 1]);
                uint u1 = pack2(st[jt][rb + 2], st[jt][rb + 3]);
                uint u2 = pack2(st[jt][rb + 4], st[jt][rb + 5]);
                uint u3 = pack2(st[jt][rb + 6], st[jt][rb + 7]);
                uint s0 = (uint)__shfl_xor((int)u0, 32);
                uint s1 = (uint)__shfl_xor((int)u1, 32);
                uint s2 = (uint)__shfl_xor((int)u2, 32);
                uint s3 = (uint)__shfl_xor((int)u3, 32);
                Frag bf;
                bf.u[0] = hilane ? s2 : u0;
                bf.u[1] = hilane ? s3 : u1;
                bf.u[2] = hilane ? u2 : s0;
                bf.u[3] = hilane ? u3 : s1;
                ot = __builtin_amdgcn_mfma_f32_32x32x16_bf16(av[jc].v, bf.v, ot, 0, 0, 0);
            }
            int gy = wy * 8 + (i >> 3);
            int gx = (wxp * 2 + win) * 8 + (i & 7);
            float* Ab = A + (((size_t)(b * 256 + h * 16)) << 16) + gy * 256 + gx;
            #pragma unroll
            for (int r = 0; r < 8; ++r) {
                int d = (r & 3) + 8 * (r >> 2) + 4 * l5;
                Ab[(size_t)d << 16] = ot[r] * rinv;
            }
        }
    }
}

// ---------------------------------------------------------------------------
// K7 (tiled): L += avgpoolV(A) + avgpoolH(A). 64x64 tile + 7-halo in LDS.
// ---------------------------------------------------------------------------
__global__ __launch_bounds__(256) void k7_pool(const float* __restrict__ A,
        float* __restrict__ L)
{
    int blk = blockIdx.x;
    int tile = blk & 15;
    int c = (blk >> 4) & 255;
    int b = blk >> 12;
    int ty = (tile >> 2) * 64, tx = (tile & 3) * 64;
    int t = threadIdx.x;
    __shared__ float aT[71][73];
    const float* Ac = A + ((size_t)(b * 256 + c) << 16);
    for (int i = t; i < 71 * 71; i += 256) {
        int rr = i / 71, cc = i - rr * 71;
        int gy = ty + rr - 3, gx = tx + cc - 3;
        float v = 0.f;
        if (gy >= 0 && gy <= 256 && gx >= 0 && gx <= 256) {
            int ry = (gy == 256) ? 254 : gy;
            int rx = (gx == 256) ? 254 : gx;
            v = Ac[ry * 256 + rx];
        }
        aT[rr][cc] = v;
    }
    __syncthreads();
    int jj = t & 63;
    int oy0 = (t >> 6) * 16;
    float* Lc = L + ((size_t)(b * 256 + c) << 16);
    #pragma unroll 4
    for (int dy = 0; dy < 16; ++dy) {
        int oi = oy0 + dy;
        float sv = 0.f, sh = 0.f;
        #pragma unroll
        for (int u = 0; u < 8; ++u) {
            sv += aT[oi + u][jj + 3];
            sh += aT[oi + 3][jj + u];
        }
        int idx = (ty + oi) * 256 + tx + jj;
        Lc[idx] += 0.125f * (sv + sh);
    }
}

// ---------------------------------------------------------------------------
// K8 (tiled): D(bf16) = sp * dwconv8x8(pad_out(L), wdw, pad=3) + bp
// ---------------------------------------------------------------------------
__global__ __launch_bounds__(256) void k8_dw(const float* __restrict__ P,
        const float* __restrict__ wdw, const float* __restrict__ sp,
        const float* __restrict__ bp, ushort* __restrict__ D)
{
    int blk = blockIdx.x;
    int tile = blk & 63;
    int c = (blk >> 6) & 255;
    int b = blk >> 14;
    int ty = (tile >> 3) * 32, tx = (tile & 7) * 32;
    int t = threadIdx.x;
    __shared__ float pT[39][40];
    __shared__ float wT[64];
    const float* Pc = P + ((size_t)(b * 256 + c) << 16);
    for (int i = t; i < 39 * 40; i += 256) {
        int rr = i / 40, cc = i - rr * 40;
        int gy = ty + rr - 3, gx = tx + cc - 3;
        float v = 0.f;
        if (gy >= 0 && gy <= 256 && gx >= 0 && gx <= 256) {
            int ry = (gy == 256) ? 254 : gy;
            int rx = (gx == 256) ? 254 : gx;
            v = Pc[ry * 256 + rx];
        }
        pT[rr][cc] = v;
    }
    if (t < 64) wT[t] = wdw[c * 64 + t];
    __syncthreads();
    int jj = t & 31;
    int oy0 = (t >> 5) * 4;
    float spc = sp[c], bpc = bp[c];
    ushort* Dc = D + ((size_t)(b * 256 + c) << 16);
    #pragma unroll
    for (int dy = 0; dy < 4; ++dy) {
        int oi = oy0 + dy;
        float acc = 0.f;
        #pragma unroll
        for (int u = 0; u < 8; ++u)
            #pragma unroll
            for (int v = 0; v < 8; ++v)
                acc += wT[u * 8 + v] * pT[oi + u][jj + v];
        Dc[(ty + oi) * 256 + tx + jj] = f2bf(spc * acc + bpc);
    }
}

// ---------------------------------------------------------------------------
// K9 (MFMA): out[co][px] = sum_ci Wpw[co][ci] * D[ci][px]
// ---------------------------------------------------------------------------
__global__ __launch_bounds__(512, 2) void k9_mfma(
        const ushort* __restrict__ D, const ushort* __restrict__ Wpwb,
        float* __restrict__ out)
{
    int blk = blockIdx.x;
    int b = blk >> 9;
    int px0 = (blk & 511) << 7;
    int t = threadIdx.x;
    int lane = t & 63;
    int w = t >> 6;
    int wr = w >> 1, wc = w & 1;

    __shared__ ushort sW[256 * 64];
    __shared__ ushort sD[128 * 64];

    floatx4 acc[4][4];
    #pragma unroll
    for (int m = 0; m < 4; ++m)
        #pragma unroll
        for (int n = 0; n < 4; ++n)
            acc[m][n] = {0.f, 0.f, 0.f, 0.f};

    int ldsWbase = w * 64 * 16;

    for (int cb = 0; cb < 4; ++cb) {
        int ci0 = cb * 64;
        __syncthreads();
        #pragma unroll
        for (int p = 0; p < 4; ++p) {
            int m = p * 512 + t;
            int row = m >> 3, ch = m & 7;
            const ushort* g = Wpwb + row * 256 + ci0 + ((ch ^ (row & 7)) << 3);
            gload16(g, (char*)sW + p * 512 * 16 + ldsWbase);
        }
        #pragma unroll
        for (int p = 0; p < 2; ++p) {
            int m = p * 512 + t;
            int ci = m & 63, pxb = (m >> 6) * 8;
            short8 v = *(const short8*)(D + ((size_t)(b * 256 + ci0 + ci) << 16) + px0 + pxb);
            #pragma unroll
            for (int k2 = 0; k2 < 8; ++k2) {
                int px = pxb + k2;
                *(ushort*)((char*)sD + px * 128 + (((ci >> 3) ^ (px & 7)) << 4) + (ci & 7) * 2) =
                    (ushort)v[k2];
            }
        }
        __syncthreads();
        #pragma unroll
        for (int kk = 0; kk < 2; ++kk) {
            int chunkb = kk * 4 + (lane >> 4);
            short8 afr[4];
            #pragma unroll
            for (int m2 = 0; m2 < 4; ++m2) {
                int row = wr * 64 + m2 * 16 + (lane & 15);
                int ch = chunkb ^ (row & 7);
                afr[m2] = *(const short8*)((const char*)sW + row * 128 + ch * 16);
            }
            #pragma unroll
            for (int n2 = 0; n2 < 4; ++n2) {
                int row = wc * 64 + n2 * 16 + (lane & 15);
                int ch = chunkb ^ (row & 7);
                short8 bfr = *(const short8*)((const char*)sD + row * 128 + ch * 16);
                #pragma unroll
                for (int m2 = 0; m2 < 4; ++m2)
                    acc[m2][n2] = __builtin_amdgcn_mfma_f32_16x16x32_bf16(
                        afr[m2], bfr, acc[m2][n2], 0, 0, 0);
            }
        }
    }
    int pxb = px0 + wc * 64 + (lane & 15);
    #pragma unroll
    for (int m2 = 0; m2 < 4; ++m2) {
        int cobase = wr * 64 + m2 * 16 + (lane >> 4) * 4;
        #pragma unroll
        for (int r = 0; r < 4; ++r) {
            int co = cobase + r;
            float* dst = out + (((size_t)(b * 256 + co)) << 16) + pxb;
            #pragma unroll
            for (int n2 = 0; n2 < 4; ++n2)
                dst[n2 * 16] = acc[m2][n2][r];
        }
    }
}

// ---------------------------------------------------------------------------
extern "C" void kernel_launch(void* const* d_in, const int* in_sizes, int n_in,
                              void* d_out, int out_size, void* d_ws, size_t ws_size,
                              hipStream_t stream)
{
    (void)in_sizes; (void)n_in; (void)out_size; (void)ws_size;
    const float* x     = (const float*)d_in[0];
    const float* y     = (const float*)d_in[1];
    const float* gamma = (const float*)d_in[2];
    const float* la_wq = (const float*)d_in[3];
    const float* la_bq = (const float*)d_in[4];
    const float* la_wk = (const float*)d_in[5];
    const float* la_bk = (const float*)d_in[6];
    const float* la_wv = (const float*)d_in[7];
    const float* la_bv = (const float*)d_in[8];
    const float* wqkv  = (const float*)d_in[9];
    const float* wl1   = (const float*)d_in[10];
    const float* s1    = (const float*)d_in[11];
    const float* b1    = (const float*)d_in[12];
    const float* wl2   = (const float*)d_in[13];
    const float* s2    = (const float*)d_in[14];
    const float* b2    = (const float*)d_in[15];
    const float* rel   = (const float*)d_in[16];
    const float* wdw   = (const float*)d_in[17];
    const float* sp    = (const float*)d_in[18];
    const float* bp    = (const float*)d_in[19];
    const float* wpw   = (const float*)d_in[20];
    float* out = (float*)d_out;

    float* ws = (float*)d_ws;
    float* Q      = ws;                      // 4,194,304 floats (Qo)
    float* Kn     = ws + 4194304;            // 4,194,304 (W-preps alias after k2)
    float* stats  = ws + 8388608;            // 40,960 floats
    float* Ksum   = stats;
    float* xsum   = stats + 64;
    float* KX     = stats + 576;
    float* matrix = stats + 16960;
    float* vsum   = stats + 33344;
    float* A      = ws + 8429568;            // 33,554,432 (ybf alias; attn out; Dbf)
    float* L      = A + 33554432;            // 33,554,432 (phase1 aliases; Lconv)

    // L-region phase-1 aliases (all dead before k5 writes L):
    float* KXp   = L;                        // 1024 x 8192
    float* xsp   = L + 8388608;
    float* ksp   = L + 8650752;
    ushort* xbf  = (ushort*)(L + 8683520);   // x NHWC bf16
    ushort* Wqkb = (ushort*)(L + 25460736);  // 16,384 ushorts

    ushort* Wb    = (ushort*)Kn;             // conv weights, 589,824 bf16
    ushort* Wqb   = (ushort*)Kn + 600064;    // qkv weights, 196,608 bf16
    ushort* Wpwb  = (ushort*)Kn + 798720;    // pw weights, 65,536 bf16
    ushort* relbf = (ushort*)Kn + 864256;    // rel table, 3,600 bf16
    ushort* ybf   = (ushort*)A;              // padded NHWC y — until k6
    ushort* Dbf   = (ushort*)A;              // bf16 dwconv out — after k8
    ushort* zbf   = (ushort*)d_out;          // z bf16 NHWC (pre-swizzled) — k4..k6

    hipMemsetAsync(ybf, 0, (size_t)2 * 258 * 258 * 256 * sizeof(ushort), stream);

    kprep_y  <<<16384, 256, 0, stream>>>(y, ybf);
    kprep_x  <<<16384, 256, 0, stream>>>(x, xbf);
    kprep_qk <<<64,    256, 0, stream>>>(la_wq, la_wk, Wqkb);
    k1_mfma  <<<2048,  512, 0, stream>>>(xbf, Wqkb, la_bq, la_bk, Q, Kn);
    k2_kx    <<<1024,  256, 0, stream>>>(xbf, Kn, KXp, xsp, ksp);
    kprep_w  <<<2304,  256, 0, stream>>>(wl1, s1, wl2, s2, Wb);  // Kn dead after k2
    kprep_qw <<<768,   256, 0, stream>>>(wqkv, Wqb);
    kprep_pw <<<256,   256, 0, stream>>>(wpw, Wpwb);
    kprep_rel<<<15,    256, 0, stream>>>(rel, relbf);
    k2r      <<<68,    256, 0, stream>>>(KXp, xsp, ksp, KX, xsum, Ksum);
    k3_mat   <<<2,     256, 0, stream>>>(la_wv, la_bv, KX, xsum, Ksum, matrix, vsum);
    k4_z     <<<2048,  256, 0, stream>>>(x, Q, matrix, vsum, Ksum, gamma, zbf);
    k5_mfma  <<<1024,  512, 0, stream>>>(ybf, Wb, b1, b2, L);    // overwrites xbf etc
    k6_mfma  <<<1024,  512, 0, stream>>>(zbf, Wqb, relbf, A);    // overwrites ybf
    k7_pool  <<<8192,  256, 0, stream>>>(A, L);
    k8_dw    <<<32768, 256, 0, stream>>>(L, wdw, sp, bp, Dbf);
    k9_mfma  <<<1024,  512, 0, stream>>>(Dbf, Wpwb, out);
}

// Round 13
// 1116.720 us; speedup vs baseline: 1.7051x; 1.1024x over previous
//
#include <hip/hip_runtime.h>
#include <hip/hip_bf16.h>

#define DI __device__ __forceinline__

constexpr int Bc = 2, Cc = 256, Hc = 256, Wc = 256, Nc = Hc * Wc; // N=65536
constexpr float LA_EPS = 1e-6f;

typedef __attribute__((ext_vector_type(8))) short short8;
typedef __attribute__((ext_vector_type(4))) float floatx4;
typedef __attribute__((ext_vector_type(16))) float floatx16;

union Frag { short8 v; uint u[4]; };

DI ushort f2bf(float f) {
    uint u = __float_as_uint(f);
    uint r = (u + 0x7fff + ((u >> 16) & 1)) >> 16;
    return (ushort)r;
}

DI float bf2f(ushort u) { return __uint_as_float((uint)u << 16); }

DI uint pack2(float a, float b) {
    return (uint)f2bf(a) | ((uint)f2bf(b) << 16);
}

DI void gload16(const void* g, void* l) {
    __builtin_amdgcn_global_load_lds(
        (const __attribute__((address_space(1))) void*)g,
        (__attribute__((address_space(3))) void*)l, 16, 0, 0);
}

// ---------------------------------------------------------------------------
// KPREP_X: NCHW f32 -> NHWC bf16 ([b][px][ci])  (linear, used for x)
// ---------------------------------------------------------------------------
__global__ __launch_bounds__(256) void kprep_x(const float* __restrict__ x,
        ushort* __restrict__ xbf)
{
    int blk = blockIdx.x;
    int b = blk >> 13;
    int rest = blk & 8191;
    int ci0 = (rest & 7) * 32;
    int n0 = (rest >> 3) * 64;
    int t = threadIdx.x;
    __shared__ uint u[16][65];
    int px = t & 63, cig = t >> 6;
    const float* yb = x + (((size_t)(b * 256 + ci0 + cig * 8)) << 16) + n0 + px;
    #pragma unroll
    for (int jj = 0; jj < 4; ++jj) {
        float v0 = yb[((size_t)(jj * 2)) << 16];
        float v1 = yb[((size_t)(jj * 2 + 1)) << 16];
        u[cig * 4 + jj][px] = pack2(v0, v1);
    }
    __syncthreads();
    uint* out32 = (uint*)xbf;
    int pr = t & 15, pg = t >> 4;
    #pragma unroll
    for (int g2 = 0; g2 < 4; ++g2) {
        int ppx = g2 * 16 + pg;
        size_t uidx = (((size_t)(b * 65536 + n0 + ppx) * 256 + ci0) >> 1) + pr;
        out32[uidx] = u[pr][ppx];
    }
}

// ---------------------------------------------------------------------------
// KPREP_QK: Wqkb[64][256] = bf16( rows 0-31: wq, rows 32-63: wk )
// ---------------------------------------------------------------------------
__global__ __launch_bounds__(256) void kprep_qk(const float* __restrict__ wq,
        const float* __restrict__ wk, ushort* __restrict__ Wqkb)
{
    int idx = blockIdx.x * 256 + threadIdx.x;   // 16384
    int oc = idx >> 8, ci = idx & 255;
    float v = (oc < 32) ? wq[oc * 256 + ci] : wk[(oc - 32) * 256 + ci];
    Wqkb[idx] = f2bf(v);
}

// ---------------------------------------------------------------------------
// K1 (MFMA): Q,K = 1x1 conv (32 ch each) + per-pixel channel L2-norm.
// 64-px tiles: LDS 64KB -> 2 blocks/CU. 8 waves = 2(q/k) x 4(16px).
// ---------------------------------------------------------------------------
__global__ __launch_bounds__(512, 2) void k1_mfma(
        const ushort* __restrict__ xbf, const ushort* __restrict__ Wqkb,
        const float* __restrict__ bq, const float* __restrict__ bk,
        float* __restrict__ Qo, float* __restrict__ Ko)
{
    int blk = blockIdx.x;
    int b = blk >> 10;
    int px0 = (blk & 1023) << 6;
    int t = threadIdx.x;
    int lane = t & 63, w = t >> 6;
    int wr = w >> 2;       // 0: q rows, 1: k rows
    int wc = w & 3;        // px quarter (16 px)

    __shared__ ushort sW[64 * 256];    // 32KB [oc][ci] swizzled
    __shared__ ushort sX[64 * 256];    // 32KB [px][ci] swizzled

    #pragma unroll
    for (int p = 0; p < 4; ++p) {
        int m = p * 512 + t;
        int row = m >> 5, ch = m & 31;
        const ushort* g = Wqkb + row * 256 + ((ch ^ (row & 7)) << 3);
        gload16(g, (char*)sW + p * 8192 + w * 1024);
    }
    const ushort* xb = xbf + (size_t)(b * 65536 + px0) * 256;
    #pragma unroll
    for (int p = 0; p < 4; ++p) {
        int m = p * 512 + t;
        int row = m >> 5, ch = m & 31;
        const ushort* g = xb + row * 256 + ((ch ^ (row & 7)) << 3);
        gload16(g, (char*)sX + p * 8192 + w * 1024);
    }
    __syncthreads();

    int l15 = lane & 15, l4 = lane >> 4;
    floatx4 acc[2];
    acc[0] = {0.f, 0.f, 0.f, 0.f};
    acc[1] = {0.f, 0.f, 0.f, 0.f};

    #pragma unroll
    for (int ks = 0; ks < 8; ++ks) {
        int cidx = ks * 4 + l4;
        short8 af[2];
        #pragma unroll
        for (int m2 = 0; m2 < 2; ++m2) {
            int row = wr * 32 + m2 * 16 + l15;
            af[m2] = *(const short8*)((const char*)sW + row * 512 + ((cidx ^ (row & 7)) << 4));
        }
        int brow = wc * 16 + l15;
        short8 bf_ = *(const short8*)((const char*)sX + brow * 512 + ((cidx ^ (brow & 7)) << 4));
        #pragma unroll
        for (int m2 = 0; m2 < 2; ++m2)
            acc[m2] = __builtin_amdgcn_mfma_f32_16x16x32_bf16(af[m2], bf_, acc[m2], 0, 0, 0);
    }

    const float* bias = wr ? bk : bq;
    float* outp = wr ? Ko : Qo;
    float v[2][4];
    float s = 0.f;
    #pragma unroll
    for (int m2 = 0; m2 < 2; ++m2)
        #pragma unroll
        for (int r = 0; r < 4; ++r) {
            float vv = acc[m2][r] + bias[m2 * 16 + l4 * 4 + r];
            v[m2][r] = vv;
            s += vv * vv;
        }
    s += __shfl_xor(s, 16);
    s += __shfl_xor(s, 32);
    float rn = rsqrtf(s);
    int px = px0 + wc * 16 + l15;
    #pragma unroll
    for (int m2 = 0; m2 < 2; ++m2)
        #pragma unroll
        for (int r = 0; r < 4; ++r) {
            int oc = m2 * 16 + l4 * 4 + r;
            outp[((size_t)(b * 32 + oc) << 16) + px] = v[m2][r] * rn;
        }
}

// ---------------------------------------------------------------------------
// K2: partial KX/xsum/Ksum per block. Reads xbf (NHWC bf16) directly.
// ---------------------------------------------------------------------------
__global__ __launch_bounds__(256) void k2_kx(const ushort* __restrict__ xbf,
        const float* __restrict__ Kn, float* __restrict__ KXp,
        float* __restrict__ xsp, float* __restrict__ ksp)
{
    int blk = blockIdx.x;
    int b = blk >> 9;
    int blkl = blk & 511;
    int t = threadIdx.x;               // t = c
    int n0 = blkl * 128;
    __shared__ float kT[32][128];      // 16KB
    for (int i = t; i < 4096; i += 256) {
        int m = i >> 7, p = i & 127;
        kT[m][p] = Kn[((size_t)(b * 32 + m) << 16) + n0 + p];
    }
    __syncthreads();
    float acc[32];
    #pragma unroll
    for (int m = 0; m < 32; ++m) acc[m] = 0.f;
    float xs = 0.f;
    const ushort* xb = xbf + (((size_t)(b * 65536 + n0)) << 8) + t;
    for (int p4 = 0; p4 < 32; ++p4) {
        float xv0 = bf2f(xb[(size_t)(p4 * 4 + 0) << 8]);
        float xv1 = bf2f(xb[(size_t)(p4 * 4 + 1) << 8]);
        float xv2 = bf2f(xb[(size_t)(p4 * 4 + 2) << 8]);
        float xv3 = bf2f(xb[(size_t)(p4 * 4 + 3) << 8]);
        xs += xv0 + xv1 + xv2 + xv3;
        #pragma unroll
        for (int m = 0; m < 32; ++m) {
            floatx4 kv = *(const floatx4*)&kT[m][p4 * 4];
            acc[m] += kv[0] * xv0 + kv[1] * xv1 + kv[2] * xv2 + kv[3] * xv3;
        }
    }
    xsp[blk * 256 + t] = xs;
    if (t < 32) {
        float ks = 0.f;
        for (int p = 0; p < 128; ++p) ks += kT[t][p];
        ksp[blk * 32 + t] = ks;
    }
    #pragma unroll
    for (int m = 0; m < 32; ++m) KXp[(size_t)blk * 8192 + m * 256 + t] = acc[m];
}

// ---------------------------------------------------------------------------
// K2R: reduce partials -> KX, xsum, Ksum
// ---------------------------------------------------------------------------
__global__ __launch_bounds__(256) void k2r(const float* __restrict__ KXp,
        const float* __restrict__ xsp, const float* __restrict__ ksp,
        float* __restrict__ KX, float* __restrict__ xsum, float* __restrict__ Ksum)
{
    int blk = blockIdx.x, t = threadIdx.x;
    if (blk < 64) {
        int gidx = blk * 256 + t;
        int b = gidx >> 13, idx = gidx & 8191;
        float s = 0.f;
        for (int ch = 0; ch < 512; ++ch)
            s += KXp[(size_t)((b << 9) + ch) * 8192 + idx];
        KX[gidx] = s;
    } else if (blk < 66) {
        int b = blk - 64;
        float s = 0.f;
        for (int ch = 0; ch < 512; ++ch)
            s += xsp[((b << 9) + ch) * 256 + t];
        xsum[b * 256 + t] = s;
    } else {
        int b = blk - 66;
        if (t < 32) {
            float s = 0.f;
            for (int ch = 0; ch < 512; ++ch)
                s += ksp[((b << 9) + ch) * 32 + t];
            Ksum[b * 32 + t] = s;
        }
    }
}

// ---------------------------------------------------------------------------
// K3: matrix/vsum from KX, xsum, Ksum
// ---------------------------------------------------------------------------
__global__ __launch_bounds__(256) void k3_mat(const float* __restrict__ wv,
        const float* __restrict__ bv, const float* __restrict__ KX,
        const float* __restrict__ xsum, const float* __restrict__ Ksum,
        float* __restrict__ matrix, float* __restrict__ vsum)
{
    int b = blockIdx.x, t = threadIdx.x;
    __shared__ float sx[256];
    __shared__ float sk[32];
    __shared__ float skx[32][256];
    __shared__ float wT[256][65];
    sx[t] = xsum[b * 256 + t];
    if (t < 32) sk[t] = Ksum[b * 32 + t];
    for (int j = 0; j < 32; ++j) skx[j][t] = KX[(b * 32 + j) * 256 + t];
    float vs = bv[t] * (float)Nc;
    float mv[32];
    #pragma unroll
    for (int m = 0; m < 32; ++m) mv[m] = 0.f;
    for (int cc0 = 0; cc0 < 256; cc0 += 64) {
        __syncthreads();
        for (int i = 0; i < 64; ++i) {
            int c = i * 4 + (t >> 6);
            wT[c][t & 63] = wv[(size_t)c * 256 + cc0 + (t & 63)];
        }
        __syncthreads();
        for (int ccl = 0; ccl < 64; ++ccl) {
            float w = wT[t][ccl];
            int cc = cc0 + ccl;
            vs += w * sx[cc];
            #pragma unroll
            for (int m = 0; m < 32; ++m) mv[m] += w * skx[m][cc];
        }
    }
    vsum[b * 256 + t] = vs;
    float bvt = bv[t];
    for (int m = 0; m < 32; ++m) matrix[(b * 32 + m) * 256 + t] = mv[m] + bvt * sk[m];
}

// ---------------------------------------------------------------------------
// K4: z = x + gamma*(vsum + Q^T matrix)*tailor -> bf16 NHWC, pre-swizzled
// ---------------------------------------------------------------------------
__global__ __launch_bounds__(256) void k4_z(const float* __restrict__ x,
        const float* __restrict__ Q, const float* __restrict__ matrix,
        const float* __restrict__ vsum, const float* __restrict__ Ksum,
        const float* __restrict__ gamma_p, ushort* __restrict__ zbf)
{
    int b = blockIdx.x >> 10;
    int n0 = (blockIdx.x & 1023) * 64;
    int t = threadIdx.x;
    int px = t & 63, g = t >> 6;
    __shared__ float qT[32][64];
    __shared__ float mat[32][256];
    __shared__ float vs[256];
    __shared__ float tail[64];
    __shared__ float sk[32];
    __shared__ uint zsh[64 * 128];   // [px][cp] bf16 pairs, swizzled (32KB)
    #pragma unroll
    for (int j = 0; j < 8; ++j) {
        int m = j * 4 + g;
        qT[m][px] = Q[((size_t)b * 32 + m) * Nc + n0 + px];
    }
    for (int j = 0; j < 32; ++j) {
        int idx = j * 256 + t;
        (&mat[0][0])[idx] = matrix[b * 8192 + idx];
    }
    vs[t] = vsum[b * 256 + t];
    if (t < 32) sk[t] = Ksum[b * 32 + t] + LA_EPS;
    __syncthreads();
    if (t < 64) {
        float s = 0.f;
        #pragma unroll
        for (int m = 0; m < 32; ++m) s += qT[m][t] * sk[m];
        tail[t] = 1.0f / ((float)Nc + s);
    }
    __syncthreads();
    float gamma = gamma_p[0];
    float tl = tail[px];
    for (int l = 0; l < 64; l += 2) {
        int c0 = g * 64 + l;
        float s0 = vs[c0], s1 = vs[c0 + 1];
        #pragma unroll
        for (int m = 0; m < 32; ++m) {
            float qv = qT[m][px];
            s0 += qv * mat[m][c0];
            s1 += qv * mat[m][c0 + 1];
        }
        size_t idx0 = (size_t)(b * 256 + c0) * Nc + n0 + px;
        float z0 = x[idx0] + gamma * s0 * tl;
        float z1 = x[idx0 + Nc] + gamma * s1 * tl;
        int cp = c0 >> 1;
        zsh[(px * 512 + (((cp >> 2) ^ (px & 7)) << 4) + (cp & 3) * 4) >> 2] = pack2(z0, z1);
    }
    __syncthreads();
    const uint4* zl = (const uint4*)zsh;
    uint4* gz = (uint4*)(zbf + (((size_t)(b * 65536 + n0)) << 8));
    #pragma unroll
    for (int i2 = 0; i2 < 8; ++i2)
        gz[i2 * 256 + t] = zl[i2 * 256 + t];
}

// ---------------------------------------------------------------------------
// KPREP_Y: y (NCHW f32) -> ybf (padded NHWC bf16, [b][258][258][256])
// ---------------------------------------------------------------------------
__global__ __launch_bounds__(256) void kprep_y(const float* __restrict__ y,
        ushort* __restrict__ ybf)
{
    int blk = blockIdx.x;
    int b = blk >> 13;
    int rest = blk & 8191;
    int ci0 = (rest & 7) * 32;
    int n0 = (rest >> 3) * 64;
    int row = n0 >> 8, x = n0 & 255;
    int t = threadIdx.x;
    __shared__ uint u[16][65];
    int px = t & 63, cig = t >> 6;
    const float* yb = y + (((size_t)(b * 256 + ci0 + cig * 8)) << 16) + n0 + px;
    #pragma unroll
    for (int jj = 0; jj < 4; ++jj) {
        float v0 = yb[((size_t)(jj * 2)) << 16];
        float v1 = yb[((size_t)(jj * 2 + 1)) << 16];
        u[cig * 4 + jj][px] = pack2(v0, v1);
    }
    __syncthreads();
    uint* out32 = (uint*)ybf;
    size_t pbase = (size_t)(row + 1) * 258 + (x + 1);
    int pr = t & 15, pg = t >> 4;
    #pragma unroll
    for (int g2 = 0; g2 < 4; ++g2) {
        int ppx = g2 * 16 + pg;
        size_t uidx = (((size_t)b * 258 * 258 * 256 + (pbase + ppx) * 256 + ci0) >> 1) + pr;
        out32[uidx] = u[pr][ppx];
    }
}

// ---------------------------------------------------------------------------
// KPREP_W: Wb[tap][co][ci] = bf16(wl1*s1 + (tap==4)*wl2*s2)
// ---------------------------------------------------------------------------
__global__ __launch_bounds__(256) void kprep_w(const float* __restrict__ wl1,
        const float* __restrict__ s1, const float* __restrict__ wl2,
        const float* __restrict__ s2, ushort* __restrict__ Wb)
{
    int idx = blockIdx.x * 256 + threadIdx.x;
    int tp = idx >> 16;
    int r = idx & 65535;
    int co = r >> 8;
    float v = wl1[(size_t)r * 9 + tp] * s1[co];
    if (tp == 4) v += wl2[r] * s2[co];
    Wb[idx] = f2bf(v);
}

// ---------------------------------------------------------------------------
// KPREP_QW: Wqb = bf16(wqkv), q rows pre-scaled by 0.25
// ---------------------------------------------------------------------------
__global__ __launch_bounds__(256) void kprep_qw(const float* __restrict__ wqkv,
        ushort* __restrict__ Wqb)
{
    int idx = blockIdx.x * 256 + threadIdx.x;
    float v = wqkv[idx];
    if (idx < 65536) v *= 0.25f;
    Wqb[idx] = f2bf(v);
}

// ---------------------------------------------------------------------------
// KPREP_PW / KPREP_REL
// ---------------------------------------------------------------------------
__global__ __launch_bounds__(256) void kprep_pw(const float* __restrict__ wpw,
        ushort* __restrict__ Wpwb)
{
    int idx = blockIdx.x * 256 + threadIdx.x;
    Wpwb[idx] = f2bf(wpw[idx]);
}

__global__ __launch_bounds__(256) void kprep_rel(const float* __restrict__ rel,
        ushort* __restrict__ relbf)
{
    int idx = blockIdx.x * 256 + threadIdx.x;
    if (idx < 3600) relbf[idx] = f2bf(rel[idx]);
}

// ---------------------------------------------------------------------------
// K5 (MFMA): L = conv3x3(ybf, Wc) + bias
// ---------------------------------------------------------------------------
__global__ __launch_bounds__(512, 2) void k5_mfma(
        const ushort* __restrict__ ybf, const ushort* __restrict__ Wb,
        const float* __restrict__ b1, const float* __restrict__ b2,
        float* __restrict__ L)
{
    int blk = blockIdx.x;
    int b = blk >> 9;
    int y0 = (blk >> 1) & 255;
    int x0 = (blk & 1) << 7;
    int t = threadIdx.x;
    int lane = t & 63;
    int w = t >> 6;
    int wr = w >> 1;
    int wc = w & 1;

    __shared__ ushort sW[256 * 64];
    __shared__ ushort sY[128 * 64];

    floatx4 acc[4][4];
    #pragma unroll
    for (int m = 0; m < 4; ++m)
        #pragma unroll
        for (int n = 0; n < 4; ++n)
            acc[m][n] = {0.f, 0.f, 0.f, 0.f};

    const ushort* yb = ybf + (size_t)b * 258 * 258 * 256;
    int ldsWbase = w * 64 * 16;
    int ldsYbase = w * 64 * 16;

    for (int tp = 0; tp < 9; ++tp) {
        int dy = tp / 3 - 1, dx = tp % 3 - 1;
        const ushort* yrow = yb + ((size_t)(y0 + dy + 1) * 258 + (x0 + dx + 1)) * 256;
        const ushort* wtap = Wb + tp * 65536;
        for (int cb = 0; cb < 4; ++cb) {
            int ci0 = cb * 64;
            __syncthreads();
            #pragma unroll
            for (int p = 0; p < 4; ++p) {
                int m = p * 512 + t;
                int row = m >> 3, ch = m & 7;
                const ushort* g = wtap + row * 256 + ci0 + ((ch ^ (row & 7)) << 3);
                gload16(g, (char*)sW + p * 512 * 16 + ldsWbase);
            }
            #pragma unroll
            for (int p = 0; p < 2; ++p) {
                int m = p * 512 + t;
                int pxr = m >> 3, ch = m & 7;
                const ushort* g = yrow + (size_t)pxr * 256 + ci0 + ((ch ^ (pxr & 7)) << 3);
                gload16(g, (char*)sY + p * 512 * 16 + ldsYbase);
            }
            __syncthreads();
            #pragma unroll
            for (int kk = 0; kk < 2; ++kk) {
                int chunkb = kk * 4 + (lane >> 4);
                short8 afr[4];
                #pragma unroll
                for (int m2 = 0; m2 < 4; ++m2) {
                    int row = wr * 64 + m2 * 16 + (lane & 15);
                    int ch = chunkb ^ (row & 7);
                    afr[m2] = *(const short8*)((const char*)sW + row * 128 + ch * 16);
                }
                #pragma unroll
                for (int n2 = 0; n2 < 4; ++n2) {
                    int row = wc * 64 + n2 * 16 + (lane & 15);
                    int ch = chunkb ^ (row & 7);
                    short8 bfr = *(const short8*)((const char*)sY + row * 128 + ch * 16);
                    #pragma unroll
                    for (int m2 = 0; m2 < 4; ++m2)
                        acc[m2][n2] = __builtin_amdgcn_mfma_f32_16x16x32_bf16(
                            afr[m2], bfr, acc[m2][n2], 0, 0, 0);
                }
            }
        }
    }
    int pxb = x0 + wc * 64 + (lane & 15);
    #pragma unroll
    for (int m2 = 0; m2 < 4; ++m2) {
        int cobase = wr * 64 + m2 * 16 + (lane >> 4) * 4;
        #pragma unroll
        for (int r = 0; r < 4; ++r) {
            int co = cobase + r;
            float bias = b1[co] + b2[co];
            float* dst = L + (((size_t)(b * 256 + co)) << 16) + y0 * 256 + pxb;
            #pragma unroll
            for (int n2 = 0; n2 < 4; ++n2)
                dst[n2 * 16] = acc[m2][n2][r] + bias;
        }
    }
}

// ---------------------------------------------------------------------------
// K6 (MFMA, fused): qkv + window attention, TWO adjacent windows per block.
// Round-9 write schedule + in-register shfl transposes + FUSED single-pass
// qkv GEMMs + bf16 rel table.
// ---------------------------------------------------------------------------
__global__ __launch_bounds__(512, 2) void k6_mfma(const ushort* __restrict__ zbf,
        const ushort* __restrict__ Wqb, const ushort* __restrict__ relbf,
        float* __restrict__ A)
{
    int blk = blockIdx.x;
    int wxp = blk & 15, wy = (blk >> 4) & 31, b = blk >> 9;
    int t = threadIdx.x;
    int lane = t & 63;
    int w = t >> 6;
    int win = w >> 2;      // waves 0-3: window 0, waves 4-7: window 1
    int wq4 = w & 3;       // 4 heads per wave

    __shared__ ushort zT[128 * 256];     // 64KB, swizzle baked in memory
    __shared__ ushort srel[3600];        // 7.2KB bf16

    char* zTc = (char*)zT;

    // ---- stage both z windows via linear global_load_lds (zbf pre-swizzled) ----
    {
        const ushort* zb = zbf + (((size_t)b) << 16) * 256;
        #pragma unroll
        for (int p = 0; p < 8; ++p) {
            int m = p * 512 + t;
            int row = m >> 5, ch = m & 31;
            int win2 = row >> 6, px = row & 63;
            int gy = wy * 8 + (px >> 3);
            int gx = (wxp * 2 + win2) * 8 + (px & 7);
            const ushort* g = zb + (((size_t)(gy * 256 + gx)) << 8) + ch * 8;
            gload16(g, zTc + p * 8192 + w * 1024);
        }
    }
    for (int i = t; i < 3600; i += 512) srel[i] = relbf[i];
    __syncthreads();

    int l15 = lane & 15, l4 = lane >> 4;
    int l31 = lane & 31, l5 = lane >> 5;
    bool hilane = (l5 != 0);
    bool hi16 = (l31 & 16) != 0;
    int srcA = (l5 << 5) + (l31 & 15);
    int srcB = srcA + 16;
    int pxbase = win * 64;

    for (int hrep = 0; hrep < 4; ++hrep) {
        int h = wq4 * 4 + hrep;

        // ---- FUSED qkv: one bz read per (ks,n) feeds all three GEMMs ----
        floatx4 qacc[4] = {}, kacc[4] = {}, vacc[4] = {};
        #pragma unroll
        for (int ks = 0; ks < 8; ++ks) {
            short8 awq = *(const short8*)(Wqb + ((h * 16 + l15) << 8) + ks * 32 + (l4 << 3));
            short8 awk = *(const short8*)(Wqb + ((256 + h * 16 + l15) << 8) + ks * 32 + (l4 << 3));
            short8 bwv = *(const short8*)(Wqb + ((512 + h * 16 + l15) << 8) + ks * 32 + (l4 << 3));
            #pragma unroll
            for (int n = 0; n < 4; ++n) {
                int px = n * 16 + l15;
                short8 bz = *(const short8*)(zTc + (pxbase + px) * 512 + (((ks * 4 + l4) ^ (px & 7)) << 4));
                qacc[n] = __builtin_amdgcn_mfma_f32_16x16x32_bf16(awq, bz, qacc[n], 0, 0, 0);
                kacc[n] = __builtin_amdgcn_mfma_f32_16x16x32_bf16(awk, bz, kacc[n], 0, 0, 0);
                vacc[n] = __builtin_amdgcn_mfma_f32_16x16x32_bf16(bz, bwv, vacc[n], 0, 0, 0);
            }
        }

        Frag bq[2];
        {
            uint plo[4], phi[4];
            #pragma unroll
            for (int n = 0; n < 4; ++n) {
                plo[n] = pack2(qacc[n][0], qacc[n][1]);
                phi[n] = pack2(qacc[n][2], qacc[n][3]);
            }
            #pragma unroll
            for (int it = 0; it < 2; ++it) {
                uint a0 = (uint)__shfl((int)plo[it * 2], srcA), a1 = (uint)__shfl((int)plo[it * 2 + 1], srcA);
                uint b0 = (uint)__shfl((int)phi[it * 2], srcA), b1 = (uint)__shfl((int)phi[it * 2 + 1], srcA);
                uint c0 = (uint)__shfl((int)plo[it * 2], srcB), c1 = (uint)__shfl((int)plo[it * 2 + 1], srcB);
                uint d0 = (uint)__shfl((int)phi[it * 2], srcB), d1 = (uint)__shfl((int)phi[it * 2 + 1], srcB);
                bq[it].u[0] = hi16 ? a1 : a0;
                bq[it].u[1] = hi16 ? b1 : b0;
                bq[it].u[2] = hi16 ? c1 : c0;
                bq[it].u[3] = hi16 ? d1 : d0;
            }
        }
        Frag ak[2];
        {
            uint plo[4], phi[4];
            #pragma unroll
            for (int n = 0; n < 4; ++n) {
                plo[n] = pack2(kacc[n][0], kacc[n][1]);
                phi[n] = pack2(kacc[n][2], kacc[n][3]);
            }
            #pragma unroll
            for (int jt = 0; jt < 2; ++jt) {
                uint a0 = (uint)__shfl((int)plo[jt * 2], srcA), a1 = (uint)__shfl((int)plo[jt * 2 + 1], srcA);
                uint b0 = (uint)__shfl((int)phi[jt * 2], srcA), b1 = (uint)__shfl((int)phi[jt * 2 + 1], srcA);
                uint c0 = (uint)__shfl((int)plo[jt * 2], srcB), c1 = (uint)__shfl((int)plo[jt * 2 + 1], srcB);
                uint d0 = (uint)__shfl((int)phi[jt * 2], srcB), d1 = (uint)__shfl((int)phi[jt * 2 + 1], srcB);
                ak[jt].u[0] = hi16 ? a1 : a0;
                ak[jt].u[1] = hi16 ? b1 : b0;
                ak[jt].u[2] = hi16 ? c1 : c0;
                ak[jt].u[3] = hi16 ? d1 : d0;
            }
        }
        // v was computed TRANSPOSED (z as A-operand): vacc[m] rows are d, cols px
        Frag av[4];
        {
            uint v01[4], v23[4];
            #pragma unroll
            for (int m = 0; m < 4; ++m) {
                v01[m] = pack2(vacc[m][0], vacc[m][1]);
                v23[m] = pack2(vacc[m][2], vacc[m][3]);
            }
            #pragma unroll
            for (int jc = 0; jc < 4; ++jc) {
                av[jc].u[0] = (uint)__shfl((int)v01[jc], srcA);
                av[jc].u[1] = (uint)__shfl((int)v23[jc], srcA);
                av[jc].u[2] = (uint)__shfl((int)v01[jc], srcB);
                av[jc].u[3] = (uint)__shfl((int)v23[jc], srcB);
            }
        }

        // ---- per-it: S^T, softmax, PV ----
        #pragma unroll
        for (int it = 0; it < 2; ++it) {
            floatx16 st[2];
            #pragma unroll
            for (int jt = 0; jt < 2; ++jt) {
                floatx16 zc = {};
                st[jt] = __builtin_amdgcn_mfma_f32_32x32x16_bf16(ak[jt].v, bq[it].v, zc, 0, 0, 0);
            }
            int i = it * 32 + l31;
            int Ai = (i >> 3) * 15 + (i & 7) + 112;
            float mx = -1e30f;
            #pragma unroll
            for (int jt = 0; jt < 2; ++jt)
                #pragma unroll
                for (int r = 0; r < 16; ++r) {
                    int j = jt * 32 + (r & 3) + 8 * (r >> 2) + 4 * l5;
                    int Bjr = (j >> 3) * 15 + (j & 7);
                    float s = st[jt][r] + bf2f(srel[(Ai - Bjr) * 16 + h]);
                    st[jt][r] = s;
                    mx = fmaxf(mx, s);
                }
            mx = fmaxf(mx, __shfl_xor(mx, 32));
            float sum = 0.f;
            #pragma unroll
            for (int jt = 0; jt < 2; ++jt)
                #pragma unroll
                for (int r = 0; r < 16; ++r) {
                    float e = __expf(st[jt][r] - mx);
                    st[jt][r] = e;
                    sum += e;
                }
            sum += __shfl_xor(sum, 32);
            float rinv = 1.0f / sum;

            floatx16 ot = {};
            #pragma unroll
            for (int jc = 0; jc < 4; ++jc) {
                int jt = jc >> 1, rb = (jc & 1) * 8;
                uint u0 = pack2(st[jt][rb + 0], st[jt][rb + 1]);
                uint u1 = pack2(st[jt][rb + 2], st[jt][rb + 3]);
                uint u2 = pack2(st[jt][rb + 4], st[jt][rb + 5]);
                uint u3 = pack2(st[jt][rb + 6], st[jt][rb + 7]);
                uint s0 = (uint)__shfl_xor((int)u0, 32);
                uint s1 = (uint)__shfl_xor((int)u1, 32);
                uint s2 = (uint)__shfl_xor((int)u2, 32);
                uint s3 = (uint)__shfl_xor((int)u3, 32);
                Frag bf;
                bf.u[0] = hilane ? s2 : u0;
                bf.u[1] = hilane ? s3 : u1;
                bf.u[2] = hilane ? u2 : s0;
                bf.u[3] = hilane ? u3 : s1;
                ot = __builtin_amdgcn_mfma_f32_32x32x16_bf16(av[jc].v, bf.v, ot, 0, 0, 0);
            }
            int gy = wy * 8 + (i >> 3);
            int gx = (wxp * 2 + win) * 8 + (i & 7);
            float* Ab = A + (((size_t)(b * 256 + h * 16)) << 16) + gy * 256 + gx;
            #pragma unroll
            for (int r = 0; r < 8; ++r) {
                int d = (r & 3) + 8 * (r >> 2) + 4 * l5;
                Ab[(size_t)d << 16] = ot[r] * rinv;
            }
        }
    }
}

// ---------------------------------------------------------------------------
// K7 (tiled): L += avgpoolV(A) + avgpoolH(A). 64x64 tile + 7-halo in LDS.
// ---------------------------------------------------------------------------
__global__ __launch_bounds__(256) void k7_pool(const float* __restrict__ A,
        float* __restrict__ L)
{
    int blk = blockIdx.x;
    int tile = blk & 15;
    int c = (blk >> 4) & 255;
    int b = blk >> 12;
    int ty = (tile >> 2) * 64, tx = (tile & 3) * 64;
    int t = threadIdx.x;
    __shared__ float aT[71][73];
    const float* Ac = A + ((size_t)(b * 256 + c) << 16);
    for (int i = t; i < 71 * 71; i += 256) {
        int rr = i / 71, cc = i - rr * 71;
        int gy = ty + rr - 3, gx = tx + cc - 3;
        float v = 0.f;
        if (gy >= 0 && gy <= 256 && gx >= 0 && gx <= 256) {
            int ry = (gy == 256) ? 254 : gy;
            int rx = (gx == 256) ? 254 : gx;
            v = Ac[ry * 256 + rx];
        }
        aT[rr][cc] = v;
    }
    __syncthreads();
    int jj = t & 63;
    int oy0 = (t >> 6) * 16;
    float* Lc = L + ((size_t)(b * 256 + c) << 16);
    #pragma unroll 4
    for (int dy = 0; dy < 16; ++dy) {
        int oi = oy0 + dy;
        float sv = 0.f, sh = 0.f;
        #pragma unroll
        for (int u = 0; u < 8; ++u) {
            sv += aT[oi + u][jj + 3];
            sh += aT[oi + 3][jj + u];
        }
        int idx = (ty + oi) * 256 + tx + jj;
        Lc[idx] += 0.125f * (sv + sh);
    }
}

// ---------------------------------------------------------------------------
// K8 (tiled): D(bf16) = sp * dwconv8x8(pad_out(L), wdw, pad=3) + bp
// Register-sliding: each thread's 4 vertical outputs share 11 input rows;
// each row's 8-wide window is loaded ONCE (88 ds_reads vs 256).
// Accumulation order per output unchanged (u asc, v asc) -> bit-identical.
// ---------------------------------------------------------------------------
__global__ __launch_bounds__(256) void k8_dw(const float* __restrict__ P,
        const float* __restrict__ wdw, const float* __restrict__ sp,
        const float* __restrict__ bp, ushort* __restrict__ D)
{
    int blk = blockIdx.x;
    int tile = blk & 63;
    int c = (blk >> 6) & 255;
    int b = blk >> 14;
    int ty = (tile >> 3) * 32, tx = (tile & 7) * 32;
    int t = threadIdx.x;
    __shared__ float pT[39][40];
    __shared__ float wT[64];
    const float* Pc = P + ((size_t)(b * 256 + c) << 16);
    for (int i = t; i < 39 * 40; i += 256) {
        int rr = i / 40, cc = i - rr * 40;
        int gy = ty + rr - 3, gx = tx + cc - 3;
        float v = 0.f;
        if (gy >= 0 && gy <= 256 && gx >= 0 && gx <= 256) {
            int ry = (gy == 256) ? 254 : gy;
            int rx = (gx == 256) ? 254 : gx;
            v = Pc[ry * 256 + rx];
        }
        pT[rr][cc] = v;
    }
    if (t < 64) wT[t] = wdw[c * 64 + t];
    __syncthreads();
    int jj = t & 31;
    int oy0 = (t >> 5) * 4;
    float acc[4] = {0.f, 0.f, 0.f, 0.f};
    #pragma unroll
    for (int r = 0; r < 11; ++r) {
        float pv[8];
        #pragma unroll
        for (int v = 0; v < 8; ++v) pv[v] = pT[oy0 + r][jj + v];
        #pragma unroll
        for (int dy = 0; dy < 4; ++dy) {
            if (dy >= r - 7 && dy <= r && dy <= 3) {
                int u = r - dy;
                #pragma unroll
                for (int v = 0; v < 8; ++v)
                    acc[dy] += wT[u * 8 + v] * pv[v];
            }
        }
    }
    float spc = sp[c], bpc = bp[c];
    ushort* Dc = D + ((size_t)(b * 256 + c) << 16);
    #pragma unroll
    for (int dy = 0; dy < 4; ++dy)
        Dc[(ty + oy0 + dy) * 256 + tx + jj] = f2bf(spc * acc[dy] + bpc);
}

// ---------------------------------------------------------------------------
// K9 (MFMA): out[co][px] = sum_ci Wpw[co][ci] * D[ci][px]
// ---------------------------------------------------------------------------
__global__ __launch_bounds__(512, 2) void k9_mfma(
        const ushort* __restrict__ D, const ushort* __restrict__ Wpwb,
        float* __restrict__ out)
{
    int blk = blockIdx.x;
    int b = blk >> 9;
    int px0 = (blk & 511) << 7;
    int t = threadIdx.x;
    int lane = t & 63;
    int w = t >> 6;
    int wr = w >> 1, wc = w & 1;

    __shared__ ushort sW[256 * 64];
    __shared__ ushort sD[128 * 64];

    floatx4 acc[4][4];
    #pragma unroll
    for (int m = 0; m < 4; ++m)
        #pragma unroll
        for (int n = 0; n < 4; ++n)
            acc[m][n] = {0.f, 0.f, 0.f, 0.f};

    int ldsWbase = w * 64 * 16;

    for (int cb = 0; cb < 4; ++cb) {
        int ci0 = cb * 64;
        __syncthreads();
        #pragma unroll
        for (int p = 0; p < 4; ++p) {
            int m = p * 512 + t;
            int row = m >> 3, ch = m & 7;
            const ushort* g = Wpwb + row * 256 + ci0 + ((ch ^ (row & 7)) << 3);
            gload16(g, (char*)sW + p * 512 * 16 + ldsWbase);
        }
        #pragma unroll
        for (int p = 0; p < 2; ++p) {
            int m = p * 512 + t;
            int ci = m & 63, pxb = (m >> 6) * 8;
            short8 v = *(const short8*)(D + ((size_t)(b * 256 + ci0 + ci) << 16) + px0 + pxb);
            #pragma unroll
            for (int k2 = 0; k2 < 8; ++k2) {
                int px = pxb + k2;
                *(ushort*)((char*)sD + px * 128 + (((ci >> 3) ^ (px & 7)) << 4) + (ci & 7) * 2) =
                    (ushort)v[k2];
            }
        }
        __syncthreads();
        #pragma unroll
        for (int kk = 0; kk < 2; ++kk) {
            int chunkb = kk * 4 + (lane >> 4);
            short8 afr[4];
            #pragma unroll
            for (int m2 = 0; m2 < 4; ++m2) {
                int row = wr * 64 + m2 * 16 + (lane & 15);
                int ch = chunkb ^ (row & 7);
                afr[m2] = *(const short8*)((const char*)sW + row * 128 + ch * 16);
            }
            #pragma unroll
            for (int n2 = 0; n2 < 4; ++n2) {
                int row = wc * 64 + n2 * 16 + (lane & 15);
                int ch = chunkb ^ (row & 7);
                short8 bfr = *(const short8*)((const char*)sD + row * 128 + ch * 16);
                #pragma unroll
                for (int m2 = 0; m2 < 4; ++m2)
                    acc[m2][n2] = __builtin_amdgcn_mfma_f32_16x16x32_bf16(
                        afr[m2], bfr, acc[m2][n2], 0, 0, 0);
            }
        }
    }
    int pxb = px0 + wc * 64 + (lane & 15);
    #pragma unroll
    for (int m2 = 0; m2 < 4; ++m2) {
        int cobase = wr * 64 + m2 * 16 + (lane >> 4) * 4;
        #pragma unroll
        for (int r = 0; r < 4; ++r) {
            int co = cobase + r;
            float* dst = out + (((size_t)(b * 256 + co)) << 16) + pxb;
            #pragma unroll
            for (int n2 = 0; n2 < 4; ++n2)
                dst[n2 * 16] = acc[m2][n2][r];
        }
    }
}

// ---------------------------------------------------------------------------
extern "C" void kernel_launch(void* const* d_in, const int* in_sizes, int n_in,
                              void* d_out, int out_size, void* d_ws, size_t ws_size,
                              hipStream_t stream)
{
    (void)in_sizes; (void)n_in; (void)out_size; (void)ws_size;
    const float* x     = (const float*)d_in[0];
    const float* y     = (const float*)d_in[1];
    const float* gamma = (const float*)d_in[2];
    const float* la_wq = (const float*)d_in[3];
    const float* la_bq = (const float*)d_in[4];
    const float* la_wk = (const float*)d_in[5];
    const float* la_bk = (const float*)d_in[6];
    const float* la_wv = (const float*)d_in[7];
    const float* la_bv = (const float*)d_in[8];
    const float* wqkv  = (const float*)d_in[9];
    const float* wl1   = (const float*)d_in[10];
    const float* s1    = (const float*)d_in[11];
    const float* b1    = (const float*)d_in[12];
    const float* wl2   = (const float*)d_in[13];
    const float* s2    = (const float*)d_in[14];
    const float* b2    = (const float*)d_in[15];
    const float* rel   = (const float*)d_in[16];
    const float* wdw   = (const float*)d_in[17];
    const float* sp    = (const float*)d_in[18];
    const float* bp    = (const float*)d_in[19];
    const float* wpw   = (const float*)d_in[20];
    float* out = (float*)d_out;

    float* ws = (float*)d_ws;
    float* Q      = ws;                      // 4,194,304 floats (Qo)
    float* Kn     = ws + 4194304;            // 4,194,304 (W-preps alias after k2)
    float* stats  = ws + 8388608;            // 40,960 floats
    float* Ksum   = stats;
    float* xsum   = stats + 64;
    float* KX     = stats + 576;
    float* matrix = stats + 16960;
    float* vsum   = stats + 33344;
    float* A      = ws + 8429568;            // 33,554,432 (ybf alias; attn out; Dbf)
    float* L      = A + 33554432;            // 33,554,432 (phase1 aliases; Lconv)

    // L-region phase-1 aliases (all dead before k5 writes L):
    float* KXp   = L;                        // 1024 x 8192
    float* xsp   = L + 8388608;
    float* ksp   = L + 8650752;
    ushort* xbf  = (ushort*)(L + 8683520);   // x NHWC bf16
    ushort* Wqkb = (ushort*)(L + 25460736);  // 16,384 ushorts

    ushort* Wb    = (ushort*)Kn;             // conv weights, 589,824 bf16
    ushort* Wqb   = (ushort*)Kn + 600064;    // qkv weights, 196,608 bf16
    ushort* Wpwb  = (ushort*)Kn + 798720;    // pw weights, 65,536 bf16
    ushort* relbf = (ushort*)Kn + 864256;    // rel table, 3,600 bf16
    ushort* ybf   = (ushort*)A;              // padded NHWC y — until k6
    ushort* Dbf   = (ushort*)A;              // bf16 dwconv out — after k8
    ushort* zbf   = (ushort*)d_out;          // z bf16 NHWC (pre-swizzled) — k4..k6

    hipMemsetAsync(ybf, 0, (size_t)2 * 258 * 258 * 256 * sizeof(ushort), stream);

    kprep_y  <<<16384, 256, 0, stream>>>(y, ybf);
    kprep_x  <<<16384, 256, 0, stream>>>(x, xbf);
    kprep_qk <<<64,    256, 0, stream>>>(la_wq, la_wk, Wqkb);
    k1_mfma  <<<2048,  512, 0, stream>>>(xbf, Wqkb, la_bq, la_bk, Q, Kn);
    k2_kx    <<<1024,  256, 0, stream>>>(xbf, Kn, KXp, xsp, ksp);
    kprep_w  <<<2304,  256, 0, stream>>>(wl1, s1, wl2, s2, Wb);  // Kn dead after k2
    kprep_qw <<<768,   256, 0, stream>>>(wqkv, Wqb);
    kprep_pw <<<256,   256, 0, stream>>>(wpw, Wpwb);
    kprep_rel<<<15,    256, 0, stream>>>(rel, relbf);
    k2r      <<<68,    256, 0, stream>>>(KXp, xsp, ksp, KX, xsum, Ksum);
    k3_mat   <<<2,     256, 0, stream>>>(la_wv, la_bv, KX, xsum, Ksum, matrix, vsum);
    k4_z     <<<2048,  256, 0, stream>>>(x, Q, matrix, vsum, Ksum, gamma, zbf);
    k5_mfma  <<<1024,  512, 0, stream>>>(ybf, Wb, b1, b2, L);    // overwrites xbf etc
    k6_mfma  <<<1024,  512, 0, stream>>>(zbf, Wqb, relbf, A);    // overwrites ybf
    k7_pool  <<<8192,  256, 0, stream>>>(A, L);
    k8_dw    <<<32768, 256, 0, stream>>>(L, wdw, sp, bp, Dbf);
    k9_mfma  <<<1024,  512, 0, stream>>>(Dbf, Wpwb, out);
}

// Round 14
// 1087.420 us; speedup vs baseline: 1.7511x; 1.0269x over previous
//
#include <hip/hip_runtime.h>
#include <hip/hip_bf16.h>

#define DI __device__ __forceinline__

constexpr int Bc = 2, Cc = 256, Hc = 256, Wc = 256, Nc = Hc * Wc; // N=65536
constexpr float LA_EPS = 1e-6f;

typedef __attribute__((ext_vector_type(8))) short short8;
typedef __attribute__((ext_vector_type(4))) float floatx4;
typedef __attribute__((ext_vector_type(16))) float floatx16;

union Frag { short8 v; uint u[4]; };

DI ushort f2bf(float f) {
    uint u = __float_as_uint(f);
    uint r = (u + 0x7fff + ((u >> 16) & 1)) >> 16;
    return (ushort)r;
}

DI float bf2f(ushort u) { return __uint_as_float((uint)u << 16); }

DI uint pack2(float a, float b) {
    return (uint)f2bf(a) | ((uint)f2bf(b) << 16);
}

DI void gload16(const void* g, void* l) {
    __builtin_amdgcn_global_load_lds(
        (const __attribute__((address_space(1))) void*)g,
        (__attribute__((address_space(3))) void*)l, 16, 0, 0);
}

// ---------------------------------------------------------------------------
// KPREP_X: NCHW f32 -> NHWC bf16 ([b][px][ci])  (linear, used for x)
// ---------------------------------------------------------------------------
__global__ __launch_bounds__(256) void kprep_x(const float* __restrict__ x,
        ushort* __restrict__ xbf)
{
    int blk = blockIdx.x;
    int b = blk >> 13;
    int rest = blk & 8191;
    int ci0 = (rest & 7) * 32;
    int n0 = (rest >> 3) * 64;
    int t = threadIdx.x;
    __shared__ uint u[16][65];
    int px = t & 63, cig = t >> 6;
    const float* yb = x + (((size_t)(b * 256 + ci0 + cig * 8)) << 16) + n0 + px;
    #pragma unroll
    for (int jj = 0; jj < 4; ++jj) {
        float v0 = yb[((size_t)(jj * 2)) << 16];
        float v1 = yb[((size_t)(jj * 2 + 1)) << 16];
        u[cig * 4 + jj][px] = pack2(v0, v1);
    }
    __syncthreads();
    uint* out32 = (uint*)xbf;
    int pr = t & 15, pg = t >> 4;
    #pragma unroll
    for (int g2 = 0; g2 < 4; ++g2) {
        int ppx = g2 * 16 + pg;
        size_t uidx = (((size_t)(b * 65536 + n0 + ppx) * 256 + ci0) >> 1) + pr;
        out32[uidx] = u[pr][ppx];
    }
}

// ---------------------------------------------------------------------------
// KPREP_QK: Wqkb[64][256] = bf16( rows 0-31: wq, rows 32-63: wk )
// ---------------------------------------------------------------------------
__global__ __launch_bounds__(256) void kprep_qk(const float* __restrict__ wq,
        const float* __restrict__ wk, ushort* __restrict__ Wqkb)
{
    int idx = blockIdx.x * 256 + threadIdx.x;   // 16384
    int oc = idx >> 8, ci = idx & 255;
    float v = (oc < 32) ? wq[oc * 256 + ci] : wk[(oc - 32) * 256 + ci];
    Wqkb[idx] = f2bf(v);
}

// ---------------------------------------------------------------------------
// K1 (MFMA): Q,K = 1x1 conv (32 ch each) + per-pixel channel L2-norm.
// ---------------------------------------------------------------------------
__global__ __launch_bounds__(512, 2) void k1_mfma(
        const ushort* __restrict__ xbf, const ushort* __restrict__ Wqkb,
        const float* __restrict__ bq, const float* __restrict__ bk,
        float* __restrict__ Qo, float* __restrict__ Ko)
{
    int blk = blockIdx.x;
    int b = blk >> 10;
    int px0 = (blk & 1023) << 6;
    int t = threadIdx.x;
    int lane = t & 63, w = t >> 6;
    int wr = w >> 2;       // 0: q rows, 1: k rows
    int wc = w & 3;        // px quarter (16 px)

    __shared__ ushort sW[64 * 256];    // 32KB [oc][ci] swizzled
    __shared__ ushort sX[64 * 256];    // 32KB [px][ci] swizzled

    #pragma unroll
    for (int p = 0; p < 4; ++p) {
        int m = p * 512 + t;
        int row = m >> 5, ch = m & 31;
        const ushort* g = Wqkb + row * 256 + ((ch ^ (row & 7)) << 3);
        gload16(g, (char*)sW + p * 8192 + w * 1024);
    }
    const ushort* xb = xbf + (size_t)(b * 65536 + px0) * 256;
    #pragma unroll
    for (int p = 0; p < 4; ++p) {
        int m = p * 512 + t;
        int row = m >> 5, ch = m & 31;
        const ushort* g = xb + row * 256 + ((ch ^ (row & 7)) << 3);
        gload16(g, (char*)sX + p * 8192 + w * 1024);
    }
    __syncthreads();

    int l15 = lane & 15, l4 = lane >> 4;
    floatx4 acc[2];
    acc[0] = {0.f, 0.f, 0.f, 0.f};
    acc[1] = {0.f, 0.f, 0.f, 0.f};

    #pragma unroll
    for (int ks = 0; ks < 8; ++ks) {
        int cidx = ks * 4 + l4;
        short8 af[2];
        #pragma unroll
        for (int m2 = 0; m2 < 2; ++m2) {
            int row = wr * 32 + m2 * 16 + l15;
            af[m2] = *(const short8*)((const char*)sW + row * 512 + ((cidx ^ (row & 7)) << 4));
        }
        int brow = wc * 16 + l15;
        short8 bf_ = *(const short8*)((const char*)sX + brow * 512 + ((cidx ^ (brow & 7)) << 4));
        #pragma unroll
        for (int m2 = 0; m2 < 2; ++m2)
            acc[m2] = __builtin_amdgcn_mfma_f32_16x16x32_bf16(af[m2], bf_, acc[m2], 0, 0, 0);
    }

    const float* bias = wr ? bk : bq;
    float* outp = wr ? Ko : Qo;
    float v[2][4];
    float s = 0.f;
    #pragma unroll
    for (int m2 = 0; m2 < 2; ++m2)
        #pragma unroll
        for (int r = 0; r < 4; ++r) {
            float vv = acc[m2][r] + bias[m2 * 16 + l4 * 4 + r];
            v[m2][r] = vv;
            s += vv * vv;
        }
    s += __shfl_xor(s, 16);
    s += __shfl_xor(s, 32);
    float rn = rsqrtf(s);
    int px = px0 + wc * 16 + l15;
    #pragma unroll
    for (int m2 = 0; m2 < 2; ++m2)
        #pragma unroll
        for (int r = 0; r < 4; ++r) {
            int oc = m2 * 16 + l4 * 4 + r;
            outp[((size_t)(b * 32 + oc) << 16) + px] = v[m2][r] * rn;
        }
}

// ---------------------------------------------------------------------------
// K2: partial KX/xsum/Ksum per block. Reads xbf (NHWC bf16) directly.
// ---------------------------------------------------------------------------
__global__ __launch_bounds__(256) void k2_kx(const ushort* __restrict__ xbf,
        const float* __restrict__ Kn, float* __restrict__ KXp,
        float* __restrict__ xsp, float* __restrict__ ksp)
{
    int blk = blockIdx.x;
    int b = blk >> 9;
    int blkl = blk & 511;
    int t = threadIdx.x;               // t = c
    int n0 = blkl * 128;
    __shared__ float kT[32][128];      // 16KB
    for (int i = t; i < 4096; i += 256) {
        int m = i >> 7, p = i & 127;
        kT[m][p] = Kn[((size_t)(b * 32 + m) << 16) + n0 + p];
    }
    __syncthreads();
    float acc[32];
    #pragma unroll
    for (int m = 0; m < 32; ++m) acc[m] = 0.f;
    float xs = 0.f;
    const ushort* xb = xbf + (((size_t)(b * 65536 + n0)) << 8) + t;
    for (int p4 = 0; p4 < 32; ++p4) {
        float xv0 = bf2f(xb[(size_t)(p4 * 4 + 0) << 8]);
        float xv1 = bf2f(xb[(size_t)(p4 * 4 + 1) << 8]);
        float xv2 = bf2f(xb[(size_t)(p4 * 4 + 2) << 8]);
        float xv3 = bf2f(xb[(size_t)(p4 * 4 + 3) << 8]);
        xs += xv0 + xv1 + xv2 + xv3;
        #pragma unroll
        for (int m = 0; m < 32; ++m) {
            floatx4 kv = *(const floatx4*)&kT[m][p4 * 4];
            acc[m] += kv[0] * xv0 + kv[1] * xv1 + kv[2] * xv2 + kv[3] * xv3;
        }
    }
    xsp[blk * 256 + t] = xs;
    if (t < 32) {
        float ks = 0.f;
        for (int p = 0; p < 128; ++p) ks += kT[t][p];
        ksp[blk * 32 + t] = ks;
    }
    #pragma unroll
    for (int m = 0; m < 32; ++m) KXp[(size_t)blk * 8192 + m * 256 + t] = acc[m];
}

// ---------------------------------------------------------------------------
// K2R: reduce partials -> KX, xsum, Ksum
// ---------------------------------------------------------------------------
__global__ __launch_bounds__(256) void k2r(const float* __restrict__ KXp,
        const float* __restrict__ xsp, const float* __restrict__ ksp,
        float* __restrict__ KX, float* __restrict__ xsum, float* __restrict__ Ksum)
{
    int blk = blockIdx.x, t = threadIdx.x;
    if (blk < 64) {
        int gidx = blk * 256 + t;
        int b = gidx >> 13, idx = gidx & 8191;
        float s = 0.f;
        for (int ch = 0; ch < 512; ++ch)
            s += KXp[(size_t)((b << 9) + ch) * 8192 + idx];
        KX[gidx] = s;
    } else if (blk < 66) {
        int b = blk - 64;
        float s = 0.f;
        for (int ch = 0; ch < 512; ++ch)
            s += xsp[((b << 9) + ch) * 256 + t];
        xsum[b * 256 + t] = s;
    } else {
        int b = blk - 66;
        if (t < 32) {
            float s = 0.f;
            for (int ch = 0; ch < 512; ++ch)
                s += ksp[((b << 9) + ch) * 32 + t];
            Ksum[b * 32 + t] = s;
        }
    }
}

// ---------------------------------------------------------------------------
// K3: matrix/vsum from KX, xsum, Ksum
// ---------------------------------------------------------------------------
__global__ __launch_bounds__(256) void k3_mat(const float* __restrict__ wv,
        const float* __restrict__ bv, const float* __restrict__ KX,
        const float* __restrict__ xsum, const float* __restrict__ Ksum,
        float* __restrict__ matrix, float* __restrict__ vsum)
{
    int b = blockIdx.x, t = threadIdx.x;
    __shared__ float sx[256];
    __shared__ float sk[32];
    __shared__ float skx[32][256];
    __shared__ float wT[256][65];
    sx[t] = xsum[b * 256 + t];
    if (t < 32) sk[t] = Ksum[b * 32 + t];
    for (int j = 0; j < 32; ++j) skx[j][t] = KX[(b * 32 + j) * 256 + t];
    float vs = bv[t] * (float)Nc;
    float mv[32];
    #pragma unroll
    for (int m = 0; m < 32; ++m) mv[m] = 0.f;
    for (int cc0 = 0; cc0 < 256; cc0 += 64) {
        __syncthreads();
        for (int i = 0; i < 64; ++i) {
            int c = i * 4 + (t >> 6);
            wT[c][t & 63] = wv[(size_t)c * 256 + cc0 + (t & 63)];
        }
        __syncthreads();
        for (int ccl = 0; ccl < 64; ++ccl) {
            float w = wT[t][ccl];
            int cc = cc0 + ccl;
            vs += w * sx[cc];
            #pragma unroll
            for (int m = 0; m < 32; ++m) mv[m] += w * skx[m][cc];
        }
    }
    vsum[b * 256 + t] = vs;
    float bvt = bv[t];
    for (int m = 0; m < 32; ++m) matrix[(b * 32 + m) * 256 + t] = mv[m] + bvt * sk[m];
}

// ---------------------------------------------------------------------------
// K4: z = x + gamma*(vsum + Q^T matrix)*tailor -> bf16 NHWC, pre-swizzled
// ---------------------------------------------------------------------------
__global__ __launch_bounds__(256) void k4_z(const float* __restrict__ x,
        const float* __restrict__ Q, const float* __restrict__ matrix,
        const float* __restrict__ vsum, const float* __restrict__ Ksum,
        const float* __restrict__ gamma_p, ushort* __restrict__ zbf)
{
    int b = blockIdx.x >> 10;
    int n0 = (blockIdx.x & 1023) * 64;
    int t = threadIdx.x;
    int px = t & 63, g = t >> 6;
    __shared__ float qT[32][64];
    __shared__ float mat[32][256];
    __shared__ float vs[256];
    __shared__ float tail[64];
    __shared__ float sk[32];
    __shared__ uint zsh[64 * 128];   // [px][cp] bf16 pairs, swizzled (32KB)
    #pragma unroll
    for (int j = 0; j < 8; ++j) {
        int m = j * 4 + g;
        qT[m][px] = Q[((size_t)b * 32 + m) * Nc + n0 + px];
    }
    for (int j = 0; j < 32; ++j) {
        int idx = j * 256 + t;
        (&mat[0][0])[idx] = matrix[b * 8192 + idx];
    }
    vs[t] = vsum[b * 256 + t];
    if (t < 32) sk[t] = Ksum[b * 32 + t] + LA_EPS;
    __syncthreads();
    if (t < 64) {
        float s = 0.f;
        #pragma unroll
        for (int m = 0; m < 32; ++m) s += qT[m][t] * sk[m];
        tail[t] = 1.0f / ((float)Nc + s);
    }
    __syncthreads();
    float gamma = gamma_p[0];
    float tl = tail[px];
    for (int l = 0; l < 64; l += 2) {
        int c0 = g * 64 + l;
        float s0 = vs[c0], s1 = vs[c0 + 1];
        #pragma unroll
        for (int m = 0; m < 32; ++m) {
            float qv = qT[m][px];
            s0 += qv * mat[m][c0];
            s1 += qv * mat[m][c0 + 1];
        }
        size_t idx0 = (size_t)(b * 256 + c0) * Nc + n0 + px;
        float z0 = x[idx0] + gamma * s0 * tl;
        float z1 = x[idx0 + Nc] + gamma * s1 * tl;
        int cp = c0 >> 1;
        zsh[(px * 512 + (((cp >> 2) ^ (px & 7)) << 4) + (cp & 3) * 4) >> 2] = pack2(z0, z1);
    }
    __syncthreads();
    const uint4* zl = (const uint4*)zsh;
    uint4* gz = (uint4*)(zbf + (((size_t)(b * 65536 + n0)) << 8));
    #pragma unroll
    for (int i2 = 0; i2 < 8; ++i2)
        gz[i2 * 256 + t] = zl[i2 * 256 + t];
}

// ---------------------------------------------------------------------------
// KPREP_Y: y (NCHW f32) -> ybf (padded NHWC bf16, [b][258][258][256])
// ---------------------------------------------------------------------------
__global__ __launch_bounds__(256) void kprep_y(const float* __restrict__ y,
        ushort* __restrict__ ybf)
{
    int blk = blockIdx.x;
    int b = blk >> 13;
    int rest = blk & 8191;
    int ci0 = (rest & 7) * 32;
    int n0 = (rest >> 3) * 64;
    int row = n0 >> 8, x = n0 & 255;
    int t = threadIdx.x;
    __shared__ uint u[16][65];
    int px = t & 63, cig = t >> 6;
    const float* yb = y + (((size_t)(b * 256 + ci0 + cig * 8)) << 16) + n0 + px;
    #pragma unroll
    for (int jj = 0; jj < 4; ++jj) {
        float v0 = yb[((size_t)(jj * 2)) << 16];
        float v1 = yb[((size_t)(jj * 2 + 1)) << 16];
        u[cig * 4 + jj][px] = pack2(v0, v1);
    }
    __syncthreads();
    uint* out32 = (uint*)ybf;
    size_t pbase = (size_t)(row + 1) * 258 + (x + 1);
    int pr = t & 15, pg = t >> 4;
    #pragma unroll
    for (int g2 = 0; g2 < 4; ++g2) {
        int ppx = g2 * 16 + pg;
        size_t uidx = (((size_t)b * 258 * 258 * 256 + (pbase + ppx) * 256 + ci0) >> 1) + pr;
        out32[uidx] = u[pr][ppx];
    }
}

// ---------------------------------------------------------------------------
// KPREP_W: Wb[tap][co][ci] = bf16(wl1*s1 + (tap==4)*wl2*s2)
// ---------------------------------------------------------------------------
__global__ __launch_bounds__(256) void kprep_w(const float* __restrict__ wl1,
        const float* __restrict__ s1, const float* __restrict__ wl2,
        const float* __restrict__ s2, ushort* __restrict__ Wb)
{
    int idx = blockIdx.x * 256 + threadIdx.x;
    int tp = idx >> 16;
    int r = idx & 65535;
    int co = r >> 8;
    float v = wl1[(size_t)r * 9 + tp] * s1[co];
    if (tp == 4) v += wl2[r] * s2[co];
    Wb[idx] = f2bf(v);
}

// ---------------------------------------------------------------------------
// KPREP_QW: Wqb = bf16(wqkv), q rows pre-scaled by 0.25
// ---------------------------------------------------------------------------
__global__ __launch_bounds__(256) void kprep_qw(const float* __restrict__ wqkv,
        ushort* __restrict__ Wqb)
{
    int idx = blockIdx.x * 256 + threadIdx.x;
    float v = wqkv[idx];
    if (idx < 65536) v *= 0.25f;
    Wqb[idx] = f2bf(v);
}

// ---------------------------------------------------------------------------
// KPREP_PW / KPREP_REL (rel transposed to [h][226] for conflict-free gathers)
// ---------------------------------------------------------------------------
__global__ __launch_bounds__(256) void kprep_pw(const float* __restrict__ wpw,
        ushort* __restrict__ Wpwb)
{
    int idx = blockIdx.x * 256 + threadIdx.x;
    Wpwb[idx] = f2bf(wpw[idx]);
}

__global__ __launch_bounds__(256) void kprep_rel(const float* __restrict__ rel,
        ushort* __restrict__ relbf)
{
    int idx = blockIdx.x * 256 + threadIdx.x;
    if (idx < 3600) {
        int d = idx >> 4, h = idx & 15;     // rel[d][h]
        relbf[h * 226 + d] = f2bf(rel[idx]); // -> relbf[h][d]
    }
}

// ---------------------------------------------------------------------------
// K5 (MFMA): L = conv3x3(ybf, Wc) + bias
// ---------------------------------------------------------------------------
__global__ __launch_bounds__(512, 2) void k5_mfma(
        const ushort* __restrict__ ybf, const ushort* __restrict__ Wb,
        const float* __restrict__ b1, const float* __restrict__ b2,
        float* __restrict__ L)
{
    int blk = blockIdx.x;
    int b = blk >> 9;
    int y0 = (blk >> 1) & 255;
    int x0 = (blk & 1) << 7;
    int t = threadIdx.x;
    int lane = t & 63;
    int w = t >> 6;
    int wr = w >> 1;
    int wc = w & 1;

    __shared__ ushort sW[256 * 64];
    __shared__ ushort sY[128 * 64];

    floatx4 acc[4][4];
    #pragma unroll
    for (int m = 0; m < 4; ++m)
        #pragma unroll
        for (int n = 0; n < 4; ++n)
            acc[m][n] = {0.f, 0.f, 0.f, 0.f};

    const ushort* yb = ybf + (size_t)b * 258 * 258 * 256;
    int ldsWbase = w * 64 * 16;
    int ldsYbase = w * 64 * 16;

    for (int tp = 0; tp < 9; ++tp) {
        int dy = tp / 3 - 1, dx = tp % 3 - 1;
        const ushort* yrow = yb + ((size_t)(y0 + dy + 1) * 258 + (x0 + dx + 1)) * 256;
        const ushort* wtap = Wb + tp * 65536;
        for (int cb = 0; cb < 4; ++cb) {
            int ci0 = cb * 64;
            __syncthreads();
            #pragma unroll
            for (int p = 0; p < 4; ++p) {
                int m = p * 512 + t;
                int row = m >> 3, ch = m & 7;
                const ushort* g = wtap + row * 256 + ci0 + ((ch ^ (row & 7)) << 3);
                gload16(g, (char*)sW + p * 512 * 16 + ldsWbase);
            }
            #pragma unroll
            for (int p = 0; p < 2; ++p) {
                int m = p * 512 + t;
                int pxr = m >> 3, ch = m & 7;
                const ushort* g = yrow + (size_t)pxr * 256 + ci0 + ((ch ^ (pxr & 7)) << 3);
                gload16(g, (char*)sY + p * 512 * 16 + ldsYbase);
            }
            __syncthreads();
            #pragma unroll
            for (int kk = 0; kk < 2; ++kk) {
                int chunkb = kk * 4 + (lane >> 4);
                short8 afr[4];
                #pragma unroll
                for (int m2 = 0; m2 < 4; ++m2) {
                    int row = wr * 64 + m2 * 16 + (lane & 15);
                    int ch = chunkb ^ (row & 7);
                    afr[m2] = *(const short8*)((const char*)sW + row * 128 + ch * 16);
                }
                #pragma unroll
                for (int n2 = 0; n2 < 4; ++n2) {
                    int row = wc * 64 + n2 * 16 + (lane & 15);
                    int ch = chunkb ^ (row & 7);
                    short8 bfr = *(const short8*)((const char*)sY + row * 128 + ch * 16);
                    #pragma unroll
                    for (int m2 = 0; m2 < 4; ++m2)
                        acc[m2][n2] = __builtin_amdgcn_mfma_f32_16x16x32_bf16(
                            afr[m2], bfr, acc[m2][n2], 0, 0, 0);
                }
            }
        }
    }
    int pxb = x0 + wc * 64 + (lane & 15);
    #pragma unroll
    for (int m2 = 0; m2 < 4; ++m2) {
        int cobase = wr * 64 + m2 * 16 + (lane >> 4) * 4;
        #pragma unroll
        for (int r = 0; r < 4; ++r) {
            int co = cobase + r;
            float bias = b1[co] + b2[co];
            float* dst = L + (((size_t)(b * 256 + co)) << 16) + y0 * 256 + pxb;
            #pragma unroll
            for (int n2 = 0; n2 < 4; ++n2)
                dst[n2 * 16] = acc[m2][n2][r] + bias;
        }
    }
}

// ---------------------------------------------------------------------------
// K6 (MFMA, fused): qkv + window attention, TWO adjacent windows per block.
// Round-9 write schedule + in-register shfl transposes + fused qkv GEMMs +
// rel table transposed [h][226] (conflict-free gathers).
// ---------------------------------------------------------------------------
__global__ __launch_bounds__(512, 2) void k6_mfma(const ushort* __restrict__ zbf,
        const ushort* __restrict__ Wqb, const ushort* __restrict__ relbf,
        float* __restrict__ A)
{
    int blk = blockIdx.x;
    int wxp = blk & 15, wy = (blk >> 4) & 31, b = blk >> 9;
    int t = threadIdx.x;
    int lane = t & 63;
    int w = t >> 6;
    int win = w >> 2;      // waves 0-3: window 0, waves 4-7: window 1
    int wq4 = w & 3;       // 4 heads per wave

    __shared__ ushort zT[128 * 256];     // 64KB, swizzle baked in memory
    __shared__ ushort srel[16 * 226];    // 7.2KB bf16, [h][delta]

    char* zTc = (char*)zT;

    // ---- stage both z windows via linear global_load_lds (zbf pre-swizzled) ----
    {
        const ushort* zb = zbf + (((size_t)b) << 16) * 256;
        #pragma unroll
        for (int p = 0; p < 8; ++p) {
            int m = p * 512 + t;
            int row = m >> 5, ch = m & 31;
            int win2 = row >> 6, px = row & 63;
            int gy = wy * 8 + (px >> 3);
            int gx = (wxp * 2 + win2) * 8 + (px & 7);
            const ushort* g = zb + (((size_t)(gy * 256 + gx)) << 8) + ch * 8;
            gload16(g, zTc + p * 8192 + w * 1024);
        }
    }
    for (int i = t; i < 16 * 226; i += 512) srel[i] = relbf[i];
    __syncthreads();

    int l15 = lane & 15, l4 = lane >> 4;
    int l31 = lane & 31, l5 = lane >> 5;
    bool hilane = (l5 != 0);
    bool hi16 = (l31 & 16) != 0;
    int srcA = (l5 << 5) + (l31 & 15);
    int srcB = srcA + 16;
    int pxbase = win * 64;

    for (int hrep = 0; hrep < 4; ++hrep) {
        int h = wq4 * 4 + hrep;
        const ushort* srh = &srel[h * 226];

        // ---- FUSED qkv: one bz read per (ks,n) feeds all three GEMMs ----
        floatx4 qacc[4] = {}, kacc[4] = {}, vacc[4] = {};
        #pragma unroll
        for (int ks = 0; ks < 8; ++ks) {
            short8 awq = *(const short8*)(Wqb + ((h * 16 + l15) << 8) + ks * 32 + (l4 << 3));
            short8 awk = *(const short8*)(Wqb + ((256 + h * 16 + l15) << 8) + ks * 32 + (l4 << 3));
            short8 bwv = *(const short8*)(Wqb + ((512 + h * 16 + l15) << 8) + ks * 32 + (l4 << 3));
            #pragma unroll
            for (int n = 0; n < 4; ++n) {
                int px = n * 16 + l15;
                short8 bz = *(const short8*)(zTc + (pxbase + px) * 512 + (((ks * 4 + l4) ^ (px & 7)) << 4));
                qacc[n] = __builtin_amdgcn_mfma_f32_16x16x32_bf16(awq, bz, qacc[n], 0, 0, 0);
                kacc[n] = __builtin_amdgcn_mfma_f32_16x16x32_bf16(awk, bz, kacc[n], 0, 0, 0);
                vacc[n] = __builtin_amdgcn_mfma_f32_16x16x32_bf16(bz, bwv, vacc[n], 0, 0, 0);
            }
        }

        Frag bq[2];
        {
            uint plo[4], phi[4];
            #pragma unroll
            for (int n = 0; n < 4; ++n) {
                plo[n] = pack2(qacc[n][0], qacc[n][1]);
                phi[n] = pack2(qacc[n][2], qacc[n][3]);
            }
            #pragma unroll
            for (int it = 0; it < 2; ++it) {
                uint a0 = (uint)__shfl((int)plo[it * 2], srcA), a1 = (uint)__shfl((int)plo[it * 2 + 1], srcA);
                uint b0 = (uint)__shfl((int)phi[it * 2], srcA), b1 = (uint)__shfl((int)phi[it * 2 + 1], srcA);
                uint c0 = (uint)__shfl((int)plo[it * 2], srcB), c1 = (uint)__shfl((int)plo[it * 2 + 1], srcB);
                uint d0 = (uint)__shfl((int)phi[it * 2], srcB), d1 = (uint)__shfl((int)phi[it * 2 + 1], srcB);
                bq[it].u[0] = hi16 ? a1 : a0;
                bq[it].u[1] = hi16 ? b1 : b0;
                bq[it].u[2] = hi16 ? c1 : c0;
                bq[it].u[3] = hi16 ? d1 : d0;
            }
        }
        Frag ak[2];
        {
            uint plo[4], phi[4];
            #pragma unroll
            for (int n = 0; n < 4; ++n) {
                plo[n] = pack2(kacc[n][0], kacc[n][1]);
                phi[n] = pack2(kacc[n][2], kacc[n][3]);
            }
            #pragma unroll
            for (int jt = 0; jt < 2; ++jt) {
                uint a0 = (uint)__shfl((int)plo[jt * 2], srcA), a1 = (uint)__shfl((int)plo[jt * 2 + 1], srcA);
                uint b0 = (uint)__shfl((int)phi[jt * 2], srcA), b1 = (uint)__shfl((int)phi[jt * 2 + 1], srcA);
                uint c0 = (uint)__shfl((int)plo[jt * 2], srcB), c1 = (uint)__shfl((int)plo[jt * 2 + 1], srcB);
                uint d0 = (uint)__shfl((int)phi[jt * 2], srcB), d1 = (uint)__shfl((int)phi[jt * 2 + 1], srcB);
                ak[jt].u[0] = hi16 ? a1 : a0;
                ak[jt].u[1] = hi16 ? b1 : b0;
                ak[jt].u[2] = hi16 ? c1 : c0;
                ak[jt].u[3] = hi16 ? d1 : d0;
            }
        }
        // v was computed TRANSPOSED (z as A-operand): vacc[m] rows are d, cols px
        Frag av[4];
        {
            uint v01[4], v23[4];
            #pragma unroll
            for (int m = 0; m < 4; ++m) {
                v01[m] = pack2(vacc[m][0], vacc[m][1]);
                v23[m] = pack2(vacc[m][2], vacc[m][3]);
            }
            #pragma unroll
            for (int jc = 0; jc < 4; ++jc) {
                av[jc].u[0] = (uint)__shfl((int)v01[jc], srcA);
                av[jc].u[1] = (uint)__shfl((int)v23[jc], srcA);
                av[jc].u[2] = (uint)__shfl((int)v01[jc], srcB);
                av[jc].u[3] = (uint)__shfl((int)v23[jc], srcB);
            }
        }

        // ---- per-it: S^T, softmax, PV ----
        #pragma unroll
        for (int it = 0; it < 2; ++it) {
            floatx16 st[2];
            #pragma unroll
            for (int jt = 0; jt < 2; ++jt) {
                floatx16 zc = {};
                st[jt] = __builtin_amdgcn_mfma_f32_32x32x16_bf16(ak[jt].v, bq[it].v, zc, 0, 0, 0);
            }
            int i = it * 32 + l31;
            int Ai = (i >> 3) * 15 + (i & 7) + 112;
            float mx = -1e30f;
            #pragma unroll
            for (int jt = 0; jt < 2; ++jt)
                #pragma unroll
                for (int r = 0; r < 16; ++r) {
                    int j = jt * 32 + (r & 3) + 8 * (r >> 2) + 4 * l5;
                    int Bjr = (j >> 3) * 15 + (j & 7);
                    float s = st[jt][r] + bf2f(srh[Ai - Bjr]);
                    st[jt][r] = s;
                    mx = fmaxf(mx, s);
                }
            mx = fmaxf(mx, __shfl_xor(mx, 32));
            float sum = 0.f;
            #pragma unroll
            for (int jt = 0; jt < 2; ++jt)
                #pragma unroll
                for (int r = 0; r < 16; ++r) {
                    float e = __expf(st[jt][r] - mx);
                    st[jt][r] = e;
                    sum += e;
                }
            sum += __shfl_xor(sum, 32);
            float rinv = 1.0f / sum;

            floatx16 ot = {};
            #pragma unroll
            for (int jc = 0; jc < 4; ++jc) {
                int jt = jc >> 1, rb = (jc & 1) * 8;
                uint u0 = pack2(st[jt][rb + 0], st[jt][rb + 1]);
                uint u1 = pack2(st[jt][rb + 2], st[jt][rb + 3]);
                uint u2 = pack2(st[jt][rb + 4], st[jt][rb + 5]);
                uint u3 = pack2(st[jt][rb + 6], st[jt][rb + 7]);
                uint s0 = (uint)__shfl_xor((int)u0, 32);
                uint s1 = (uint)__shfl_xor((int)u1, 32);
                uint s2 = (uint)__shfl_xor((int)u2, 32);
                uint s3 = (uint)__shfl_xor((int)u3, 32);
                Frag bf;
                bf.u[0] = hilane ? s2 : u0;
                bf.u[1] = hilane ? s3 : u1;
                bf.u[2] = hilane ? u2 : s0;
                bf.u[3] = hilane ? u3 : s1;
                ot = __builtin_amdgcn_mfma_f32_32x32x16_bf16(av[jc].v, bf.v, ot, 0, 0, 0);
            }
            int gy = wy * 8 + (i >> 3);
            int gx = (wxp * 2 + win) * 8 + (i & 7);
            float* Ab = A + (((size_t)(b * 256 + h * 16)) << 16) + gy * 256 + gx;
            #pragma unroll
            for (int r = 0; r < 8; ++r) {
                int d = (r & 3) + 8 * (r >> 2) + 4 * l5;
                Ab[(size_t)d << 16] = ot[r] * rinv;
            }
        }
    }
}

// ---------------------------------------------------------------------------
// K7 (tiled): L += avgpoolV(A) + avgpoolH(A). 64x64 tile + 7-halo in LDS.
// ---------------------------------------------------------------------------
__global__ __launch_bounds__(256) void k7_pool(const float* __restrict__ A,
        float* __restrict__ L)
{
    int blk = blockIdx.x;
    int tile = blk & 15;
    int c = (blk >> 4) & 255;
    int b = blk >> 12;
    int ty = (tile >> 2) * 64, tx = (tile & 3) * 64;
    int t = threadIdx.x;
    __shared__ float aT[71][73];
    const float* Ac = A + ((size_t)(b * 256 + c) << 16);
    for (int i = t; i < 71 * 71; i += 256) {
        int rr = i / 71, cc = i - rr * 71;
        int gy = ty + rr - 3, gx = tx + cc - 3;
        float v = 0.f;
        if (gy >= 0 && gy <= 256 && gx >= 0 && gx <= 256) {
            int ry = (gy == 256) ? 254 : gy;
            int rx = (gx == 256) ? 254 : gx;
            v = Ac[ry * 256 + rx];
        }
        aT[rr][cc] = v;
    }
    __syncthreads();
    int jj = t & 63;
    int oy0 = (t >> 6) * 16;
    float* Lc = L + ((size_t)(b * 256 + c) << 16);
    #pragma unroll 4
    for (int dy = 0; dy < 16; ++dy) {
        int oi = oy0 + dy;
        float sv = 0.f, sh = 0.f;
        #pragma unroll
        for (int u = 0; u < 8; ++u) {
            sv += aT[oi + u][jj + 3];
            sh += aT[oi + 3][jj + u];
        }
        int idx = (ty + oi) * 256 + tx + jj;
        Lc[idx] += 0.125f * (sv + sh);
    }
}

// ---------------------------------------------------------------------------
// K8 (tiled): D(bf16) = sp * dwconv8x8(pad_out(L), wdw, pad=3) + bp
// Register-sliding rows (88 ds_reads vs 256); accumulation order unchanged.
// ---------------------------------------------------------------------------
__global__ __launch_bounds__(256) void k8_dw(const float* __restrict__ P,
        const float* __restrict__ wdw, const float* __restrict__ sp,
        const float* __restrict__ bp, ushort* __restrict__ D)
{
    int blk = blockIdx.x;
    int tile = blk & 63;
    int c = (blk >> 6) & 255;
    int b = blk >> 14;
    int ty = (tile >> 3) * 32, tx = (tile & 7) * 32;
    int t = threadIdx.x;
    __shared__ float pT[39][40];
    __shared__ float wT[64];
    const float* Pc = P + ((size_t)(b * 256 + c) << 16);
    for (int i = t; i < 39 * 40; i += 256) {
        int rr = i / 40, cc = i - rr * 40;
        int gy = ty + rr - 3, gx = tx + cc - 3;
        float v = 0.f;
        if (gy >= 0 && gy <= 256 && gx >= 0 && gx <= 256) {
            int ry = (gy == 256) ? 254 : gy;
            int rx = (gx == 256) ? 254 : gx;
            v = Pc[ry * 256 + rx];
        }
        pT[rr][cc] = v;
    }
    if (t < 64) wT[t] = wdw[c * 64 + t];
    __syncthreads();
    int jj = t & 31;
    int oy0 = (t >> 5) * 4;
    float acc[4] = {0.f, 0.f, 0.f, 0.f};
    #pragma unroll
    for (int r = 0; r < 11; ++r) {
        float pv[8];
        #pragma unroll
        for (int v = 0; v < 8; ++v) pv[v] = pT[oy0 + r][jj + v];
        #pragma unroll
        for (int dy = 0; dy < 4; ++dy) {
            if (dy >= r - 7 && dy <= r && dy <= 3) {
                int u = r - dy;
                #pragma unroll
                for (int v = 0; v < 8; ++v)
                    acc[dy] += wT[u * 8 + v] * pv[v];
            }
        }
    }
    float spc = sp[c], bpc = bp[c];
    ushort* Dc = D + ((size_t)(b * 256 + c) << 16);
    #pragma unroll
    for (int dy = 0; dy < 4; ++dy)
        Dc[(ty + oy0 + dy) * 256 + tx + jj] = f2bf(spc * acc[dy] + bpc);
}

// ---------------------------------------------------------------------------
// K9 (MFMA): out[co][px] = sum_ci Wpw[co][ci] * D[ci][px]
// ---------------------------------------------------------------------------
__global__ __launch_bounds__(512, 2) void k9_mfma(
        const ushort* __restrict__ D, const ushort* __restrict__ Wpwb,
        float* __restrict__ out)
{
    int blk = blockIdx.x;
    int b = blk >> 9;
    int px0 = (blk & 511) << 7;
    int t = threadIdx.x;
    int lane = t & 63;
    int w = t >> 6;
    int wr = w >> 1, wc = w & 1;

    __shared__ ushort sW[256 * 64];
    __shared__ ushort sD[128 * 64];

    floatx4 acc[4][4];
    #pragma unroll
    for (int m = 0; m < 4; ++m)
        #pragma unroll
        for (int n = 0; n < 4; ++n)
            acc[m][n] = {0.f, 0.f, 0.f, 0.f};

    int ldsWbase = w * 64 * 16;

    for (int cb = 0; cb < 4; ++cb) {
        int ci0 = cb * 64;
        __syncthreads();
        #pragma unroll
        for (int p = 0; p < 4; ++p) {
            int m = p * 512 + t;
            int row = m >> 3, ch = m & 7;
            const ushort* g = Wpwb + row * 256 + ci0 + ((ch ^ (row & 7)) << 3);
            gload16(g, (char*)sW + p * 512 * 16 + ldsWbase);
        }
        #pragma unroll
        for (int p = 0; p < 2; ++p) {
            int m = p * 512 + t;
            int ci = m & 63, pxb = (m >> 6) * 8;
            short8 v = *(const short8*)(D + ((size_t)(b * 256 + ci0 + ci) << 16) + px0 + pxb);
            #pragma unroll
            for (int k2 = 0; k2 < 8; ++k2) {
                int px = pxb + k2;
                *(ushort*)((char*)sD + px * 128 + (((ci >> 3) ^ (px & 7)) << 4) + (ci & 7) * 2) =
                    (ushort)v[k2];
            }
        }
        __syncthreads();
        #pragma unroll
        for (int kk = 0; kk < 2; ++kk) {
            int chunkb = kk * 4 + (lane >> 4);
            short8 afr[4];
            #pragma unroll
            for (int m2 = 0; m2 < 4; ++m2) {
                int row = wr * 64 + m2 * 16 + (lane & 15);
                int ch = chunkb ^ (row & 7);
                afr[m2] = *(const short8*)((const char*)sW + row * 128 + ch * 16);
            }
            #pragma unroll
            for (int n2 = 0; n2 < 4; ++n2) {
                int row = wc * 64 + n2 * 16 + (lane & 15);
                int ch = chunkb ^ (row & 7);
                short8 bfr = *(const short8*)((const char*)sD + row * 128 + ch * 16);
                #pragma unroll
                for (int m2 = 0; m2 < 4; ++m2)
                    acc[m2][n2] = __builtin_amdgcn_mfma_f32_16x16x32_bf16(
                        afr[m2], bfr, acc[m2][n2], 0, 0, 0);
            }
        }
    }
    int pxb = px0 + wc * 64 + (lane & 15);
    #pragma unroll
    for (int m2 = 0; m2 < 4; ++m2) {
        int cobase = wr * 64 + m2 * 16 + (lane >> 4) * 4;
        #pragma unroll
        for (int r = 0; r < 4; ++r) {
            int co = cobase + r;
            float* dst = out + (((size_t)(b * 256 + co)) << 16) + pxb;
            #pragma unroll
            for (int n2 = 0; n2 < 4; ++n2)
                dst[n2 * 16] = acc[m2][n2][r];
        }
    }
}

// ---------------------------------------------------------------------------
extern "C" void kernel_launch(void* const* d_in, const int* in_sizes, int n_in,
                              void* d_out, int out_size, void* d_ws, size_t ws_size,
                              hipStream_t stream)
{
    (void)in_sizes; (void)n_in; (void)out_size; (void)ws_size;
    const float* x     = (const float*)d_in[0];
    const float* y     = (const float*)d_in[1];
    const float* gamma = (const float*)d_in[2];
    const float* la_wq = (const float*)d_in[3];
    const float* la_bq = (const float*)d_in[4];
    const float* la_wk = (const float*)d_in[5];
    const float* la_bk = (const float*)d_in[6];
    const float* la_wv = (const float*)d_in[7];
    const float* la_bv = (const float*)d_in[8];
    const float* wqkv  = (const float*)d_in[9];
    const float* wl1   = (const float*)d_in[10];
    const float* s1    = (const float*)d_in[11];
    const float* b1    = (const float*)d_in[12];
    const float* wl2   = (const float*)d_in[13];
    const float* s2    = (const float*)d_in[14];
    const float* b2    = (const float*)d_in[15];
    const float* rel   = (const float*)d_in[16];
    const float* wdw   = (const float*)d_in[17];
    const float* sp    = (const float*)d_in[18];
    const float* bp    = (const float*)d_in[19];
    const float* wpw   = (const float*)d_in[20];
    float* out = (float*)d_out;

    float* ws = (float*)d_ws;
    float* Q      = ws;                      // 4,194,304 floats (Qo)
    float* Kn     = ws + 4194304;            // 4,194,304 (W-preps alias after k2)
    float* stats  = ws + 8388608;            // 40,960 floats
    float* Ksum   = stats;
    float* xsum   = stats + 64;
    float* KX     = stats + 576;
    float* matrix = stats + 16960;
    float* vsum   = stats + 33344;
    float* A      = ws + 8429568;            // 33,554,432 (ybf alias; attn out; Dbf)
    float* L      = A + 33554432;            // 33,554,432 (phase1 aliases; Lconv)

    // L-region phase-1 aliases (all dead before k5 writes L):
    float* KXp   = L;                        // 1024 x 8192
    float* xsp   = L + 8388608;
    float* ksp   = L + 8650752;
    ushort* xbf  = (ushort*)(L + 8683520);   // x NHWC bf16
    ushort* Wqkb = (ushort*)(L + 25460736);  // 16,384 ushorts

    ushort* Wb    = (ushort*)Kn;             // conv weights, 589,824 bf16
    ushort* Wqb   = (ushort*)Kn + 600064;    // qkv weights, 196,608 bf16
    ushort* Wpwb  = (ushort*)Kn + 798720;    // pw weights, 65,536 bf16
    ushort* relbf = (ushort*)Kn + 864256;    // rel table [16][226], 3,616 bf16
    ushort* ybf   = (ushort*)A;              // padded NHWC y — until k6
    ushort* Dbf   = (ushort*)A;              // bf16 dwconv out — after k8
    ushort* zbf   = (ushort*)d_out;          // z bf16 NHWC (pre-swizzled) — k4..k6

    hipMemsetAsync(ybf, 0, (size_t)2 * 258 * 258 * 256 * sizeof(ushort), stream);

    kprep_y  <<<16384, 256, 0, stream>>>(y, ybf);
    kprep_x  <<<16384, 256, 0, stream>>>(x, xbf);
    kprep_qk <<<64,    256, 0, stream>>>(la_wq, la_wk, Wqkb);
    k1_mfma  <<<2048,  512, 0, stream>>>(xbf, Wqkb, la_bq, la_bk, Q, Kn);
    k2_kx    <<<1024,  256, 0, stream>>>(xbf, Kn, KXp, xsp, ksp);
    kprep_w  <<<2304,  256, 0, stream>>>(wl1, s1, wl2, s2, Wb);  // Kn dead after k2
    kprep_qw <<<768,   256, 0, stream>>>(wqkv, Wqb);
    kprep_pw <<<256,   256, 0, stream>>>(wpw, Wpwb);
    kprep_rel<<<15,    256, 0, stream>>>(rel, relbf);
    k2r      <<<68,    256, 0, stream>>>(KXp, xsp, ksp, KX, xsum, Ksum);
    k3_mat   <<<2,     256, 0, stream>>>(la_wv, la_bv, KX, xsum, Ksum, matrix, vsum);
    k4_z     <<<2048,  256, 0, stream>>>(x, Q, matrix, vsum, Ksum, gamma, zbf);
    k5_mfma  <<<1024,  512, 0, stream>>>(ybf, Wb, b1, b2, L);    // overwrites xbf etc
    k6_mfma  <<<1024,  512, 0, stream>>>(zbf, Wqb, relbf, A);    // overwrites ybf
    k7_pool  <<<8192,  256, 0, stream>>>(A, L);
    k8_dw    <<<32768, 256, 0, stream>>>(L, wdw, sp, bp, Dbf);
    k9_mfma  <<<1024,  512, 0, stream>>>(Dbf, Wpwb, out);
}

// Round 15
// 1043.517 us; speedup vs baseline: 1.8248x; 1.0421x over previous
//
#include <hip/hip_runtime.h>
#include <hip/hip_bf16.h>

#define DI __device__ __forceinline__

constexpr int Bc = 2, Cc = 256, Hc = 256, Wc = 256, Nc = Hc * Wc; // N=65536
constexpr float LA_EPS = 1e-6f;

typedef __attribute__((ext_vector_type(8))) short short8;
typedef __attribute__((ext_vector_type(4))) float floatx4;
typedef __attribute__((ext_vector_type(16))) float floatx16;

union Frag { short8 v; uint u[4]; };

DI ushort f2bf(float f) {
    uint u = __float_as_uint(f);
    uint r = (u + 0x7fff + ((u >> 16) & 1)) >> 16;
    return (ushort)r;
}

DI float bf2f(ushort u) { return __uint_as_float((uint)u << 16); }

DI uint pack2(float a, float b) {
    return (uint)f2bf(a) | ((uint)f2bf(b) << 16);
}

DI void gload16(const void* g, void* l) {
    __builtin_amdgcn_global_load_lds(
        (const __attribute__((address_space(1))) void*)g,
        (__attribute__((address_space(3))) void*)l, 16, 0, 0);
}

// ---------------------------------------------------------------------------
// KPREP_X: NCHW f32 -> NHWC bf16 ([b][px][ci])  (linear, used for x)
// ---------------------------------------------------------------------------
__global__ __launch_bounds__(256) void kprep_x(const float* __restrict__ x,
        ushort* __restrict__ xbf)
{
    int blk = blockIdx.x;
    int b = blk >> 13;
    int rest = blk & 8191;
    int ci0 = (rest & 7) * 32;
    int n0 = (rest >> 3) * 64;
    int t = threadIdx.x;
    __shared__ uint u[16][65];
    int px = t & 63, cig = t >> 6;
    const float* yb = x + (((size_t)(b * 256 + ci0 + cig * 8)) << 16) + n0 + px;
    #pragma unroll
    for (int jj = 0; jj < 4; ++jj) {
        float v0 = yb[((size_t)(jj * 2)) << 16];
        float v1 = yb[((size_t)(jj * 2 + 1)) << 16];
        u[cig * 4 + jj][px] = pack2(v0, v1);
    }
    __syncthreads();
    uint* out32 = (uint*)xbf;
    int pr = t & 15, pg = t >> 4;
    #pragma unroll
    for (int g2 = 0; g2 < 4; ++g2) {
        int ppx = g2 * 16 + pg;
        size_t uidx = (((size_t)(b * 65536 + n0 + ppx) * 256 + ci0) >> 1) + pr;
        out32[uidx] = u[pr][ppx];
    }
}

// ---------------------------------------------------------------------------
// KPREP_QK: Wqkb[64][256] = bf16( rows 0-31: wq, rows 32-63: wk )
// ---------------------------------------------------------------------------
__global__ __launch_bounds__(256) void kprep_qk(const float* __restrict__ wq,
        const float* __restrict__ wk, ushort* __restrict__ Wqkb)
{
    int idx = blockIdx.x * 256 + threadIdx.x;   // 16384
    int oc = idx >> 8, ci = idx & 255;
    float v = (oc < 32) ? wq[oc * 256 + ci] : wk[(oc - 32) * 256 + ci];
    Wqkb[idx] = f2bf(v);
}

// ---------------------------------------------------------------------------
// K1 (MFMA): Q,K = 1x1 conv (32 ch each) + per-pixel channel L2-norm.
// ---------------------------------------------------------------------------
__global__ __launch_bounds__(512, 2) void k1_mfma(
        const ushort* __restrict__ xbf, const ushort* __restrict__ Wqkb,
        const float* __restrict__ bq, const float* __restrict__ bk,
        float* __restrict__ Qo, float* __restrict__ Ko)
{
    int blk = blockIdx.x;
    int b = blk >> 10;
    int px0 = (blk & 1023) << 6;
    int t = threadIdx.x;
    int lane = t & 63, w = t >> 6;
    int wr = w >> 2;       // 0: q rows, 1: k rows
    int wc = w & 3;        // px quarter (16 px)

    __shared__ ushort sW[64 * 256];    // 32KB [oc][ci] swizzled
    __shared__ ushort sX[64 * 256];    // 32KB [px][ci] swizzled

    #pragma unroll
    for (int p = 0; p < 4; ++p) {
        int m = p * 512 + t;
        int row = m >> 5, ch = m & 31;
        const ushort* g = Wqkb + row * 256 + ((ch ^ (row & 7)) << 3);
        gload16(g, (char*)sW + p * 8192 + w * 1024);
    }
    const ushort* xb = xbf + (size_t)(b * 65536 + px0) * 256;
    #pragma unroll
    for (int p = 0; p < 4; ++p) {
        int m = p * 512 + t;
        int row = m >> 5, ch = m & 31;
        const ushort* g = xb + row * 256 + ((ch ^ (row & 7)) << 3);
        gload16(g, (char*)sX + p * 8192 + w * 1024);
    }
    __syncthreads();

    int l15 = lane & 15, l4 = lane >> 4;
    floatx4 acc[2];
    acc[0] = {0.f, 0.f, 0.f, 0.f};
    acc[1] = {0.f, 0.f, 0.f, 0.f};

    #pragma unroll
    for (int ks = 0; ks < 8; ++ks) {
        int cidx = ks * 4 + l4;
        short8 af[2];
        #pragma unroll
        for (int m2 = 0; m2 < 2; ++m2) {
            int row = wr * 32 + m2 * 16 + l15;
            af[m2] = *(const short8*)((const char*)sW + row * 512 + ((cidx ^ (row & 7)) << 4));
        }
        int brow = wc * 16 + l15;
        short8 bf_ = *(const short8*)((const char*)sX + brow * 512 + ((cidx ^ (brow & 7)) << 4));
        #pragma unroll
        for (int m2 = 0; m2 < 2; ++m2)
            acc[m2] = __builtin_amdgcn_mfma_f32_16x16x32_bf16(af[m2], bf_, acc[m2], 0, 0, 0);
    }

    const float* bias = wr ? bk : bq;
    float* outp = wr ? Ko : Qo;
    float v[2][4];
    float s = 0.f;
    #pragma unroll
    for (int m2 = 0; m2 < 2; ++m2)
        #pragma unroll
        for (int r = 0; r < 4; ++r) {
            float vv = acc[m2][r] + bias[m2 * 16 + l4 * 4 + r];
            v[m2][r] = vv;
            s += vv * vv;
        }
    s += __shfl_xor(s, 16);
    s += __shfl_xor(s, 32);
    float rn = rsqrtf(s);
    int px = px0 + wc * 16 + l15;
    #pragma unroll
    for (int m2 = 0; m2 < 2; ++m2)
        #pragma unroll
        for (int r = 0; r < 4; ++r) {
            int oc = m2 * 16 + l4 * 4 + r;
            outp[((size_t)(b * 32 + oc) << 16) + px] = v[m2][r] * rn;
        }
}

// ---------------------------------------------------------------------------
// K2: partial KX/xsum/Ksum per block. Reads xbf (NHWC bf16) directly.
// ---------------------------------------------------------------------------
__global__ __launch_bounds__(256) void k2_kx(const ushort* __restrict__ xbf,
        const float* __restrict__ Kn, float* __restrict__ KXp,
        float* __restrict__ xsp, float* __restrict__ ksp)
{
    int blk = blockIdx.x;
    int b = blk >> 9;
    int blkl = blk & 511;
    int t = threadIdx.x;               // t = c
    int n0 = blkl * 128;
    __shared__ float kT[32][128];      // 16KB
    for (int i = t; i < 4096; i += 256) {
        int m = i >> 7, p = i & 127;
        kT[m][p] = Kn[((size_t)(b * 32 + m) << 16) + n0 + p];
    }
    __syncthreads();
    float acc[32];
    #pragma unroll
    for (int m = 0; m < 32; ++m) acc[m] = 0.f;
    float xs = 0.f;
    const ushort* xb = xbf + (((size_t)(b * 65536 + n0)) << 8) + t;
    for (int p4 = 0; p4 < 32; ++p4) {
        float xv0 = bf2f(xb[(size_t)(p4 * 4 + 0) << 8]);
        float xv1 = bf2f(xb[(size_t)(p4 * 4 + 1) << 8]);
        float xv2 = bf2f(xb[(size_t)(p4 * 4 + 2) << 8]);
        float xv3 = bf2f(xb[(size_t)(p4 * 4 + 3) << 8]);
        xs += xv0 + xv1 + xv2 + xv3;
        #pragma unroll
        for (int m = 0; m < 32; ++m) {
            floatx4 kv = *(const floatx4*)&kT[m][p4 * 4];
            acc[m] += kv[0] * xv0 + kv[1] * xv1 + kv[2] * xv2 + kv[3] * xv3;
        }
    }
    xsp[blk * 256 + t] = xs;
    if (t < 32) {
        float ks = 0.f;
        for (int p = 0; p < 128; ++p) ks += kT[t][p];
        ksp[blk * 32 + t] = ks;
    }
    #pragma unroll
    for (int m = 0; m < 32; ++m) KXp[(size_t)blk * 8192 + m * 256 + t] = acc[m];
}

// ---------------------------------------------------------------------------
// K2R: reduce partials -> KX, xsum, Ksum
// ---------------------------------------------------------------------------
__global__ __launch_bounds__(256) void k2r(const float* __restrict__ KXp,
        const float* __restrict__ xsp, const float* __restrict__ ksp,
        float* __restrict__ KX, float* __restrict__ xsum, float* __restrict__ Ksum)
{
    int blk = blockIdx.x, t = threadIdx.x;
    if (blk < 64) {
        int gidx = blk * 256 + t;
        int b = gidx >> 13, idx = gidx & 8191;
        float s = 0.f;
        for (int ch = 0; ch < 512; ++ch)
            s += KXp[(size_t)((b << 9) + ch) * 8192 + idx];
        KX[gidx] = s;
    } else if (blk < 66) {
        int b = blk - 64;
        float s = 0.f;
        for (int ch = 0; ch < 512; ++ch)
            s += xsp[((b << 9) + ch) * 256 + t];
        xsum[b * 256 + t] = s;
    } else {
        int b = blk - 66;
        if (t < 32) {
            float s = 0.f;
            for (int ch = 0; ch < 512; ++ch)
                s += ksp[((b << 9) + ch) * 32 + t];
            Ksum[b * 32 + t] = s;
        }
    }
}

// ---------------------------------------------------------------------------
// K3: matrix/vsum from KX, xsum, Ksum
// ---------------------------------------------------------------------------
__global__ __launch_bounds__(256) void k3_mat(const float* __restrict__ wv,
        const float* __restrict__ bv, const float* __restrict__ KX,
        const float* __restrict__ xsum, const float* __restrict__ Ksum,
        float* __restrict__ matrix, float* __restrict__ vsum)
{
    int b = blockIdx.x, t = threadIdx.x;
    __shared__ float sx[256];
    __shared__ float sk[32];
    __shared__ float skx[32][256];
    __shared__ float wT[256][65];
    sx[t] = xsum[b * 256 + t];
    if (t < 32) sk[t] = Ksum[b * 32 + t];
    for (int j = 0; j < 32; ++j) skx[j][t] = KX[(b * 32 + j) * 256 + t];
    float vs = bv[t] * (float)Nc;
    float mv[32];
    #pragma unroll
    for (int m = 0; m < 32; ++m) mv[m] = 0.f;
    for (int cc0 = 0; cc0 < 256; cc0 += 64) {
        __syncthreads();
        for (int i = 0; i < 64; ++i) {
            int c = i * 4 + (t >> 6);
            wT[c][t & 63] = wv[(size_t)c * 256 + cc0 + (t & 63)];
        }
        __syncthreads();
        for (int ccl = 0; ccl < 64; ++ccl) {
            float w = wT[t][ccl];
            int cc = cc0 + ccl;
            vs += w * sx[cc];
            #pragma unroll
            for (int m = 0; m < 32; ++m) mv[m] += w * skx[m][cc];
        }
    }
    vsum[b * 256 + t] = vs;
    float bvt = bv[t];
    for (int m = 0; m < 32; ++m) matrix[(b * 32 + m) * 256 + t] = mv[m] + bvt * sk[m];
}

// ---------------------------------------------------------------------------
// K4: z = x + gamma*(vsum + Q^T matrix)*tailor -> bf16 NHWC, pre-swizzled
// ---------------------------------------------------------------------------
__global__ __launch_bounds__(256) void k4_z(const float* __restrict__ x,
        const float* __restrict__ Q, const float* __restrict__ matrix,
        const float* __restrict__ vsum, const float* __restrict__ Ksum,
        const float* __restrict__ gamma_p, ushort* __restrict__ zbf)
{
    int b = blockIdx.x >> 10;
    int n0 = (blockIdx.x & 1023) * 64;
    int t = threadIdx.x;
    int px = t & 63, g = t >> 6;
    __shared__ float qT[32][64];
    __shared__ float mat[32][256];
    __shared__ float vs[256];
    __shared__ float tail[64];
    __shared__ float sk[32];
    __shared__ uint zsh[64 * 128];   // [px][cp] bf16 pairs, swizzled (32KB)
    #pragma unroll
    for (int j = 0; j < 8; ++j) {
        int m = j * 4 + g;
        qT[m][px] = Q[((size_t)b * 32 + m) * Nc + n0 + px];
    }
    for (int j = 0; j < 32; ++j) {
        int idx = j * 256 + t;
        (&mat[0][0])[idx] = matrix[b * 8192 + idx];
    }
    vs[t] = vsum[b * 256 + t];
    if (t < 32) sk[t] = Ksum[b * 32 + t] + LA_EPS;
    __syncthreads();
    if (t < 64) {
        float s = 0.f;
        #pragma unroll
        for (int m = 0; m < 32; ++m) s += qT[m][t] * sk[m];
        tail[t] = 1.0f / ((float)Nc + s);
    }
    __syncthreads();
    float gamma = gamma_p[0];
    float tl = tail[px];
    for (int l = 0; l < 64; l += 2) {
        int c0 = g * 64 + l;
        float s0 = vs[c0], s1 = vs[c0 + 1];
        #pragma unroll
        for (int m = 0; m < 32; ++m) {
            float qv = qT[m][px];
            s0 += qv * mat[m][c0];
            s1 += qv * mat[m][c0 + 1];
        }
        size_t idx0 = (size_t)(b * 256 + c0) * Nc + n0 + px;
        float z0 = x[idx0] + gamma * s0 * tl;
        float z1 = x[idx0 + Nc] + gamma * s1 * tl;
        int cp = c0 >> 1;
        zsh[(px * 512 + (((cp >> 2) ^ (px & 7)) << 4) + (cp & 3) * 4) >> 2] = pack2(z0, z1);
    }
    __syncthreads();
    const uint4* zl = (const uint4*)zsh;
    uint4* gz = (uint4*)(zbf + (((size_t)(b * 65536 + n0)) << 8));
    #pragma unroll
    for (int i2 = 0; i2 < 8; ++i2)
        gz[i2 * 256 + t] = zl[i2 * 256 + t];
}

// ---------------------------------------------------------------------------
// KPREP_Y: y (NCHW f32) -> ybf (padded NHWC bf16, [b][258][258][256])
// ---------------------------------------------------------------------------
__global__ __launch_bounds__(256) void kprep_y(const float* __restrict__ y,
        ushort* __restrict__ ybf)
{
    int blk = blockIdx.x;
    int b = blk >> 13;
    int rest = blk & 8191;
    int ci0 = (rest & 7) * 32;
    int n0 = (rest >> 3) * 64;
    int row = n0 >> 8, x = n0 & 255;
    int t = threadIdx.x;
    __shared__ uint u[16][65];
    int px = t & 63, cig = t >> 6;
    const float* yb = y + (((size_t)(b * 256 + ci0 + cig * 8)) << 16) + n0 + px;
    #pragma unroll
    for (int jj = 0; jj < 4; ++jj) {
        float v0 = yb[((size_t)(jj * 2)) << 16];
        float v1 = yb[((size_t)(jj * 2 + 1)) << 16];
        u[cig * 4 + jj][px] = pack2(v0, v1);
    }
    __syncthreads();
    uint* out32 = (uint*)ybf;
    size_t pbase = (size_t)(row + 1) * 258 + (x + 1);
    int pr = t & 15, pg = t >> 4;
    #pragma unroll
    for (int g2 = 0; g2 < 4; ++g2) {
        int ppx = g2 * 16 + pg;
        size_t uidx = (((size_t)b * 258 * 258 * 256 + (pbase + ppx) * 256 + ci0) >> 1) + pr;
        out32[uidx] = u[pr][ppx];
    }
}

// ---------------------------------------------------------------------------
// KPREP_W: Wb[tap][co][ci] = bf16(wl1*s1 + (tap==4)*wl2*s2)
// ---------------------------------------------------------------------------
__global__ __launch_bounds__(256) void kprep_w(const float* __restrict__ wl1,
        const float* __restrict__ s1, const float* __restrict__ wl2,
        const float* __restrict__ s2, ushort* __restrict__ Wb)
{
    int idx = blockIdx.x * 256 + threadIdx.x;
    int tp = idx >> 16;
    int r = idx & 65535;
    int co = r >> 8;
    float v = wl1[(size_t)r * 9 + tp] * s1[co];
    if (tp == 4) v += wl2[r] * s2[co];
    Wb[idx] = f2bf(v);
}

// ---------------------------------------------------------------------------
// KPREP_QW: Wqb = bf16(wqkv), q rows pre-scaled by 0.25
// ---------------------------------------------------------------------------
__global__ __launch_bounds__(256) void kprep_qw(const float* __restrict__ wqkv,
        ushort* __restrict__ Wqb)
{
    int idx = blockIdx.x * 256 + threadIdx.x;
    float v = wqkv[idx];
    if (idx < 65536) v *= 0.25f;
    Wqb[idx] = f2bf(v);
}

// ---------------------------------------------------------------------------
// KPREP_PW / KPREP_REL (rel transposed to [h][226] for conflict-free gathers)
// ---------------------------------------------------------------------------
__global__ __launch_bounds__(256) void kprep_pw(const float* __restrict__ wpw,
        ushort* __restrict__ Wpwb)
{
    int idx = blockIdx.x * 256 + threadIdx.x;
    Wpwb[idx] = f2bf(wpw[idx]);
}

__global__ __launch_bounds__(256) void kprep_rel(const float* __restrict__ rel,
        ushort* __restrict__ relbf)
{
    int idx = blockIdx.x * 256 + threadIdx.x;
    if (idx < 3600) {
        int d = idx >> 4, h = idx & 15;     // rel[d][h]
        relbf[h * 226 + d] = f2bf(rel[idx]); // -> relbf[h][d]
    }
}

// ---------------------------------------------------------------------------
// K5 (MFMA): L(bf16) = conv3x3(ybf, Wc) + bias
// ---------------------------------------------------------------------------
__global__ __launch_bounds__(512, 2) void k5_mfma(
        const ushort* __restrict__ ybf, const ushort* __restrict__ Wb,
        const float* __restrict__ b1, const float* __restrict__ b2,
        ushort* __restrict__ L)
{
    int blk = blockIdx.x;
    int b = blk >> 9;
    int y0 = (blk >> 1) & 255;
    int x0 = (blk & 1) << 7;
    int t = threadIdx.x;
    int lane = t & 63;
    int w = t >> 6;
    int wr = w >> 1;
    int wc = w & 1;

    __shared__ ushort sW[256 * 64];
    __shared__ ushort sY[128 * 64];

    floatx4 acc[4][4];
    #pragma unroll
    for (int m = 0; m < 4; ++m)
        #pragma unroll
        for (int n = 0; n < 4; ++n)
            acc[m][n] = {0.f, 0.f, 0.f, 0.f};

    const ushort* yb = ybf + (size_t)b * 258 * 258 * 256;
    int ldsWbase = w * 64 * 16;
    int ldsYbase = w * 64 * 16;

    for (int tp = 0; tp < 9; ++tp) {
        int dy = tp / 3 - 1, dx = tp % 3 - 1;
        const ushort* yrow = yb + ((size_t)(y0 + dy + 1) * 258 + (x0 + dx + 1)) * 256;
        const ushort* wtap = Wb + tp * 65536;
        for (int cb = 0; cb < 4; ++cb) {
            int ci0 = cb * 64;
            __syncthreads();
            #pragma unroll
            for (int p = 0; p < 4; ++p) {
                int m = p * 512 + t;
                int row = m >> 3, ch = m & 7;
                const ushort* g = wtap + row * 256 + ci0 + ((ch ^ (row & 7)) << 3);
                gload16(g, (char*)sW + p * 512 * 16 + ldsWbase);
            }
            #pragma unroll
            for (int p = 0; p < 2; ++p) {
                int m = p * 512 + t;
                int pxr = m >> 3, ch = m & 7;
                const ushort* g = yrow + (size_t)pxr * 256 + ci0 + ((ch ^ (pxr & 7)) << 3);
                gload16(g, (char*)sY + p * 512 * 16 + ldsYbase);
            }
            __syncthreads();
            #pragma unroll
            for (int kk = 0; kk < 2; ++kk) {
                int chunkb = kk * 4 + (lane >> 4);
                short8 afr[4];
                #pragma unroll
                for (int m2 = 0; m2 < 4; ++m2) {
                    int row = wr * 64 + m2 * 16 + (lane & 15);
                    int ch = chunkb ^ (row & 7);
                    afr[m2] = *(const short8*)((const char*)sW + row * 128 + ch * 16);
                }
                #pragma unroll
                for (int n2 = 0; n2 < 4; ++n2) {
                    int row = wc * 64 + n2 * 16 + (lane & 15);
                    int ch = chunkb ^ (row & 7);
                    short8 bfr = *(const short8*)((const char*)sY + row * 128 + ch * 16);
                    #pragma unroll
                    for (int m2 = 0; m2 < 4; ++m2)
                        acc[m2][n2] = __builtin_amdgcn_mfma_f32_16x16x32_bf16(
                            afr[m2], bfr, acc[m2][n2], 0, 0, 0);
                }
            }
        }
    }
    int pxb = x0 + wc * 64 + (lane & 15);
    #pragma unroll
    for (int m2 = 0; m2 < 4; ++m2) {
        int cobase = wr * 64 + m2 * 16 + (lane >> 4) * 4;
        #pragma unroll
        for (int r = 0; r < 4; ++r) {
            int co = cobase + r;
            float bias = b1[co] + b2[co];
            ushort* dst = L + (((size_t)(b * 256 + co)) << 16) + y0 * 256 + pxb;
            #pragma unroll
            for (int n2 = 0; n2 < 4; ++n2)
                dst[n2 * 16] = f2bf(acc[m2][n2][r] + bias);
        }
    }
}

// ---------------------------------------------------------------------------
// K6 (MFMA, fused): qkv + window attention, TWO adjacent windows per block.
// Round-9 write schedule + in-register shfl transposes + fused qkv GEMMs +
// rel table transposed [h][226] (conflict-free gathers).
// ---------------------------------------------------------------------------
__global__ __launch_bounds__(512, 2) void k6_mfma(const ushort* __restrict__ zbf,
        const ushort* __restrict__ Wqb, const ushort* __restrict__ relbf,
        float* __restrict__ A)
{
    int blk = blockIdx.x;
    int wxp = blk & 15, wy = (blk >> 4) & 31, b = blk >> 9;
    int t = threadIdx.x;
    int lane = t & 63;
    int w = t >> 6;
    int win = w >> 2;      // waves 0-3: window 0, waves 4-7: window 1
    int wq4 = w & 3;       // 4 heads per wave

    __shared__ ushort zT[128 * 256];     // 64KB, swizzle baked in memory
    __shared__ ushort srel[16 * 226];    // 7.2KB bf16, [h][delta]

    char* zTc = (char*)zT;

    // ---- stage both z windows via linear global_load_lds (zbf pre-swizzled) ----
    {
        const ushort* zb = zbf + (((size_t)b) << 16) * 256;
        #pragma unroll
        for (int p = 0; p < 8; ++p) {
            int m = p * 512 + t;
            int row = m >> 5, ch = m & 31;
            int win2 = row >> 6, px = row & 63;
            int gy = wy * 8 + (px >> 3);
            int gx = (wxp * 2 + win2) * 8 + (px & 7);
            const ushort* g = zb + (((size_t)(gy * 256 + gx)) << 8) + ch * 8;
            gload16(g, zTc + p * 8192 + w * 1024);
        }
    }
    for (int i = t; i < 16 * 226; i += 512) srel[i] = relbf[i];
    __syncthreads();

    int l15 = lane & 15, l4 = lane >> 4;
    int l31 = lane & 31, l5 = lane >> 5;
    bool hilane = (l5 != 0);
    bool hi16 = (l31 & 16) != 0;
    int srcA = (l5 << 5) + (l31 & 15);
    int srcB = srcA + 16;
    int pxbase = win * 64;

    for (int hrep = 0; hrep < 4; ++hrep) {
        int h = wq4 * 4 + hrep;
        const ushort* srh = &srel[h * 226];

        // ---- FUSED qkv: one bz read per (ks,n) feeds all three GEMMs ----
        floatx4 qacc[4] = {}, kacc[4] = {}, vacc[4] = {};
        #pragma unroll
        for (int ks = 0; ks < 8; ++ks) {
            short8 awq = *(const short8*)(Wqb + ((h * 16 + l15) << 8) + ks * 32 + (l4 << 3));
            short8 awk = *(const short8*)(Wqb + ((256 + h * 16 + l15) << 8) + ks * 32 + (l4 << 3));
            short8 bwv = *(const short8*)(Wqb + ((512 + h * 16 + l15) << 8) + ks * 32 + (l4 << 3));
            #pragma unroll
            for (int n = 0; n < 4; ++n) {
                int px = n * 16 + l15;
                short8 bz = *(const short8*)(zTc + (pxbase + px) * 512 + (((ks * 4 + l4) ^ (px & 7)) << 4));
                qacc[n] = __builtin_amdgcn_mfma_f32_16x16x32_bf16(awq, bz, qacc[n], 0, 0, 0);
                kacc[n] = __builtin_amdgcn_mfma_f32_16x16x32_bf16(awk, bz, kacc[n], 0, 0, 0);
                vacc[n] = __builtin_amdgcn_mfma_f32_16x16x32_bf16(bz, bwv, vacc[n], 0, 0, 0);
            }
        }

        Frag bq[2];
        {
            uint plo[4], phi[4];
            #pragma unroll
            for (int n = 0; n < 4; ++n) {
                plo[n] = pack2(qacc[n][0], qacc[n][1]);
                phi[n] = pack2(qacc[n][2], qacc[n][3]);
            }
            #pragma unroll
            for (int it = 0; it < 2; ++it) {
                uint a0 = (uint)__shfl((int)plo[it * 2], srcA), a1 = (uint)__shfl((int)plo[it * 2 + 1], srcA);
                uint b0 = (uint)__shfl((int)phi[it * 2], srcA), b1 = (uint)__shfl((int)phi[it * 2 + 1], srcA);
                uint c0 = (uint)__shfl((int)plo[it * 2], srcB), c1 = (uint)__shfl((int)plo[it * 2 + 1], srcB);
                uint d0 = (uint)__shfl((int)phi[it * 2], srcB), d1 = (uint)__shfl((int)phi[it * 2 + 1], srcB);
                bq[it].u[0] = hi16 ? a1 : a0;
                bq[it].u[1] = hi16 ? b1 : b0;
                bq[it].u[2] = hi16 ? c1 : c0;
                bq[it].u[3] = hi16 ? d1 : d0;
            }
        }
        Frag ak[2];
        {
            uint plo[4], phi[4];
            #pragma unroll
            for (int n = 0; n < 4; ++n) {
                plo[n] = pack2(kacc[n][0], kacc[n][1]);
                phi[n] = pack2(kacc[n][2], kacc[n][3]);
            }
            #pragma unroll
            for (int jt = 0; jt < 2; ++jt) {
                uint a0 = (uint)__shfl((int)plo[jt * 2], srcA), a1 = (uint)__shfl((int)plo[jt * 2 + 1], srcA);
                uint b0 = (uint)__shfl((int)phi[jt * 2], srcA), b1 = (uint)__shfl((int)phi[jt * 2 + 1], srcA);
                uint c0 = (uint)__shfl((int)plo[jt * 2], srcB), c1 = (uint)__shfl((int)plo[jt * 2 + 1], srcB);
                uint d0 = (uint)__shfl((int)phi[jt * 2], srcB), d1 = (uint)__shfl((int)phi[jt * 2 + 1], srcB);
                ak[jt].u[0] = hi16 ? a1 : a0;
                ak[jt].u[1] = hi16 ? b1 : b0;
                ak[jt].u[2] = hi16 ? c1 : c0;
                ak[jt].u[3] = hi16 ? d1 : d0;
            }
        }
        // v was computed TRANSPOSED (z as A-operand): vacc[m] rows are d, cols px
        Frag av[4];
        {
            uint v01[4], v23[4];
            #pragma unroll
            for (int m = 0; m < 4; ++m) {
                v01[m] = pack2(vacc[m][0], vacc[m][1]);
                v23[m] = pack2(vacc[m][2], vacc[m][3]);
            }
            #pragma unroll
            for (int jc = 0; jc < 4; ++jc) {
                av[jc].u[0] = (uint)__shfl((int)v01[jc], srcA);
                av[jc].u[1] = (uint)__shfl((int)v23[jc], srcA);
                av[jc].u[2] = (uint)__shfl((int)v01[jc], srcB);
                av[jc].u[3] = (uint)__shfl((int)v23[jc], srcB);
            }
        }

        // ---- per-it: S^T, softmax, PV ----
        #pragma unroll
        for (int it = 0; it < 2; ++it) {
            floatx16 st[2];
            #pragma unroll
            for (int jt = 0; jt < 2; ++jt) {
                floatx16 zc = {};
                st[jt] = __builtin_amdgcn_mfma_f32_32x32x16_bf16(ak[jt].v, bq[it].v, zc, 0, 0, 0);
            }
            int i = it * 32 + l31;
            int Ai = (i >> 3) * 15 + (i & 7) + 112;
            float mx = -1e30f;
            #pragma unroll
            for (int jt = 0; jt < 2; ++jt)
                #pragma unroll
                for (int r = 0; r < 16; ++r) {
                    int j = jt * 32 + (r & 3) + 8 * (r >> 2) + 4 * l5;
                    int Bjr = (j >> 3) * 15 + (j & 7);
                    float s = st[jt][r] + bf2f(srh[Ai - Bjr]);
                    st[jt][r] = s;
                    mx = fmaxf(mx, s);
                }
            mx = fmaxf(mx, __shfl_xor(mx, 32));
            float sum = 0.f;
            #pragma unroll
            for (int jt = 0; jt < 2; ++jt)
                #pragma unroll
                for (int r = 0; r < 16; ++r) {
                    float e = __expf(st[jt][r] - mx);
                    st[jt][r] = e;
                    sum += e;
                }
            sum += __shfl_xor(sum, 32);
            float rinv = 1.0f / sum;

            floatx16 ot = {};
            #pragma unroll
            for (int jc = 0; jc < 4; ++jc) {
                int jt = jc >> 1, rb = (jc & 1) * 8;
                uint u0 = pack2(st[jt][rb + 0], st[jt][rb + 1]);
                uint u1 = pack2(st[jt][rb + 2], st[jt][rb + 3]);
                uint u2 = pack2(st[jt][rb + 4], st[jt][rb + 5]);
                uint u3 = pack2(st[jt][rb + 6], st[jt][rb + 7]);
                uint s0 = (uint)__shfl_xor((int)u0, 32);
                uint s1 = (uint)__shfl_xor((int)u1, 32);
                uint s2 = (uint)__shfl_xor((int)u2, 32);
                uint s3 = (uint)__shfl_xor((int)u3, 32);
                Frag bf;
                bf.u[0] = hilane ? s2 : u0;
                bf.u[1] = hilane ? s3 : u1;
                bf.u[2] = hilane ? u2 : s0;
                bf.u[3] = hilane ? u3 : s1;
                ot = __builtin_amdgcn_mfma_f32_32x32x16_bf16(av[jc].v, bf.v, ot, 0, 0, 0);
            }
            int gy = wy * 8 + (i >> 3);
            int gx = (wxp * 2 + win) * 8 + (i & 7);
            float* Ab = A + (((size_t)(b * 256 + h * 16)) << 16) + gy * 256 + gx;
            #pragma unroll
            for (int r = 0; r < 8; ++r) {
                int d = (r & 3) + 8 * (r >> 2) + 4 * l5;
                Ab[(size_t)d << 16] = ot[r] * rinv;
            }
        }
    }
}

// ---------------------------------------------------------------------------
// K7 (tiled): L(bf16) += avgpoolV(A) + avgpoolH(A). 64x64 tile + 7-halo LDS.
// ---------------------------------------------------------------------------
__global__ __launch_bounds__(256) void k7_pool(const float* __restrict__ A,
        ushort* __restrict__ L)
{
    int blk = blockIdx.x;
    int tile = blk & 15;
    int c = (blk >> 4) & 255;
    int b = blk >> 12;
    int ty = (tile >> 2) * 64, tx = (tile & 3) * 64;
    int t = threadIdx.x;
    __shared__ float aT[71][73];
    const float* Ac = A + ((size_t)(b * 256 + c) << 16);
    for (int i = t; i < 71 * 71; i += 256) {
        int rr = i / 71, cc = i - rr * 71;
        int gy = ty + rr - 3, gx = tx + cc - 3;
        float v = 0.f;
        if (gy >= 0 && gy <= 256 && gx >= 0 && gx <= 256) {
            int ry = (gy == 256) ? 254 : gy;
            int rx = (gx == 256) ? 254 : gx;
            v = Ac[ry * 256 + rx];
        }
        aT[rr][cc] = v;
    }
    __syncthreads();
    int jj = t & 63;
    int oy0 = (t >> 6) * 16;
    ushort* Lc = L + ((size_t)(b * 256 + c) << 16);
    #pragma unroll 4
    for (int dy = 0; dy < 16; ++dy) {
        int oi = oy0 + dy;
        float sv = 0.f, sh = 0.f;
        #pragma unroll
        for (int u = 0; u < 8; ++u) {
            sv += aT[oi + u][jj + 3];
            sh += aT[oi + 3][jj + u];
        }
        int idx = (ty + oi) * 256 + tx + jj;
        Lc[idx] = f2bf(bf2f(Lc[idx]) + 0.125f * (sv + sh));
    }
}

// ---------------------------------------------------------------------------
// K8 (tiled): D(bf16) = sp * dwconv8x8(pad_out(L bf16), wdw, pad=3) + bp
// Register-sliding rows; accumulation order unchanged.
// ---------------------------------------------------------------------------
__global__ __launch_bounds__(256) void k8_dw(const ushort* __restrict__ P,
        const float* __restrict__ wdw, const float* __restrict__ sp,
        const float* __restrict__ bp, ushort* __restrict__ D)
{
    int blk = blockIdx.x;
    int tile = blk & 63;
    int c = (blk >> 6) & 255;
    int b = blk >> 14;
    int ty = (tile >> 3) * 32, tx = (tile & 7) * 32;
    int t = threadIdx.x;
    __shared__ float pT[39][40];
    __shared__ float wT[64];
    const ushort* Pc = P + ((size_t)(b * 256 + c) << 16);
    for (int i = t; i < 39 * 40; i += 256) {
        int rr = i / 40, cc = i - rr * 40;
        int gy = ty + rr - 3, gx = tx + cc - 3;
        float v = 0.f;
        if (gy >= 0 && gy <= 256 && gx >= 0 && gx <= 256) {
            int ry = (gy == 256) ? 254 : gy;
            int rx = (gx == 256) ? 254 : gx;
            v = bf2f(Pc[ry * 256 + rx]);
        }
        pT[rr][cc] = v;
    }
    if (t < 64) wT[t] = wdw[c * 64 + t];
    __syncthreads();
    int jj = t & 31;
    int oy0 = (t >> 5) * 4;
    float acc[4] = {0.f, 0.f, 0.f, 0.f};
    #pragma unroll
    for (int r = 0; r < 11; ++r) {
        float pv[8];
        #pragma unroll
        for (int v = 0; v < 8; ++v) pv[v] = pT[oy0 + r][jj + v];
        #pragma unroll
        for (int dy = 0; dy < 4; ++dy) {
            if (dy >= r - 7 && dy <= r && dy <= 3) {
                int u = r - dy;
                #pragma unroll
                for (int v = 0; v < 8; ++v)
                    acc[dy] += wT[u * 8 + v] * pv[v];
            }
        }
    }
    float spc = sp[c], bpc = bp[c];
    ushort* Dc = D + ((size_t)(b * 256 + c) << 16);
    #pragma unroll
    for (int dy = 0; dy < 4; ++dy)
        Dc[(ty + oy0 + dy) * 256 + tx + jj] = f2bf(spc * acc[dy] + bpc);
}

// ---------------------------------------------------------------------------
// K9 (MFMA): out[co][px] = sum_ci Wpw[co][ci] * D[ci][px]
// ---------------------------------------------------------------------------
__global__ __launch_bounds__(512, 2) void k9_mfma(
        const ushort* __restrict__ D, const ushort* __restrict__ Wpwb,
        float* __restrict__ out)
{
    int blk = blockIdx.x;
    int b = blk >> 9;
    int px0 = (blk & 511) << 7;
    int t = threadIdx.x;
    int lane = t & 63;
    int w = t >> 6;
    int wr = w >> 1, wc = w & 1;

    __shared__ ushort sW[256 * 64];
    __shared__ ushort sD[128 * 64];

    floatx4 acc[4][4];
    #pragma unroll
    for (int m = 0; m < 4; ++m)
        #pragma unroll
        for (int n = 0; n < 4; ++n)
            acc[m][n] = {0.f, 0.f, 0.f, 0.f};

    int ldsWbase = w * 64 * 16;

    for (int cb = 0; cb < 4; ++cb) {
        int ci0 = cb * 64;
        __syncthreads();
        #pragma unroll
        for (int p = 0; p < 4; ++p) {
            int m = p * 512 + t;
            int row = m >> 3, ch = m & 7;
            const ushort* g = Wpwb + row * 256 + ci0 + ((ch ^ (row & 7)) << 3);
            gload16(g, (char*)sW + p * 512 * 16 + ldsWbase);
        }
        #pragma unroll
        for (int p = 0; p < 2; ++p) {
            int m = p * 512 + t;
            int ci = m & 63, pxb = (m >> 6) * 8;
            short8 v = *(const short8*)(D + ((size_t)(b * 256 + ci0 + ci) << 16) + px0 + pxb);
            #pragma unroll
            for (int k2 = 0; k2 < 8; ++k2) {
                int px = pxb + k2;
                *(ushort*)((char*)sD + px * 128 + (((ci >> 3) ^ (px & 7)) << 4) + (ci & 7) * 2) =
                    (ushort)v[k2];
            }
        }
        __syncthreads();
        #pragma unroll
        for (int kk = 0; kk < 2; ++kk) {
            int chunkb = kk * 4 + (lane >> 4);
            short8 afr[4];
            #pragma unroll
            for (int m2 = 0; m2 < 4; ++m2) {
                int row = wr * 64 + m2 * 16 + (lane & 15);
                int ch = chunkb ^ (row & 7);
                afr[m2] = *(const short8*)((const char*)sW + row * 128 + ch * 16);
            }
            #pragma unroll
            for (int n2 = 0; n2 < 4; ++n2) {
                int row = wc * 64 + n2 * 16 + (lane & 15);
                int ch = chunkb ^ (row & 7);
                short8 bfr = *(const short8*)((const char*)sD + row * 128 + ch * 16);
                #pragma unroll
                for (int m2 = 0; m2 < 4; ++m2)
                    acc[m2][n2] = __builtin_amdgcn_mfma_f32_16x16x32_bf16(
                        afr[m2], bfr, acc[m2][n2], 0, 0, 0);
            }
        }
    }
    int pxb = px0 + wc * 64 + (lane & 15);
    #pragma unroll
    for (int m2 = 0; m2 < 4; ++m2) {
        int cobase = wr * 64 + m2 * 16 + (lane >> 4) * 4;
        #pragma unroll
        for (int r = 0; r < 4; ++r) {
            int co = cobase + r;
            float* dst = out + (((size_t)(b * 256 + co)) << 16) + pxb;
            #pragma unroll
            for (int n2 = 0; n2 < 4; ++n2)
                dst[n2 * 16] = acc[m2][n2][r];
        }
    }
}

// ---------------------------------------------------------------------------
extern "C" void kernel_launch(void* const* d_in, const int* in_sizes, int n_in,
                              void* d_out, int out_size, void* d_ws, size_t ws_size,
                              hipStream_t stream)
{
    (void)in_sizes; (void)n_in; (void)out_size; (void)ws_size;
    const float* x     = (const float*)d_in[0];
    const float* y     = (const float*)d_in[1];
    const float* gamma = (const float*)d_in[2];
    const float* la_wq = (const float*)d_in[3];
    const float* la_bq = (const float*)d_in[4];
    const float* la_wk = (const float*)d_in[5];
    const float* la_bk = (const float*)d_in[6];
    const float* la_wv = (const float*)d_in[7];
    const float* la_bv = (const float*)d_in[8];
    const float* wqkv  = (const float*)d_in[9];
    const float* wl1   = (const float*)d_in[10];
    const float* s1    = (const float*)d_in[11];
    const float* b1    = (const float*)d_in[12];
    const float* wl2   = (const float*)d_in[13];
    const float* s2    = (const float*)d_in[14];
    const float* b2    = (const float*)d_in[15];
    const float* rel   = (const float*)d_in[16];
    const float* wdw   = (const float*)d_in[17];
    const float* sp    = (const float*)d_in[18];
    const float* bp    = (const float*)d_in[19];
    const float* wpw   = (const float*)d_in[20];
    float* out = (float*)d_out;

    float* ws = (float*)d_ws;
    float* Q      = ws;                      // 4,194,304 floats (Qo)
    float* Kn     = ws + 4194304;            // 4,194,304 (W-preps alias after k2)
    float* stats  = ws + 8388608;            // 40,960 floats
    float* Ksum   = stats;
    float* xsum   = stats + 64;
    float* KX     = stats + 576;
    float* matrix = stats + 16960;
    float* vsum   = stats + 33344;
    float* A      = ws + 8429568;            // 33,554,432 (ybf alias; attn out; Dbf)
    float* L      = A + 33554432;            // 33,554,432 (phase1 aliases; Lb bf16)

    // L-region phase-1 aliases (all dead before k5 writes Lb):
    float* KXp   = L;                        // 1024 x 8192
    float* xsp   = L + 8388608;
    float* ksp   = L + 8650752;
    ushort* xbf  = (ushort*)(L + 8683520);   // x NHWC bf16
    ushort* Wqkb = (ushort*)(L + 25460736);  // 16,384 ushorts

    ushort* Wb    = (ushort*)Kn;             // conv weights, 589,824 bf16
    ushort* Wqb   = (ushort*)Kn + 600064;    // qkv weights, 196,608 bf16
    ushort* Wpwb  = (ushort*)Kn + 798720;    // pw weights, 65,536 bf16
    ushort* relbf = (ushort*)Kn + 864256;    // rel table [16][226], 3,616 bf16
    ushort* ybf   = (ushort*)A;              // padded NHWC y — until k6
    ushort* Dbf   = (ushort*)A;              // bf16 dwconv out — after k8
    ushort* zbf   = (ushort*)d_out;          // z bf16 NHWC (pre-swizzled) — k4..k6
    ushort* Lb    = (ushort*)L;              // local+pool accumulator, bf16

    hipMemsetAsync(ybf, 0, (size_t)2 * 258 * 258 * 256 * sizeof(ushort), stream);

    kprep_y  <<<16384, 256, 0, stream>>>(y, ybf);
    kprep_x  <<<16384, 256, 0, stream>>>(x, xbf);
    kprep_qk <<<64,    256, 0, stream>>>(la_wq, la_wk, Wqkb);
    k1_mfma  <<<2048,  512, 0, stream>>>(xbf, Wqkb, la_bq, la_bk, Q, Kn);
    k2_kx    <<<1024,  256, 0, stream>>>(xbf, Kn, KXp, xsp, ksp);
    kprep_w  <<<2304,  256, 0, stream>>>(wl1, s1, wl2, s2, Wb);  // Kn dead after k2
    kprep_qw <<<768,   256, 0, stream>>>(wqkv, Wqb);
    kprep_pw <<<256,   256, 0, stream>>>(wpw, Wpwb);
    kprep_rel<<<15,    256, 0, stream>>>(rel, relbf);
    k2r      <<<68,    256, 0, stream>>>(KXp, xsp, ksp, KX, xsum, Ksum);
    k3_mat   <<<2,     256, 0, stream>>>(la_wv, la_bv, KX, xsum, Ksum, matrix, vsum);
    k4_z     <<<2048,  256, 0, stream>>>(x, Q, matrix, vsum, Ksum, gamma, zbf);
    k5_mfma  <<<1024,  512, 0, stream>>>(ybf, Wb, b1, b2, Lb);   // overwrites xbf etc
    k6_mfma  <<<1024,  512, 0, stream>>>(zbf, Wqb, relbf, A);    // overwrites ybf
    k7_pool  <<<8192,  256, 0, stream>>>(A, Lb);
    k8_dw    <<<32768, 256, 0, stream>>>(Lb, wdw, sp, bp, Dbf);
    k9_mfma  <<<1024,  512, 0, stream>>>(Dbf, Wpwb, out);
}